// Round 9
// baseline (422.698 us; speedup 1.0000x reference)
//
#include <hip/hip_runtime.h>
#include <hip/hip_bf16.h>
#include <math.h>

#define MORD 862

typedef short s16x8 __attribute__((ext_vector_type(8)));
typedef float f32x4 __attribute__((ext_vector_type(4)));
typedef float f32x4a __attribute__((ext_vector_type(4), aligned(4)));

static __device__ __forceinline__ unsigned short f2bf(float v) {
  __hip_bfloat16 h = __float2bfloat16(v);
  return *(unsigned short*)&h;
}

// ---- Binned CSR build ----
__global__ __launch_bounds__(256) void bin_hist(const int* __restrict__ dstA, int* __restrict__ bhist, int E, int nbins) {
  __shared__ int lh[512];
  for (int i = threadIdx.x; i < nbins; i += 256) lh[i] = 0;
  __syncthreads();
  for (int e = blockIdx.x * 256 + threadIdx.x; e < E; e += gridDim.x * 256)
    atomicAdd(&lh[dstA[e] >> 10], 1);
  __syncthreads();
  for (int i = threadIdx.x; i < nbins; i += 256)
    if (lh[i]) atomicAdd(&bhist[i], lh[i]);
}

__global__ __launch_bounds__(512) void bin_scan(const int* __restrict__ bhist, int* __restrict__ boff,
                                                int* __restrict__ gcur, int nbins, int E) {
  __shared__ int ts[512];
  int tid = threadIdx.x;
  int v = (tid < nbins) ? bhist[tid] : 0;
  ts[tid] = v;
  __syncthreads();
  for (int st = 1; st < 512; st <<= 1) {
    int t = (tid >= st) ? ts[tid - st] : 0;
    __syncthreads();
    ts[tid] += t;
    __syncthreads();
  }
  int ex = ts[tid] - v;
  if (tid < nbins) { boff[tid] = ex; gcur[tid] = ex; }
  if (tid == 0) boff[nbins] = E;
}

__global__ __launch_bounds__(256) void bin_split(const int* __restrict__ srcA, const int* __restrict__ dstA,
                                                 int* __restrict__ gcur, unsigned long long* __restrict__ ebuf,
                                                 int E, int nbins) {
  __shared__ unsigned long long sbuf[512 * 8];
  __shared__ int lcur[512];
  int tid = threadIdx.x;
  for (int base = blockIdx.x * 1024; base < E; base += (int)gridDim.x * 1024) {
    for (int i = tid; i < nbins; i += 256) lcur[i] = 0;
    __syncthreads();
    int e0 = base + tid * 4;
#pragma unroll
    for (int j = 0; j < 4; j++) {
      int e = e0 + j;
      if (e < E) {
        int d = dstA[e], s = srcA[e];
        int bin = d >> 10;
        unsigned long long p = ((unsigned long long)(unsigned int)d << 32) | (unsigned int)s;
        int slot = atomicAdd(&lcur[bin], 1);
        if (slot < 8) sbuf[bin * 8 + slot] = p;
        else { int g = atomicAdd(&gcur[bin], 1); ebuf[g] = p; }
      }
    }
    __syncthreads();
    for (int b = tid; b < nbins; b += 256) {
      int cnt = min(lcur[b], 8);
      if (cnt > 0) {
        int g = atomicAdd(&gcur[b], cnt);
        for (int k = 0; k < cnt; k++) ebuf[g + k] = sbuf[b * 8 + k];
      }
    }
    __syncthreads();
  }
}

__global__ __launch_bounds__(256) void bin_csr(const unsigned long long* __restrict__ ebuf,
                                               const int* __restrict__ boff,
                                               int* __restrict__ off, int* __restrict__ csr,
                                               int N, int E) {
  __shared__ int lcur[1024];
  __shared__ int part[256];
  int b = blockIdx.x;
  int n0 = b << 10;
  int nn = min(1024, N - n0);
  int e0 = boff[b], e1 = boff[b + 1];
  int tid = threadIdx.x;
  for (int i = tid; i < nn; i += 256) lcur[i] = 0;
  __syncthreads();
  for (int e = e0 + tid; e < e1; e += 256) {
    int d = (int)(ebuf[e] >> 32);
    atomicAdd(&lcur[d - n0], 1);
  }
  __syncthreads();
  int base4 = tid * 4;
  int c0 = (base4 < nn) ? lcur[base4] : 0;
  int c1 = (base4 + 1 < nn) ? lcur[base4 + 1] : 0;
  int c2 = (base4 + 2 < nn) ? lcur[base4 + 2] : 0;
  int c3 = (base4 + 3 < nn) ? lcur[base4 + 3] : 0;
  int tot = c0 + c1 + c2 + c3;
  part[tid] = tot;
  __syncthreads();
  for (int st = 1; st < 256; st <<= 1) {
    int t = (tid >= st) ? part[tid - st] : 0;
    __syncthreads();
    part[tid] += t;
    __syncthreads();
  }
  int pre = part[tid] - tot;
  __syncthreads();
  if (base4 < nn)     { lcur[base4]     = pre;                off[n0 + base4]     = e0 + pre; }
  if (base4 + 1 < nn) { lcur[base4 + 1] = pre + c0;           off[n0 + base4 + 1] = e0 + pre + c0; }
  if (base4 + 2 < nn) { lcur[base4 + 2] = pre + c0 + c1;      off[n0 + base4 + 2] = e0 + pre + c0 + c1; }
  if (base4 + 3 < nn) { lcur[base4 + 3] = pre + c0 + c1 + c2; off[n0 + base4 + 3] = e0 + pre + c0 + c1 + c2; }
  if (b == 0 && tid == 0) off[N] = E;
  __syncthreads();
  for (int e = e0 + tid; e < e1; e += 256) {
    unsigned long long p = ebuf[e];
    int d = (int)(p >> 32);
    int s = (int)(p & 0xffffffffu);
    int slot = atomicAdd(&lcur[d - n0], 1);
    csr[e0 + slot] = s;
  }
}

__global__ __launch_bounds__(256) void graph_off(const int* __restrict__ batch, int* __restrict__ goff, int N, int B) {
  int b = blockIdx.x * blockDim.x + threadIdx.x;
  if (b > B) return;
  int lo = 0, hi = N;
  while (lo < hi) {
    int mid = (lo + hi) >> 1;
    if (batch[mid] < b) lo = mid + 1; else hi = mid;
  }
  goff[b] = lo;
}

__global__ __launch_bounds__(256) void prep_wcat3(const float* __restrict__ Wl1, const float* __restrict__ Wr1,
                                                  unsigned short* __restrict__ Wc1,
                                                  const float* __restrict__ Wl2, const float* __restrict__ Wr2,
                                                  unsigned short* __restrict__ Wc2,
                                                  const float* __restrict__ Wl3, const float* __restrict__ Wr3,
                                                  unsigned short* __restrict__ Wc3) {
  int set = blockIdx.y;
  const float* Wl = set == 0 ? Wl1 : (set == 1 ? Wl2 : Wl3);
  const float* Wr = set == 0 ? Wr1 : (set == 1 ? Wr2 : Wr3);
  unsigned short* Wc = set == 0 ? Wc1 : (set == 1 ? Wc2 : Wc3);
  int CIN = set == 0 ? 8 : 32;
  int idx = blockIdx.x * 256 + threadIdx.x;
  if (idx >= 352 * 64) return;
  int row = idx >> 6, k = idx & 63;
  int d = row >> 5, o = row & 31;
  float v = 0.f;
  if (k < CIN) v = Wl[((size_t)d * 32 + o) * CIN + k];
  else if (k < 2 * CIN) v = Wr[((size_t)d * 32 + o) * CIN + (k - CIN)];
  Wc[idx] = f2bf(v);
}

// hx1[n][32] bf16: 0-7 = neighbor-sum(x), 8-15 = x, 16-31 zero
__global__ __launch_bounds__(256) void prep_hx1(const float* __restrict__ x, const int* __restrict__ off,
                                                const int* __restrict__ csr, unsigned short* __restrict__ hx1, int N) {
  int n = blockIdx.x * 256 + threadIdx.x;
  if (n >= N) return;
  int a = off[n], b = off[n + 1];
  float ag[8] = {};
  for (int j = a; j < b; j++) {
    const float* xr = x + (size_t)csr[j] * 8;
#pragma unroll
    for (int t = 0; t < 8; t++) ag[t] += xr[t];
  }
  const float* xo = x + (size_t)n * 8;
  unsigned short* d = hx1 + (size_t)n * 32;
  s16x8 w0, w1, z;
#pragma unroll
  for (int t = 0; t < 8; t++) {
    w0[t] = (short)f2bf(ag[t]);
    w1[t] = (short)f2bf(xo[t]);
    z[t] = 0;
  }
  *(s16x8*)(d) = w0;
  *(s16x8*)(d + 8) = w1;
  *(s16x8*)(d + 16) = z;
  *(s16x8*)(d + 24) = z;
}

__global__ __launch_bounds__(256) void gather_bf16(const unsigned short* __restrict__ hx, const int* __restrict__ off,
                                                   const int* __restrict__ csr, unsigned short* __restrict__ hxw, int N) {
  long long tid = (long long)blockIdx.x * 256 + threadIdx.x;
  if (tid >= (long long)N * 4) return;
  int n = (int)(tid >> 2), q = (int)(tid & 3);
  int a = off[n], b = off[n + 1];
  float s[8] = {};
  for (int j = a; j < b; j++) {
    const s16x8 v = *(const s16x8*)(hx + (size_t)csr[j] * 64 + 32 + q * 8);
#pragma unroll
    for (int t = 0; t < 8; t++) {
      unsigned int u = ((unsigned int)(unsigned short)v[t]) << 16;
      s[t] += *(float*)&u;
    }
  }
  s16x8 w;
#pragma unroll
  for (int t = 0; t < 8; t++) w[t] = (short)f2bf(s[t]);
  *(s16x8*)(hxw + (size_t)n * 64 + q * 8) = w;
}

// MFMA all-degree transform. ACH = 16B chunks per A row.
template <int KS, int ACH, int OUTMODE>
__global__ __launch_bounds__(512, 4) void mfconv_mfma(const unsigned short* __restrict__ hx,
                                                      const unsigned short* __restrict__ Wcat,
                                                      const float* __restrict__ bl,
                                                      const int* __restrict__ off,
                                                      void* __restrict__ outp, int N) {
  __shared__ __align__(16) unsigned short As[128 * ACH * 8];
  __shared__ __align__(16) unsigned short Bs[352 * 64];
  __shared__ float sbias[352];
  __shared__ int sdeg[128];
  const int tid = threadIdx.x;
  const int wid = tid >> 6, lane = tid & 63;

  for (int s = wid; s < 44; s += 8) {
    int c = s * 64 + lane;
    int cs = c ^ ((c >> 3) & 7);
    __builtin_amdgcn_global_load_lds((const __attribute__((address_space(1))) void*)((const char*)Wcat + (size_t)cs * 16),
                                     (__attribute__((address_space(3))) void*)((char*)Bs + s * 1024), 16, 0, 0);
  }
  for (int i = tid; i < 352; i += 512) sbias[i] = bl[i];

  const int ntiles = N >> 7;
  for (int t = blockIdx.x; t < ntiles; t += (int)gridDim.x) {
    const int row0 = t << 7;
    __syncthreads();
    const char* Abase = (const char*)hx + (size_t)row0 * ACH * 16;
    for (int s = wid; s < 2 * ACH; s += 8) {
      int c = s * 64 + lane;
      int row = c / ACH, ch = c & (ACH - 1);
      int cs = row * ACH + (ch ^ (row & (ACH - 1)));
      __builtin_amdgcn_global_load_lds((const __attribute__((address_space(1))) void*)(Abase + (size_t)cs * 16),
                                       (__attribute__((address_space(3))) void*)((char*)As + s * 1024), 16, 0, 0);
    }
    if (tid < 128) sdeg[tid] = min(off[row0 + tid + 1] - off[row0 + tid], 10);
    __syncthreads();

    const int ra = wid * 16 + (lane & 15);
    const int g4 = lane >> 4;
    const int rl0 = wid * 16 + g4 * 4;
    int dj[4];
#pragma unroll
    for (int j = 0; j < 4; j++) dj[j] = sdeg[rl0 + j];

#pragma unroll
    for (int h = 0; h < 2; h++) {
      f32x4 acc[11] = {};
#pragma unroll
      for (int kk = 0; kk < KS; kk++) {
        int cha = (kk * 4 + g4) ^ (ra & (ACH - 1));
        s16x8 af = *(const s16x8*)((const char*)As + (size_t)(ra * ACH + cha) * 16);
#pragma unroll
        for (int nn = 0; nn < 11; nn++) {
          int rb = (h * 11 + nn) * 16 + (lane & 15);
          int cb = rb * 8 + kk * 4 + g4;
          s16x8 bf = *(const s16x8*)((const char*)Bs + (size_t)(cb ^ (rb & 7)) * 16);
          acc[nn] = __builtin_amdgcn_mfma_f32_16x16x32_bf16(af, bf, acc[nn], 0, 0, 0);
        }
      }
#pragma unroll
      for (int nn = 0; nn < 11; nn++) {
        int n = h * 11 + nn;
        int dsel = n >> 1;
        int o = (n & 1) * 16 + (lane & 15);
        float bv = sbias[dsel * 32 + o];
#pragma unroll
        for (int j = 0; j < 4; j++) {
          if (dj[j] == dsel) {
            float v = acc[nn][j] + bv;
            size_t gr = (size_t)row0 + rl0 + j;
            if (OUTMODE == 0) {
              v = fmaxf(v, 0.f);
              ((unsigned short*)outp)[gr * 64 + 32 + o] = f2bf(v);
            } else {
              ((float*)outp)[gr * 32 + o] = v;
            }
          }
        }
      }
    }
  }
}

__global__ __launch_bounds__(256) void pool_seg(const float* __restrict__ h, const int* __restrict__ goff,
                                                float* __restrict__ pooled, int B) {
  int w = (int)((blockIdx.x * 256 + threadIdx.x) >> 6);
  if (w >= B) return;
  int lane = threadIdx.x & 63;
  int c = lane & 31, r2 = lane >> 5;
  int a = goff[w], b = goff[w + 1];
  float s = 0.f;
  for (int r = a + r2; r < b; r += 2) s += h[(size_t)r * 32 + c];
  s += __shfl_down(s, 32);
  if (r2 == 0) pooled[(size_t)w * 32 + c] = s / fmaxf((float)(b - a), 1.f);
}

// fc1 v2: BM=64, BN=128, BK=64, 256 thr (4 waves, 32x64/wave). Coalesced reg-staged
// fp32->bf16 + XOR-swizzled LDS + fused colstats. Grid (4, M/64) = 1024 blocks.
__global__ __launch_bounds__(256) void gemm_fc1(const float* __restrict__ A, const float* __restrict__ Bw,
                                                const float* __restrict__ bias, unsigned short* __restrict__ Cout,
                                                float* __restrict__ csum, float* __restrict__ csq, int M, int Nn) {
  __shared__ __align__(16) unsigned short As[64 * 64];
  __shared__ __align__(16) unsigned short Bs[128 * 64];
  __shared__ float scs[128], sqs[128];
  const int tid = threadIdx.x;
  const int lane = tid & 63, wid = tid >> 6;
  const int m0 = blockIdx.y * 64, n0 = blockIdx.x * 128;
  const int wr = wid >> 1, wc = wid & 1;
  const int g4 = lane >> 4, lc = lane & 15;
  f32x4 acc[2][4] = {};

  for (int k0 = 0; k0 < 896; k0 += 64) {
    __syncthreads();
    // A stage: 64x64, 1024 f32x4 chunks; idx = tid + i*256; row=idx>>4, c16=idx&15 (8B units)
#pragma unroll
    for (int i = 0; i < 4; i++) {
      int idx = tid + i * 256;
      int row = idx >> 4, c16 = idx & 15;
      int kbase = k0 + c16 * 4;
      float fv[4];
      if (kbase + 4 <= MORD) {
        f32x4a v = *(const f32x4a*)(A + (size_t)(m0 + row) * MORD + kbase);
        fv[0] = v[0]; fv[1] = v[1]; fv[2] = v[2]; fv[3] = v[3];
      } else {
        const float* ga = A + (size_t)(m0 + row) * MORD;
#pragma unroll
        for (int e = 0; e < 4; e++) fv[e] = (kbase + e < MORD) ? ga[kbase + e] : 0.f;
      }
      unsigned short w[4];
#pragma unroll
      for (int e = 0; e < 4; e++) w[e] = f2bf(fv[e]);
      int ch = (c16 >> 1) ^ (row & 7);
      *(unsigned long long*)((char*)As + row * 128 + ch * 16 + (c16 & 1) * 8) =
          *(unsigned long long*)w;
    }
    // B stage: 128x64, 2048 chunks
#pragma unroll
    for (int i = 0; i < 8; i++) {
      int idx = tid + i * 256;
      int row = idx >> 4, c16 = idx & 15;
      int kbase = k0 + c16 * 4;
      float fv[4];
      if (kbase + 4 <= MORD) {
        f32x4a v = *(const f32x4a*)(Bw + (size_t)(n0 + row) * MORD + kbase);
        fv[0] = v[0]; fv[1] = v[1]; fv[2] = v[2]; fv[3] = v[3];
      } else {
        const float* gb = Bw + (size_t)(n0 + row) * MORD;
#pragma unroll
        for (int e = 0; e < 4; e++) fv[e] = (kbase + e < MORD) ? gb[kbase + e] : 0.f;
      }
      unsigned short w[4];
#pragma unroll
      for (int e = 0; e < 4; e++) w[e] = f2bf(fv[e]);
      int ch = (c16 >> 1) ^ (row & 7);
      *(unsigned long long*)((char*)Bs + row * 128 + ch * 16 + (c16 & 1) * 8) =
          *(unsigned long long*)w;
    }
    __syncthreads();
#pragma unroll
    for (int kk = 0; kk < 2; kk++) {
      s16x8 af[2], bfr[4];
#pragma unroll
      for (int m = 0; m < 2; m++) {
        int ra = wr * 32 + m * 16 + lc;
        af[m] = *(const s16x8*)((const char*)As + ra * 128 + (((kk * 4 + g4) ^ (ra & 7)) * 16));
      }
#pragma unroll
      for (int n = 0; n < 4; n++) {
        int rb = wc * 64 + n * 16 + lc;
        bfr[n] = *(const s16x8*)((const char*)Bs + rb * 128 + (((kk * 4 + g4) ^ (rb & 7)) * 16));
      }
#pragma unroll
      for (int m = 0; m < 2; m++)
#pragma unroll
        for (int n = 0; n < 4; n++)
          acc[m][n] = __builtin_amdgcn_mfma_f32_16x16x32_bf16(af[m], bfr[n], acc[m][n], 0, 0, 0);
    }
  }
  __syncthreads();
  if (tid < 128) { scs[tid] = 0.f; sqs[tid] = 0.f; }
  __syncthreads();
  const int rbase = m0 + wr * 32 + g4 * 4;
#pragma unroll
  for (int n = 0; n < 4; n++) {
    int colb = wc * 64 + n * 16 + lc;
    float bv = bias[n0 + colb];
    float s = 0.f, q = 0.f;
#pragma unroll
    for (int m = 0; m < 2; m++) {
#pragma unroll
      for (int j = 0; j < 4; j++) {
        float v = fmaxf(acc[m][n][j] + bv, 0.f);
        Cout[(size_t)(rbase + m * 16 + j) * Nn + n0 + colb] = f2bf(v);
        s += v;
        q = fmaf(v, v, q);
      }
    }
    s += __shfl_xor(s, 16); q += __shfl_xor(q, 16);
    s += __shfl_xor(s, 32); q += __shfl_xor(q, 32);
    if (g4 == 0) { atomicAdd(&scs[colb], s); atomicAdd(&sqs[colb], q); }
  }
  __syncthreads();
  if (tid < 128) { atomicAdd(&csum[n0 + tid], scs[tid]); atomicAdd(&csq[n0 + tid], sqs[tid]); }
}

__global__ __launch_bounds__(256) void prepW2_kernel(const float* __restrict__ W2, const float* __restrict__ b2,
                                                     const float* __restrict__ a1, const float* __restrict__ h1,
                                                     unsigned short* __restrict__ W2p, float* __restrict__ b2p,
                                                     int Nn, int K) {
  int wid = threadIdx.x >> 6, lane = threadIdx.x & 63;
  int n = blockIdx.x * 4 + wid;
  if (n >= Nn) return;
  float part = 0.f;
  for (int k = lane; k < K; k += 64) {
    float w = W2[(size_t)n * K + k];
    W2p[(size_t)n * K + k] = f2bf(w * a1[k]);
    part = fmaf(w, h1[k], part);
  }
#pragma unroll
  for (int off = 32; off > 0; off >>= 1) part += __shfl_down(part, off, 64);
  if (lane == 0) b2p[n] = b2[n] + part;
}

// bf16 MFMA GEMM (fc2)
template <int OUTBF16>
__global__ __launch_bounds__(256) void gemm_mfma(const unsigned short* __restrict__ A,
                                                 const unsigned short* __restrict__ Bw,
                                                 const float* __restrict__ bias,
                                                 void* __restrict__ Cout, int M, int Nn, int Kp) {
  __shared__ __align__(16) unsigned short As[128 * 64];
  __shared__ __align__(16) unsigned short Bs[128 * 64];
  int tid = threadIdx.x;
  int wid = tid >> 6, lane = tid & 63;
  int m0 = blockIdx.y * 128, n0 = blockIdx.x * 128;
  int wr = wid >> 1, wc = wid & 1;
  f32x4 acc[4][4] = {};

  int srow_l = lane >> 3;
  int scol = (lane & 7) * 8;
  int aReadBase = ((wr * 64 + (lane & 15)) * 128) + ((lane >> 4) * 16);
  int bReadBase = ((wc * 64 + (lane & 15)) * 128) + ((lane >> 4) * 16);

  const unsigned short* Ablk = A + (size_t)m0 * Kp;
  const unsigned short* Bblk = Bw + (size_t)n0 * Kp;

  for (int k0 = 0; k0 < Kp; k0 += 64) {
#pragma unroll
    for (int i = 0; i < 4; i++) {
      int s = wid * 4 + i;
      int row = s * 8 + srow_l;
      const unsigned short* ga = Ablk + (size_t)row * Kp + k0 + scol;
      const unsigned short* gb = Bblk + (size_t)row * Kp + k0 + scol;
      __builtin_amdgcn_global_load_lds((const __attribute__((address_space(1))) void*)ga,
                                       (__attribute__((address_space(3))) void*)(As + s * 512), 16, 0, 0);
      __builtin_amdgcn_global_load_lds((const __attribute__((address_space(1))) void*)gb,
                                       (__attribute__((address_space(3))) void*)(Bs + s * 512), 16, 0, 0);
    }
    __syncthreads();
#pragma unroll
    for (int kk = 0; kk < 2; kk++) {
      s16x8 af[4], bfr[4];
#pragma unroll
      for (int m = 0; m < 4; m++)
        af[m] = *(const s16x8*)((const char*)As + aReadBase + m * (16 * 128) + kk * 64);
#pragma unroll
      for (int n = 0; n < 4; n++)
        bfr[n] = *(const s16x8*)((const char*)Bs + bReadBase + n * (16 * 128) + kk * 64);
#pragma unroll
      for (int m = 0; m < 4; m++)
#pragma unroll
        for (int n = 0; n < 4; n++)
          acc[m][n] = __builtin_amdgcn_mfma_f32_16x16x32_bf16(af[m], bfr[n], acc[m][n], 0, 0, 0);
    }
    __syncthreads();
  }

  int rbase = m0 + wr * 64 + (lane >> 4) * 4;
  int cbase = n0 + wc * 64 + (lane & 15);
#pragma unroll
  for (int m = 0; m < 4; m++)
#pragma unroll
    for (int n = 0; n < 4; n++) {
      int col = cbase + n * 16;
      float bv = bias[col];
#pragma unroll
      for (int j = 0; j < 4; j++) {
        int row = rbase + m * 16 + j;
        float v = fmaxf(acc[m][n][j] + bv, 0.f);
        if (OUTBF16)
          ((unsigned short*)Cout)[(size_t)row * Nn + col] = f2bf(v);
        else
          ((float*)Cout)[(size_t)row * Nn + col] = v;
      }
    }
}

// fp32 fallback GEMM (fc3)
template <bool RELU>
__global__ __launch_bounds__(256) void gemm_bias(const float* __restrict__ A, const float* __restrict__ Bw,
                                                 const float* __restrict__ bias,
                                                 const float* __restrict__ scA, const float* __restrict__ shA,
                                                 float* __restrict__ C, int M, int Nn, int K) {
  const int BM = 64, BN = 64, BK = 16;
  __shared__ float As[BK][BM + 1];
  __shared__ float Bs[BK][BN + 1];
  int bm = blockIdx.y * BM, bn = blockIdx.x * BN;
  int tid = threadIdx.x;
  int tr = tid / 16, tc = tid % 16;
  float acc[4][4] = {};
  for (int k0 = 0; k0 < K; k0 += BK) {
    for (int i = tid; i < BM * BK; i += 256) {
      int m = i / BK, k = i % BK;
      float v = 0.f;
      if (k0 + k < K) {
        v = A[(size_t)(bm + m) * K + k0 + k];
        if (scA) v = fmaf(v, scA[k0 + k], shA[k0 + k]);
      }
      As[k][m] = v;
    }
    for (int i = tid; i < BN * BK; i += 256) {
      int n = i / BK, k = i % BK;
      float v = 0.f;
      if (k0 + k < K) v = Bw[(size_t)(bn + n) * K + k0 + k];
      Bs[k][n] = v;
    }
    __syncthreads();
#pragma unroll
    for (int k = 0; k < BK; k++) {
      float a4[4], b4[4];
#pragma unroll
      for (int xx = 0; xx < 4; xx++) a4[xx] = As[k][tr * 4 + xx];
#pragma unroll
      for (int yy = 0; yy < 4; yy++) b4[yy] = Bs[k][tc * 4 + yy];
#pragma unroll
      for (int xx = 0; xx < 4; xx++)
#pragma unroll
        for (int yy = 0; yy < 4; yy++) acc[xx][yy] = fmaf(a4[xx], b4[yy], acc[xx][yy]);
    }
    __syncthreads();
  }
  for (int xx = 0; xx < 4; xx++) {
    int m = bm + tr * 4 + xx;
    for (int yy = 0; yy < 4; yy++) {
      int n = bn + tc * 4 + yy;
      float v = acc[xx][yy] + bias[n];
      if (RELU) v = fmaxf(v, 0.f);
      C[(size_t)m * Nn + n] = v;
    }
  }
}

__global__ __launch_bounds__(256) void colstats_kernel(const float* __restrict__ X, int M, int C,
                                                       float* __restrict__ sum, float* __restrict__ sumsq) {
  int cl = threadIdx.x & 63, rl = threadIdx.x >> 6;
  int c = blockIdx.x * 64 + cl;
  float s = 0.f, q = 0.f;
  int r0 = blockIdx.y * 256;
  int rend = min(r0 + 256, M);
  for (int r = r0 + rl; r < rend; r += 4) {
    float v = X[(size_t)r * C + c];
    s += v;
    q = fmaf(v, v, q);
  }
  __shared__ float ss[4][64];
  __shared__ float qq[4][64];
  ss[rl][cl] = s;
  qq[rl][cl] = q;
  __syncthreads();
  if (rl == 0) {
    s = ss[0][cl] + ss[1][cl] + ss[2][cl] + ss[3][cl];
    q = qq[0][cl] + qq[1][cl] + qq[2][cl] + qq[3][cl];
    atomicAdd(&sum[c], s);
    atomicAdd(&sumsq[c], q);
  }
}

__global__ __launch_bounds__(256) void bn_coef_kernel(const float* __restrict__ sum, const float* __restrict__ sumsq,
                                                      const float* __restrict__ g, const float* __restrict__ be,
                                                      float* __restrict__ a, float* __restrict__ b, int C, float invM) {
  int c = blockIdx.x * blockDim.x + threadIdx.x;
  if (c >= C) return;
  float mu = sum[c] * invM;
  float var = sumsq[c] * invM - mu * mu;
  float s = g[c] * rsqrtf(var + 1e-5f);
  a[c] = s;
  b[c] = be[c] - mu * s;
}

__global__ __launch_bounds__(256) void head_kernel(const float* __restrict__ pooled,
                                                   const float* __restrict__ m3, const float* __restrict__ a3,
                                                   const float* __restrict__ b3, const float* __restrict__ Wout,
                                                   const float* __restrict__ bout, float* __restrict__ out, int B) {
  int b = blockIdx.x * blockDim.x + threadIdx.x;
  if (b >= B) return;
  float acc = bout[0];
#pragma unroll
  for (int j = 0; j < 32; j++) acc = fmaf(pooled[(size_t)b * 32 + j], Wout[j], acc);
#pragma unroll
  for (int j = 0; j < 64; j++) acc = fmaf(fmaf(m3[(size_t)b * 64 + j], a3[j], b3[j]), Wout[32 + j], acc);
  out[b] = 1.f / (1.f + expf(-acc));
}

extern "C" void kernel_launch(void* const* d_in, const int* in_sizes, int n_in,
                              void* d_out, int out_size, void* d_ws, size_t ws_size,
                              hipStream_t stream) {
  const float* x = (const float*)d_in[0];
  const int* eidx = (const int*)d_in[1];
  const int* batch = (const int*)d_in[2];
  const float* xmord = (const float*)d_in[3];
  const float* Wl1 = (const float*)d_in[4];
  const float* bl1 = (const float*)d_in[5];
  const float* Wr1 = (const float*)d_in[6];
  const float* Wl2 = (const float*)d_in[7];
  const float* bl2 = (const float*)d_in[8];
  const float* Wr2 = (const float*)d_in[9];
  const float* Wl3 = (const float*)d_in[10];
  const float* bl3 = (const float*)d_in[11];
  const float* Wr3 = (const float*)d_in[12];
  const float* Wf1 = (const float*)d_in[13];
  const float* bf1 = (const float*)d_in[14];
  const float* g1 = (const float*)d_in[15];
  const float* be1 = (const float*)d_in[16];
  const float* Wf2 = (const float*)d_in[17];
  const float* bf2 = (const float*)d_in[18];
  const float* g2 = (const float*)d_in[19];
  const float* be2 = (const float*)d_in[20];
  const float* Wf3 = (const float*)d_in[21];
  const float* bf3 = (const float*)d_in[22];
  const float* g3 = (const float*)d_in[23];
  const float* be3 = (const float*)d_in[24];
  const float* Wout = (const float*)d_in[25];
  const float* bout = (const float*)d_in[26];
  float* out = (float*)d_out;

  const int N = in_sizes[2];
  const int E = in_sizes[1] / 2;
  const int B = in_sizes[3] / MORD;
  const int nbins = (N + 1023) >> 10;
  const int* src = eidx;
  const int* dst = eidx + E;

  char* ws = (char*)d_ws;
  size_t off_ = 0;
  auto alloc = [&](size_t bytes) { size_t o = off_; off_ += (bytes + 255) & ~(size_t)255; return o; };
  size_t oHX1 = alloc((size_t)N * 64 * 2);
  size_t oHX2 = alloc((size_t)N * 64 * 2);
  size_t oHX3 = alloc((size_t)N * 64 * 2);
  size_t oOff = alloc((size_t)(N + 1) * 4);
  size_t oCsr = alloc((size_t)E * 4);
  size_t oEbuf = alloc((size_t)E * 8);
  size_t oGoff = alloc((size_t)(B + 1) * 4);
  size_t oPool = alloc((size_t)B * 32 * 4);
  size_t oStats = alloc(8192 * 4);
  size_t oWc1 = alloc(352 * 64 * 2);
  size_t oWc2 = alloc(352 * 64 * 2);
  size_t oWc3 = alloc(352 * 64 * 2);
  (void)ws_size;

  unsigned short* hx1 = (unsigned short*)(ws + oHX1);
  unsigned short* hx2 = (unsigned short*)(ws + oHX2);
  unsigned short* hx3 = (unsigned short*)(ws + oHX3);
  float* H3 = (float*)(ws + oHX1);
  int* offp = (int*)(ws + oOff);
  int* csr = (int*)(ws + oCsr);
  unsigned long long* ebuf = (unsigned long long*)(ws + oEbuf);
  int* goff = (int*)(ws + oGoff);
  float* pooled = (float*)(ws + oPool);
  float* st = (float*)(ws + oStats);
  int* bhist = (int*)(st + 4096);
  int* boff = (int*)(st + 4608);
  int* gcur = (int*)(st + 5184);
  unsigned short* Wc1 = (unsigned short*)(ws + oWc1);
  unsigned short* Wc2 = (unsigned short*)(ws + oWc2);
  unsigned short* Wc3 = (unsigned short*)(ws + oWc3);
  float *s1 = st, *q1 = st + 512, *a1 = st + 1024, *h1 = st + 1536;
  float *s2 = st + 2048, *q2 = st + 2176, *a2 = st + 2304, *h2 = st + 2432;
  float *s3 = st + 2560, *q3 = st + 2624, *a3 = st + 2688, *h3 = st + 2752;

  unsigned short* W2p = (unsigned short*)(ws + oHX2);
  float* b2p = (float*)(ws + oHX2 + 131072);
  unsigned short* m1 = (unsigned short*)(ws + oHX3);
  float* m2 = (float*)(ws + oHX3 + 16777216);
  float* m3 = (float*)(ws + oHX3 + 25165824);

  hipMemsetAsync(st, 0, 4608 * 4, stream);

  // Binned CSR build
  bin_hist<<<400, 256, 0, stream>>>(dst, bhist, E, nbins);
  bin_scan<<<1, 512, 0, stream>>>(bhist, boff, gcur, nbins, E);
  bin_split<<<400, 256, 0, stream>>>(src, dst, gcur, ebuf, E, nbins);
  bin_csr<<<nbins, 256, 0, stream>>>(ebuf, boff, offp, csr, N, E);
  graph_off<<<(B + 1 + 255) / 256, 256, 0, stream>>>(batch, goff, N, B);
  prep_wcat3<<<dim3(88, 3), 256, 0, stream>>>(Wl1, Wr1, Wc1, Wl2, Wr2, Wc2, Wl3, Wr3, Wc3);

  // GNN layers
  prep_hx1<<<(N + 255) / 256, 256, 0, stream>>>(x, offp, csr, hx1, N);
  mfconv_mfma<1, 4, 0><<<512, 512, 0, stream>>>(hx1, Wc1, bl1, offp, hx2, N);
  gather_bf16<<<(int)(((long long)N * 4 + 255) / 256), 256, 0, stream>>>(hx2, offp, csr, hx2, N);
  mfconv_mfma<2, 8, 0><<<512, 512, 0, stream>>>(hx2, Wc2, bl2, offp, hx3, N);
  gather_bf16<<<(int)(((long long)N * 4 + 255) / 256), 256, 0, stream>>>(hx3, offp, csr, hx3, N);
  mfconv_mfma<2, 8, 1><<<512, 512, 0, stream>>>(hx3, Wc3, bl3, offp, H3, N);

  pool_seg<<<(B * 64 + 255) / 256, 256, 0, stream>>>(H3, goff, pooled, B);

  // ---- MLP head ----
  gemm_fc1<<<dim3(4, B / 64), 256, 0, stream>>>(xmord, Wf1, bf1, m1, s1, q1, B, 512);
  bn_coef_kernel<<<2, 256, 0, stream>>>(s1, q1, g1, be1, a1, h1, 512, 1.f / B);

  prepW2_kernel<<<32, 256, 0, stream>>>(Wf2, bf2, a1, h1, W2p, b2p, 128, 512);
  gemm_mfma<0><<<dim3(1, B / 128), 256, 0, stream>>>(m1, W2p, b2p, m2, B, 128, 512);
  colstats_kernel<<<dim3(2, B / 256), 256, 0, stream>>>(m2, B, 128, s2, q2);
  bn_coef_kernel<<<1, 256, 0, stream>>>(s2, q2, g2, be2, a2, h2, 128, 1.f / B);

  gemm_bias<true><<<dim3(1, B / 64), 256, 0, stream>>>(m2, Wf3, bf3, a2, h2, m3, B, 64, 128);
  colstats_kernel<<<dim3(1, B / 256), 256, 0, stream>>>(m3, B, 64, s3, q3);
  bn_coef_kernel<<<1, 256, 0, stream>>>(s3, q3, g3, be3, a3, h3, 64, 1.f / B);

  head_kernel<<<(B + 255) / 256, 256, 0, stream>>>(pooled, m3, a3, h3, Wout, bout, out, B);
}

// Round 10
// 386.765 us; speedup vs baseline: 1.0929x; 1.0929x over previous
//
#include <hip/hip_runtime.h>
#include <hip/hip_bf16.h>
#include <math.h>

#define MORD 862

typedef short s16x8 __attribute__((ext_vector_type(8)));
typedef float f32x4 __attribute__((ext_vector_type(4)));

static __device__ __forceinline__ unsigned short f2bf(float v) {
  __hip_bfloat16 h = __float2bfloat16(v);
  return *(unsigned short*)&h;
}

// ---- Binned CSR build ----
__global__ __launch_bounds__(256) void bin_hist(const int* __restrict__ dstA, int* __restrict__ bhist, int E, int nbins) {
  __shared__ int lh[512];
  for (int i = threadIdx.x; i < nbins; i += 256) lh[i] = 0;
  __syncthreads();
  for (int e = blockIdx.x * 256 + threadIdx.x; e < E; e += gridDim.x * 256)
    atomicAdd(&lh[dstA[e] >> 10], 1);
  __syncthreads();
  for (int i = threadIdx.x; i < nbins; i += 256)
    if (lh[i]) atomicAdd(&bhist[i], lh[i]);
}

__global__ __launch_bounds__(512) void bin_scan(const int* __restrict__ bhist, int* __restrict__ boff,
                                                int* __restrict__ gcur, int nbins, int E) {
  __shared__ int ts[512];
  int tid = threadIdx.x;
  int v = (tid < nbins) ? bhist[tid] : 0;
  ts[tid] = v;
  __syncthreads();
  for (int st = 1; st < 512; st <<= 1) {
    int t = (tid >= st) ? ts[tid - st] : 0;
    __syncthreads();
    ts[tid] += t;
    __syncthreads();
  }
  int ex = ts[tid] - v;
  if (tid < nbins) { boff[tid] = ex; gcur[tid] = ex; }
  if (tid == 0) boff[nbins] = E;
}

__global__ __launch_bounds__(256) void bin_split(const int* __restrict__ srcA, const int* __restrict__ dstA,
                                                 int* __restrict__ gcur, unsigned long long* __restrict__ ebuf,
                                                 int E, int nbins) {
  __shared__ unsigned long long sbuf[512 * 8];
  __shared__ int lcur[512];
  int tid = threadIdx.x;
  for (int base = blockIdx.x * 1024; base < E; base += (int)gridDim.x * 1024) {
    for (int i = tid; i < nbins; i += 256) lcur[i] = 0;
    __syncthreads();
    int e0 = base + tid * 4;
#pragma unroll
    for (int j = 0; j < 4; j++) {
      int e = e0 + j;
      if (e < E) {
        int d = dstA[e], s = srcA[e];
        int bin = d >> 10;
        unsigned long long p = ((unsigned long long)(unsigned int)d << 32) | (unsigned int)s;
        int slot = atomicAdd(&lcur[bin], 1);
        if (slot < 8) sbuf[bin * 8 + slot] = p;
        else { int g = atomicAdd(&gcur[bin], 1); ebuf[g] = p; }
      }
    }
    __syncthreads();
    for (int b = tid; b < nbins; b += 256) {
      int cnt = min(lcur[b], 8);
      if (cnt > 0) {
        int g = atomicAdd(&gcur[b], cnt);
        for (int k = 0; k < cnt; k++) ebuf[g + k] = sbuf[b * 8 + k];
      }
    }
    __syncthreads();
  }
}

__global__ __launch_bounds__(256) void bin_csr(const unsigned long long* __restrict__ ebuf,
                                               const int* __restrict__ boff,
                                               int* __restrict__ off, int* __restrict__ csr,
                                               int N, int E) {
  __shared__ int lcur[1024];
  __shared__ int part[256];
  int b = blockIdx.x;
  int n0 = b << 10;
  int nn = min(1024, N - n0);
  int e0 = boff[b], e1 = boff[b + 1];
  int tid = threadIdx.x;
  for (int i = tid; i < nn; i += 256) lcur[i] = 0;
  __syncthreads();
  for (int e = e0 + tid; e < e1; e += 256) {
    int d = (int)(ebuf[e] >> 32);
    atomicAdd(&lcur[d - n0], 1);
  }
  __syncthreads();
  int base4 = tid * 4;
  int c0 = (base4 < nn) ? lcur[base4] : 0;
  int c1 = (base4 + 1 < nn) ? lcur[base4 + 1] : 0;
  int c2 = (base4 + 2 < nn) ? lcur[base4 + 2] : 0;
  int c3 = (base4 + 3 < nn) ? lcur[base4 + 3] : 0;
  int tot = c0 + c1 + c2 + c3;
  part[tid] = tot;
  __syncthreads();
  for (int st = 1; st < 256; st <<= 1) {
    int t = (tid >= st) ? part[tid - st] : 0;
    __syncthreads();
    part[tid] += t;
    __syncthreads();
  }
  int pre = part[tid] - tot;
  __syncthreads();
  if (base4 < nn)     { lcur[base4]     = pre;                off[n0 + base4]     = e0 + pre; }
  if (base4 + 1 < nn) { lcur[base4 + 1] = pre + c0;           off[n0 + base4 + 1] = e0 + pre + c0; }
  if (base4 + 2 < nn) { lcur[base4 + 2] = pre + c0 + c1;      off[n0 + base4 + 2] = e0 + pre + c0 + c1; }
  if (base4 + 3 < nn) { lcur[base4 + 3] = pre + c0 + c1 + c2; off[n0 + base4 + 3] = e0 + pre + c0 + c1 + c2; }
  if (b == 0 && tid == 0) off[N] = E;
  __syncthreads();
  for (int e = e0 + tid; e < e1; e += 256) {
    unsigned long long p = ebuf[e];
    int d = (int)(p >> 32);
    int s = (int)(p & 0xffffffffu);
    int slot = atomicAdd(&lcur[d - n0], 1);
    csr[e0 + slot] = s;
  }
}

__global__ __launch_bounds__(256) void graph_off(const int* __restrict__ batch, int* __restrict__ goff, int N, int B) {
  int b = blockIdx.x * blockDim.x + threadIdx.x;
  if (b > B) return;
  int lo = 0, hi = N;
  while (lo < hi) {
    int mid = (lo + hi) >> 1;
    if (batch[mid] < b) lo = mid + 1; else hi = mid;
  }
  goff[b] = lo;
}

__global__ __launch_bounds__(256) void prep_wcat3(const float* __restrict__ Wl1, const float* __restrict__ Wr1,
                                                  unsigned short* __restrict__ Wc1,
                                                  const float* __restrict__ Wl2, const float* __restrict__ Wr2,
                                                  unsigned short* __restrict__ Wc2,
                                                  const float* __restrict__ Wl3, const float* __restrict__ Wr3,
                                                  unsigned short* __restrict__ Wc3) {
  int set = blockIdx.y;
  const float* Wl = set == 0 ? Wl1 : (set == 1 ? Wl2 : Wl3);
  const float* Wr = set == 0 ? Wr1 : (set == 1 ? Wr2 : Wr3);
  unsigned short* Wc = set == 0 ? Wc1 : (set == 1 ? Wc2 : Wc3);
  int CIN = set == 0 ? 8 : 32;
  int idx = blockIdx.x * 256 + threadIdx.x;
  if (idx >= 352 * 64) return;
  int row = idx >> 6, k = idx & 63;
  int d = row >> 5, o = row & 31;
  float v = 0.f;
  if (k < CIN) v = Wl[((size_t)d * 32 + o) * CIN + k];
  else if (k < 2 * CIN) v = Wr[((size_t)d * 32 + o) * CIN + (k - CIN)];
  Wc[idx] = f2bf(v);
}

// hx1[n][32] bf16: 0-7 = neighbor-sum(x), 8-15 = x, 16-31 zero
__global__ __launch_bounds__(256) void prep_hx1(const float* __restrict__ x, const int* __restrict__ off,
                                                const int* __restrict__ csr, unsigned short* __restrict__ hx1, int N) {
  int n = blockIdx.x * 256 + threadIdx.x;
  if (n >= N) return;
  int a = off[n], b = off[n + 1];
  float ag[8] = {};
  for (int j = a; j < b; j++) {
    const float* xr = x + (size_t)csr[j] * 8;
#pragma unroll
    for (int t = 0; t < 8; t++) ag[t] += xr[t];
  }
  const float* xo = x + (size_t)n * 8;
  unsigned short* d = hx1 + (size_t)n * 32;
  s16x8 w0, w1, z;
#pragma unroll
  for (int t = 0; t < 8; t++) {
    w0[t] = (short)f2bf(ag[t]);
    w1[t] = (short)f2bf(xo[t]);
    z[t] = 0;
  }
  *(s16x8*)(d) = w0;
  *(s16x8*)(d + 8) = w1;
  *(s16x8*)(d + 16) = z;
  *(s16x8*)(d + 24) = z;
}

__global__ __launch_bounds__(256) void gather_bf16(const unsigned short* __restrict__ hx, const int* __restrict__ off,
                                                   const int* __restrict__ csr, unsigned short* __restrict__ hxw, int N) {
  long long tid = (long long)blockIdx.x * 256 + threadIdx.x;
  if (tid >= (long long)N * 4) return;
  int n = (int)(tid >> 2), q = (int)(tid & 3);
  int a = off[n], b = off[n + 1];
  float s[8] = {};
  for (int j = a; j < b; j++) {
    const s16x8 v = *(const s16x8*)(hx + (size_t)csr[j] * 64 + 32 + q * 8);
#pragma unroll
    for (int t = 0; t < 8; t++) {
      unsigned int u = ((unsigned int)(unsigned short)v[t]) << 16;
      s[t] += *(float*)&u;
    }
  }
  s16x8 w;
#pragma unroll
  for (int t = 0; t < 8; t++) w[t] = (short)f2bf(s[t]);
  *(s16x8*)(hxw + (size_t)n * 64 + q * 8) = w;
}

// MFMA all-degree transform. ACH = 16B chunks per A row.
template <int KS, int ACH, int OUTMODE>
__global__ __launch_bounds__(512, 4) void mfconv_mfma(const unsigned short* __restrict__ hx,
                                                      const unsigned short* __restrict__ Wcat,
                                                      const float* __restrict__ bl,
                                                      const int* __restrict__ off,
                                                      void* __restrict__ outp, int N) {
  __shared__ __align__(16) unsigned short As[128 * ACH * 8];
  __shared__ __align__(16) unsigned short Bs[352 * 64];
  __shared__ float sbias[352];
  __shared__ int sdeg[128];
  const int tid = threadIdx.x;
  const int wid = tid >> 6, lane = tid & 63;

  for (int s = wid; s < 44; s += 8) {
    int c = s * 64 + lane;
    int cs = c ^ ((c >> 3) & 7);
    __builtin_amdgcn_global_load_lds((const __attribute__((address_space(1))) void*)((const char*)Wcat + (size_t)cs * 16),
                                     (__attribute__((address_space(3))) void*)((char*)Bs + s * 1024), 16, 0, 0);
  }
  for (int i = tid; i < 352; i += 512) sbias[i] = bl[i];

  const int ntiles = N >> 7;
  for (int t = blockIdx.x; t < ntiles; t += (int)gridDim.x) {
    const int row0 = t << 7;
    __syncthreads();
    const char* Abase = (const char*)hx + (size_t)row0 * ACH * 16;
    for (int s = wid; s < 2 * ACH; s += 8) {
      int c = s * 64 + lane;
      int row = c / ACH, ch = c & (ACH - 1);
      int cs = row * ACH + (ch ^ (row & (ACH - 1)));
      __builtin_amdgcn_global_load_lds((const __attribute__((address_space(1))) void*)(Abase + (size_t)cs * 16),
                                       (__attribute__((address_space(3))) void*)((char*)As + s * 1024), 16, 0, 0);
    }
    if (tid < 128) sdeg[tid] = min(off[row0 + tid + 1] - off[row0 + tid], 10);
    __syncthreads();

    const int ra = wid * 16 + (lane & 15);
    const int g4 = lane >> 4;
    const int rl0 = wid * 16 + g4 * 4;
    int dj[4];
#pragma unroll
    for (int j = 0; j < 4; j++) dj[j] = sdeg[rl0 + j];

#pragma unroll
    for (int h = 0; h < 2; h++) {
      f32x4 acc[11] = {};
#pragma unroll
      for (int kk = 0; kk < KS; kk++) {
        int cha = (kk * 4 + g4) ^ (ra & (ACH - 1));
        s16x8 af = *(const s16x8*)((const char*)As + (size_t)(ra * ACH + cha) * 16);
#pragma unroll
        for (int nn = 0; nn < 11; nn++) {
          int rb = (h * 11 + nn) * 16 + (lane & 15);
          int cb = rb * 8 + kk * 4 + g4;
          s16x8 bf = *(const s16x8*)((const char*)Bs + (size_t)(cb ^ (rb & 7)) * 16);
          acc[nn] = __builtin_amdgcn_mfma_f32_16x16x32_bf16(af, bf, acc[nn], 0, 0, 0);
        }
      }
#pragma unroll
      for (int nn = 0; nn < 11; nn++) {
        int n = h * 11 + nn;
        int dsel = n >> 1;
        int o = (n & 1) * 16 + (lane & 15);
        float bv = sbias[dsel * 32 + o];
#pragma unroll
        for (int j = 0; j < 4; j++) {
          if (dj[j] == dsel) {
            float v = acc[nn][j] + bv;
            size_t gr = (size_t)row0 + rl0 + j;
            if (OUTMODE == 0) {
              v = fmaxf(v, 0.f);
              ((unsigned short*)outp)[gr * 64 + 32 + o] = f2bf(v);
            } else {
              ((float*)outp)[gr * 32 + o] = v;
            }
          }
        }
      }
    }
  }
}

__global__ __launch_bounds__(256) void pool_seg(const float* __restrict__ h, const int* __restrict__ goff,
                                                float* __restrict__ pooled, int B) {
  int w = (int)((blockIdx.x * 256 + threadIdx.x) >> 6);
  if (w >= B) return;
  int lane = threadIdx.x & 63;
  int c = lane & 31, r2 = lane >> 5;
  int a = goff[w], b = goff[w + 1];
  float s = 0.f;
  for (int r = a + r2; r < b; r += 2) s += h[(size_t)r * 32 + c];
  s += __shfl_down(s, 32);
  if (r2 == 0) pooled[(size_t)w * 32 + c] = s / fmaxf((float)(b - a), 1.f);
}

// fp32 -> bf16 with K padding to Kp (zeros in pad)
__global__ __launch_bounds__(256) void cvt_bf16_pad(const float* __restrict__ src, unsigned short* __restrict__ dst,
                                                    int rows, int K, int Kp) {
  int t = blockIdx.x * blockDim.x + threadIdx.x;
  int q = Kp / 4;
  if (t >= rows * q) return;
  int r = t / q, c4 = (t % q) * 4;
#pragma unroll
  for (int j = 0; j < 4; j++) {
    int k = c4 + j;
    float v = (k < K) ? src[(size_t)r * K + k] : 0.f;
    dst[(size_t)r * Kp + k] = f2bf(v);
  }
}

// fc1: bf16-in MFMA GEMM, 128x128 tile, BK=64, global_load_lds; relu+bias -> bf16 out;
// colstats fused in epilogue.
__global__ __launch_bounds__(256) void gemm_fc1b(const unsigned short* __restrict__ A,
                                                 const unsigned short* __restrict__ Bw,
                                                 const float* __restrict__ bias,
                                                 unsigned short* __restrict__ Cout,
                                                 float* __restrict__ csum, float* __restrict__ csq,
                                                 int M, int Nn, int Kp) {
  __shared__ __align__(16) unsigned short As[128 * 64];
  __shared__ __align__(16) unsigned short Bs[128 * 64];
  __shared__ float scs[128], sqs[128];
  int tid = threadIdx.x;
  int wid = tid >> 6, lane = tid & 63;
  int m0 = blockIdx.y * 128, n0 = blockIdx.x * 128;
  int wr = wid >> 1, wc = wid & 1;
  f32x4 acc[4][4] = {};

  int srow_l = lane >> 3;
  int scol = (lane & 7) * 8;
  int aReadBase = ((wr * 64 + (lane & 15)) * 128) + ((lane >> 4) * 16);
  int bReadBase = ((wc * 64 + (lane & 15)) * 128) + ((lane >> 4) * 16);

  const unsigned short* Ablk = A + (size_t)m0 * Kp;
  const unsigned short* Bblk = Bw + (size_t)n0 * Kp;

  for (int k0 = 0; k0 < Kp; k0 += 64) {
#pragma unroll
    for (int i = 0; i < 4; i++) {
      int s = wid * 4 + i;
      int row = s * 8 + srow_l;
      const unsigned short* ga = Ablk + (size_t)row * Kp + k0 + scol;
      const unsigned short* gb = Bblk + (size_t)row * Kp + k0 + scol;
      __builtin_amdgcn_global_load_lds((const __attribute__((address_space(1))) void*)ga,
                                       (__attribute__((address_space(3))) void*)(As + s * 512), 16, 0, 0);
      __builtin_amdgcn_global_load_lds((const __attribute__((address_space(1))) void*)gb,
                                       (__attribute__((address_space(3))) void*)(Bs + s * 512), 16, 0, 0);
    }
    __syncthreads();
#pragma unroll
    for (int kk = 0; kk < 2; kk++) {
      s16x8 af[4], bfr[4];
#pragma unroll
      for (int m = 0; m < 4; m++)
        af[m] = *(const s16x8*)((const char*)As + aReadBase + m * (16 * 128) + kk * 64);
#pragma unroll
      for (int n = 0; n < 4; n++)
        bfr[n] = *(const s16x8*)((const char*)Bs + bReadBase + n * (16 * 128) + kk * 64);
#pragma unroll
      for (int m = 0; m < 4; m++)
#pragma unroll
        for (int n = 0; n < 4; n++)
          acc[m][n] = __builtin_amdgcn_mfma_f32_16x16x32_bf16(af[m], bfr[n], acc[m][n], 0, 0, 0);
    }
    __syncthreads();
  }

  if (tid < 128) { scs[tid] = 0.f; sqs[tid] = 0.f; }
  __syncthreads();
  int rbase = m0 + wr * 64 + (lane >> 4) * 4;
  int lc = lane & 15;
#pragma unroll
  for (int n = 0; n < 4; n++) {
    int colb = wc * 64 + n * 16 + lc;
    float bv = bias[n0 + colb];
    float s = 0.f, q = 0.f;
#pragma unroll
    for (int m = 0; m < 4; m++) {
#pragma unroll
      for (int j = 0; j < 4; j++) {
        int row = rbase + m * 16 + j;
        float v = fmaxf(acc[m][n][j] + bv, 0.f);
        Cout[(size_t)row * Nn + n0 + colb] = f2bf(v);
        s += v;
        q = fmaf(v, v, q);
      }
    }
    s += __shfl_xor(s, 16); q += __shfl_xor(q, 16);
    s += __shfl_xor(s, 32); q += __shfl_xor(q, 32);
    if ((lane >> 4) == 0) { atomicAdd(&scs[colb], s); atomicAdd(&sqs[colb], q); }
  }
  __syncthreads();
  if (tid < 128) { atomicAdd(&csum[n0 + tid], scs[tid]); atomicAdd(&csq[n0 + tid], sqs[tid]); }
}

__global__ __launch_bounds__(256) void prepW2_kernel(const float* __restrict__ W2, const float* __restrict__ b2,
                                                     const float* __restrict__ a1, const float* __restrict__ h1,
                                                     unsigned short* __restrict__ W2p, float* __restrict__ b2p,
                                                     int Nn, int K) {
  int wid = threadIdx.x >> 6, lane = threadIdx.x & 63;
  int n = blockIdx.x * 4 + wid;
  if (n >= Nn) return;
  float part = 0.f;
  for (int k = lane; k < K; k += 64) {
    float w = W2[(size_t)n * K + k];
    W2p[(size_t)n * K + k] = f2bf(w * a1[k]);
    part = fmaf(w, h1[k], part);
  }
#pragma unroll
  for (int off = 32; off > 0; off >>= 1) part += __shfl_down(part, off, 64);
  if (lane == 0) b2p[n] = b2[n] + part;
}

// bf16 MFMA GEMM (fc2)
template <int OUTBF16>
__global__ __launch_bounds__(256) void gemm_mfma(const unsigned short* __restrict__ A,
                                                 const unsigned short* __restrict__ Bw,
                                                 const float* __restrict__ bias,
                                                 void* __restrict__ Cout, int M, int Nn, int Kp) {
  __shared__ __align__(16) unsigned short As[128 * 64];
  __shared__ __align__(16) unsigned short Bs[128 * 64];
  int tid = threadIdx.x;
  int wid = tid >> 6, lane = tid & 63;
  int m0 = blockIdx.y * 128, n0 = blockIdx.x * 128;
  int wr = wid >> 1, wc = wid & 1;
  f32x4 acc[4][4] = {};

  int srow_l = lane >> 3;
  int scol = (lane & 7) * 8;
  int aReadBase = ((wr * 64 + (lane & 15)) * 128) + ((lane >> 4) * 16);
  int bReadBase = ((wc * 64 + (lane & 15)) * 128) + ((lane >> 4) * 16);

  const unsigned short* Ablk = A + (size_t)m0 * Kp;
  const unsigned short* Bblk = Bw + (size_t)n0 * Kp;

  for (int k0 = 0; k0 < Kp; k0 += 64) {
#pragma unroll
    for (int i = 0; i < 4; i++) {
      int s = wid * 4 + i;
      int row = s * 8 + srow_l;
      const unsigned short* ga = Ablk + (size_t)row * Kp + k0 + scol;
      const unsigned short* gb = Bblk + (size_t)row * Kp + k0 + scol;
      __builtin_amdgcn_global_load_lds((const __attribute__((address_space(1))) void*)ga,
                                       (__attribute__((address_space(3))) void*)(As + s * 512), 16, 0, 0);
      __builtin_amdgcn_global_load_lds((const __attribute__((address_space(1))) void*)gb,
                                       (__attribute__((address_space(3))) void*)(Bs + s * 512), 16, 0, 0);
    }
    __syncthreads();
#pragma unroll
    for (int kk = 0; kk < 2; kk++) {
      s16x8 af[4], bfr[4];
#pragma unroll
      for (int m = 0; m < 4; m++)
        af[m] = *(const s16x8*)((const char*)As + aReadBase + m * (16 * 128) + kk * 64);
#pragma unroll
      for (int n = 0; n < 4; n++)
        bfr[n] = *(const s16x8*)((const char*)Bs + bReadBase + n * (16 * 128) + kk * 64);
#pragma unroll
      for (int m = 0; m < 4; m++)
#pragma unroll
        for (int n = 0; n < 4; n++)
          acc[m][n] = __builtin_amdgcn_mfma_f32_16x16x32_bf16(af[m], bfr[n], acc[m][n], 0, 0, 0);
    }
    __syncthreads();
  }

  int rbase = m0 + wr * 64 + (lane >> 4) * 4;
  int cbase = n0 + wc * 64 + (lane & 15);
#pragma unroll
  for (int m = 0; m < 4; m++)
#pragma unroll
    for (int n = 0; n < 4; n++) {
      int col = cbase + n * 16;
      float bv = bias[col];
#pragma unroll
      for (int j = 0; j < 4; j++) {
        int row = rbase + m * 16 + j;
        float v = fmaxf(acc[m][n][j] + bv, 0.f);
        if (OUTBF16)
          ((unsigned short*)Cout)[(size_t)row * Nn + col] = f2bf(v);
        else
          ((float*)Cout)[(size_t)row * Nn + col] = v;
      }
    }
}

// fp32 fallback GEMM (fc3)
template <bool RELU>
__global__ __launch_bounds__(256) void gemm_bias(const float* __restrict__ A, const float* __restrict__ Bw,
                                                 const float* __restrict__ bias,
                                                 const float* __restrict__ scA, const float* __restrict__ shA,
                                                 float* __restrict__ C, int M, int Nn, int K) {
  const int BM = 64, BN = 64, BK = 16;
  __shared__ float As[BK][BM + 1];
  __shared__ float Bs[BK][BN + 1];
  int bm = blockIdx.y * BM, bn = blockIdx.x * BN;
  int tid = threadIdx.x;
  int tr = tid / 16, tc = tid % 16;
  float acc[4][4] = {};
  for (int k0 = 0; k0 < K; k0 += BK) {
    for (int i = tid; i < BM * BK; i += 256) {
      int m = i / BK, k = i % BK;
      float v = 0.f;
      if (k0 + k < K) {
        v = A[(size_t)(bm + m) * K + k0 + k];
        if (scA) v = fmaf(v, scA[k0 + k], shA[k0 + k]);
      }
      As[k][m] = v;
    }
    for (int i = tid; i < BN * BK; i += 256) {
      int n = i / BK, k = i % BK;
      float v = 0.f;
      if (k0 + k < K) v = Bw[(size_t)(bn + n) * K + k0 + k];
      Bs[k][n] = v;
    }
    __syncthreads();
#pragma unroll
    for (int k = 0; k < BK; k++) {
      float a4[4], b4[4];
#pragma unroll
      for (int xx = 0; xx < 4; xx++) a4[xx] = As[k][tr * 4 + xx];
#pragma unroll
      for (int yy = 0; yy < 4; yy++) b4[yy] = Bs[k][tc * 4 + yy];
#pragma unroll
      for (int xx = 0; xx < 4; xx++)
#pragma unroll
        for (int yy = 0; yy < 4; yy++) acc[xx][yy] = fmaf(a4[xx], b4[yy], acc[xx][yy]);
    }
    __syncthreads();
  }
  for (int xx = 0; xx < 4; xx++) {
    int m = bm + tr * 4 + xx;
    for (int yy = 0; yy < 4; yy++) {
      int n = bn + tc * 4 + yy;
      float v = acc[xx][yy] + bias[n];
      if (RELU) v = fmaxf(v, 0.f);
      C[(size_t)m * Nn + n] = v;
    }
  }
}

__global__ __launch_bounds__(256) void colstats_kernel(const float* __restrict__ X, int M, int C,
                                                       float* __restrict__ sum, float* __restrict__ sumsq) {
  int cl = threadIdx.x & 63, rl = threadIdx.x >> 6;
  int c = blockIdx.x * 64 + cl;
  float s = 0.f, q = 0.f;
  int r0 = blockIdx.y * 256;
  int rend = min(r0 + 256, M);
  for (int r = r0 + rl; r < rend; r += 4) {
    float v = X[(size_t)r * C + c];
    s += v;
    q = fmaf(v, v, q);
  }
  __shared__ float ss[4][64];
  __shared__ float qq[4][64];
  ss[rl][cl] = s;
  qq[rl][cl] = q;
  __syncthreads();
  if (rl == 0) {
    s = ss[0][cl] + ss[1][cl] + ss[2][cl] + ss[3][cl];
    q = qq[0][cl] + qq[1][cl] + qq[2][cl] + qq[3][cl];
    atomicAdd(&sum[c], s);
    atomicAdd(&sumsq[c], q);
  }
}

__global__ __launch_bounds__(256) void bn_coef_kernel(const float* __restrict__ sum, const float* __restrict__ sumsq,
                                                      const float* __restrict__ g, const float* __restrict__ be,
                                                      float* __restrict__ a, float* __restrict__ b, int C, float invM) {
  int c = blockIdx.x * blockDim.x + threadIdx.x;
  if (c >= C) return;
  float mu = sum[c] * invM;
  float var = sumsq[c] * invM - mu * mu;
  float s = g[c] * rsqrtf(var + 1e-5f);
  a[c] = s;
  b[c] = be[c] - mu * s;
}

__global__ __launch_bounds__(256) void head_kernel(const float* __restrict__ pooled,
                                                   const float* __restrict__ m3, const float* __restrict__ a3,
                                                   const float* __restrict__ b3, const float* __restrict__ Wout,
                                                   const float* __restrict__ bout, float* __restrict__ out, int B) {
  int b = blockIdx.x * blockDim.x + threadIdx.x;
  if (b >= B) return;
  float acc = bout[0];
#pragma unroll
  for (int j = 0; j < 32; j++) acc = fmaf(pooled[(size_t)b * 32 + j], Wout[j], acc);
#pragma unroll
  for (int j = 0; j < 64; j++) acc = fmaf(fmaf(m3[(size_t)b * 64 + j], a3[j], b3[j]), Wout[32 + j], acc);
  out[b] = 1.f / (1.f + expf(-acc));
}

extern "C" void kernel_launch(void* const* d_in, const int* in_sizes, int n_in,
                              void* d_out, int out_size, void* d_ws, size_t ws_size,
                              hipStream_t stream) {
  const float* x = (const float*)d_in[0];
  const int* eidx = (const int*)d_in[1];
  const int* batch = (const int*)d_in[2];
  const float* xmord = (const float*)d_in[3];
  const float* Wl1 = (const float*)d_in[4];
  const float* bl1 = (const float*)d_in[5];
  const float* Wr1 = (const float*)d_in[6];
  const float* Wl2 = (const float*)d_in[7];
  const float* bl2 = (const float*)d_in[8];
  const float* Wr2 = (const float*)d_in[9];
  const float* Wl3 = (const float*)d_in[10];
  const float* bl3 = (const float*)d_in[11];
  const float* Wr3 = (const float*)d_in[12];
  const float* Wf1 = (const float*)d_in[13];
  const float* bf1 = (const float*)d_in[14];
  const float* g1 = (const float*)d_in[15];
  const float* be1 = (const float*)d_in[16];
  const float* Wf2 = (const float*)d_in[17];
  const float* bf2 = (const float*)d_in[18];
  const float* g2 = (const float*)d_in[19];
  const float* be2 = (const float*)d_in[20];
  const float* Wf3 = (const float*)d_in[21];
  const float* bf3 = (const float*)d_in[22];
  const float* g3 = (const float*)d_in[23];
  const float* be3 = (const float*)d_in[24];
  const float* Wout = (const float*)d_in[25];
  const float* bout = (const float*)d_in[26];
  float* out = (float*)d_out;

  const int N = in_sizes[2];
  const int E = in_sizes[1] / 2;
  const int B = in_sizes[3] / MORD;
  const int Kp1 = 896;
  const int nbins = (N + 1023) >> 10;
  const int* src = eidx;
  const int* dst = eidx + E;

  char* ws = (char*)d_ws;
  size_t off_ = 0;
  auto alloc = [&](size_t bytes) { size_t o = off_; off_ += (bytes + 255) & ~(size_t)255; return o; };
  size_t oHX1 = alloc((size_t)N * 64 * 2);
  size_t oHX2 = alloc((size_t)N * 64 * 2);
  size_t oHX3 = alloc((size_t)N * 64 * 2);
  size_t oOff = alloc((size_t)(N + 1) * 4);
  size_t oCsr = alloc((size_t)E * 4);
  size_t oEbuf = alloc((size_t)E * 8);
  size_t oGoff = alloc((size_t)(B + 1) * 4);
  size_t oPool = alloc((size_t)B * 32 * 4);
  size_t oStats = alloc(8192 * 4);
  size_t oWc1 = alloc(352 * 64 * 2);
  size_t oWc2 = alloc(352 * 64 * 2);
  size_t oWc3 = alloc(352 * 64 * 2);
  (void)ws_size;

  unsigned short* hx1 = (unsigned short*)(ws + oHX1);
  unsigned short* hx2 = (unsigned short*)(ws + oHX2);
  unsigned short* hx3 = (unsigned short*)(ws + oHX3);
  float* H3 = (float*)(ws + oHX1);
  int* offp = (int*)(ws + oOff);
  int* csr = (int*)(ws + oCsr);
  unsigned long long* ebuf = (unsigned long long*)(ws + oEbuf);
  int* goff = (int*)(ws + oGoff);
  float* pooled = (float*)(ws + oPool);
  float* st = (float*)(ws + oStats);
  int* bhist = (int*)(st + 4096);
  int* boff = (int*)(st + 4608);
  int* gcur = (int*)(st + 5184);
  unsigned short* Wc1 = (unsigned short*)(ws + oWc1);
  unsigned short* Wc2 = (unsigned short*)(ws + oWc2);
  unsigned short* Wc3 = (unsigned short*)(ws + oWc3);
  float *s1 = st, *q1 = st + 512, *a1 = st + 1024, *h1 = st + 1536;
  float *s2 = st + 2048, *q2 = st + 2176, *a2 = st + 2304, *h2 = st + 2432;
  float *s3 = st + 2560, *q3 = st + 2624, *a3 = st + 2688, *h3 = st + 2752;

  // MLP overlays in hx2 region (free after mfconv2 consumes hx2):
  // Abf [16384,896]bf16 (29.36MB) | Bbf1 [512,896]bf16 | W2p [128,512]bf16 | b2p
  unsigned short* Abf = (unsigned short*)(ws + oHX2);
  unsigned short* Bbf1 = (unsigned short*)(ws + oHX2 + 29360128);
  unsigned short* W2p = (unsigned short*)(ws + oHX2 + 29360128 + 917504);
  float* b2p = (float*)(ws + oHX2 + 29360128 + 917504 + 131072);
  unsigned short* m1 = (unsigned short*)(ws + oHX3);
  float* m2 = (float*)(ws + oHX3 + 16777216);
  float* m3 = (float*)(ws + oHX3 + 25165824);

  hipMemsetAsync(st, 0, 4608 * 4, stream);

  // Binned CSR build
  bin_hist<<<400, 256, 0, stream>>>(dst, bhist, E, nbins);
  bin_scan<<<1, 512, 0, stream>>>(bhist, boff, gcur, nbins, E);
  bin_split<<<400, 256, 0, stream>>>(src, dst, gcur, ebuf, E, nbins);
  bin_csr<<<nbins, 256, 0, stream>>>(ebuf, boff, offp, csr, N, E);
  graph_off<<<(B + 1 + 255) / 256, 256, 0, stream>>>(batch, goff, N, B);
  prep_wcat3<<<dim3(88, 3), 256, 0, stream>>>(Wl1, Wr1, Wc1, Wl2, Wr2, Wc2, Wl3, Wr3, Wc3);

  // GNN layers
  prep_hx1<<<(N + 255) / 256, 256, 0, stream>>>(x, offp, csr, hx1, N);
  mfconv_mfma<1, 4, 0><<<512, 512, 0, stream>>>(hx1, Wc1, bl1, offp, hx2, N);
  gather_bf16<<<(int)(((long long)N * 4 + 255) / 256), 256, 0, stream>>>(hx2, offp, csr, hx2, N);
  mfconv_mfma<2, 8, 0><<<512, 512, 0, stream>>>(hx2, Wc2, bl2, offp, hx3, N);
  gather_bf16<<<(int)(((long long)N * 4 + 255) / 256), 256, 0, stream>>>(hx3, offp, csr, hx3, N);
  mfconv_mfma<2, 8, 1><<<512, 512, 0, stream>>>(hx3, Wc3, bl3, offp, H3, N);

  pool_seg<<<(B * 64 + 255) / 256, 256, 0, stream>>>(H3, goff, pooled, B);

  // ---- MLP head (round-7 split structure + fused colstats) ----
  cvt_bf16_pad<<<(B * (Kp1 / 4) + 255) / 256, 256, 0, stream>>>(xmord, Abf, B, MORD, Kp1);
  cvt_bf16_pad<<<(512 * (Kp1 / 4) + 255) / 256, 256, 0, stream>>>(Wf1, Bbf1, 512, MORD, Kp1);
  gemm_fc1b<<<dim3(4, B / 128), 256, 0, stream>>>(Abf, Bbf1, bf1, m1, s1, q1, B, 512, Kp1);
  bn_coef_kernel<<<2, 256, 0, stream>>>(s1, q1, g1, be1, a1, h1, 512, 1.f / B);

  prepW2_kernel<<<32, 256, 0, stream>>>(Wf2, bf2, a1, h1, W2p, b2p, 128, 512);
  gemm_mfma<0><<<dim3(1, B / 128), 256, 0, stream>>>(m1, W2p, b2p, m2, B, 128, 512);
  colstats_kernel<<<dim3(2, B / 256), 256, 0, stream>>>(m2, B, 128, s2, q2);
  bn_coef_kernel<<<1, 256, 0, stream>>>(s2, q2, g2, be2, a2, h2, 128, 1.f / B);

  gemm_bias<true><<<dim3(1, B / 64), 256, 0, stream>>>(m2, Wf3, bf3, a2, h2, m3, B, 64, 128);
  colstats_kernel<<<dim3(1, B / 256), 256, 0, stream>>>(m3, B, 64, s3, q3);
  bn_coef_kernel<<<1, 256, 0, stream>>>(s3, q3, g3, be3, a3, h3, 64, 1.f / B);

  head_kernel<<<(B + 255) / 256, 256, 0, stream>>>(pooled, m3, a3, h3, Wout, bout, out, B);
}

// Round 11
// 340.632 us; speedup vs baseline: 1.2409x; 1.1354x over previous
//
#include <hip/hip_runtime.h>
#include <hip/hip_bf16.h>
#include <math.h>

#define MORD 862

typedef short s16x8 __attribute__((ext_vector_type(8)));
typedef float f32x4 __attribute__((ext_vector_type(4)));

static __device__ __forceinline__ unsigned short f2bf(float v) {
  __hip_bfloat16 h = __float2bfloat16(v);
  return *(unsigned short*)&h;
}

// ---- Binned CSR build ----
__global__ __launch_bounds__(256) void bin_hist(const int* __restrict__ dstA, int* __restrict__ bhist, int E, int nbins) {
  __shared__ int lh[512];
  for (int i = threadIdx.x; i < nbins; i += 256) lh[i] = 0;
  __syncthreads();
  for (int e = blockIdx.x * 256 + threadIdx.x; e < E; e += gridDim.x * 256)
    atomicAdd(&lh[dstA[e] >> 10], 1);
  __syncthreads();
  for (int i = threadIdx.x; i < nbins; i += 256)
    if (lh[i]) atomicAdd(&bhist[i], lh[i]);
}

__global__ __launch_bounds__(512) void bin_scan(const int* __restrict__ bhist, int* __restrict__ boff,
                                                int* __restrict__ gcur, int nbins, int E) {
  __shared__ int ts[512];
  int tid = threadIdx.x;
  int v = (tid < nbins) ? bhist[tid] : 0;
  ts[tid] = v;
  __syncthreads();
  for (int st = 1; st < 512; st <<= 1) {
    int t = (tid >= st) ? ts[tid - st] : 0;
    __syncthreads();
    ts[tid] += t;
    __syncthreads();
  }
  int ex = ts[tid] - v;
  if (tid < nbins) { boff[tid] = ex; gcur[tid] = ex; }
  if (tid == 0) boff[nbins] = E;
}

__global__ __launch_bounds__(256) void bin_split(const int* __restrict__ srcA, const int* __restrict__ dstA,
                                                 int* __restrict__ gcur, unsigned long long* __restrict__ ebuf,
                                                 int E, int nbins) {
  __shared__ unsigned long long sbuf[512 * 8];
  __shared__ int lcur[512];
  int tid = threadIdx.x;
  for (int base = blockIdx.x * 1024; base < E; base += (int)gridDim.x * 1024) {
    for (int i = tid; i < nbins; i += 256) lcur[i] = 0;
    __syncthreads();
    int e0 = base + tid * 4;
#pragma unroll
    for (int j = 0; j < 4; j++) {
      int e = e0 + j;
      if (e < E) {
        int d = dstA[e], s = srcA[e];
        int bin = d >> 10;
        unsigned long long p = ((unsigned long long)(unsigned int)d << 32) | (unsigned int)s;
        int slot = atomicAdd(&lcur[bin], 1);
        if (slot < 8) sbuf[bin * 8 + slot] = p;
        else { int g = atomicAdd(&gcur[bin], 1); ebuf[g] = p; }
      }
    }
    __syncthreads();
    for (int b = tid; b < nbins; b += 256) {
      int cnt = min(lcur[b], 8);
      if (cnt > 0) {
        int g = atomicAdd(&gcur[b], cnt);
        for (int k = 0; k < cnt; k++) ebuf[g + k] = sbuf[b * 8 + k];
      }
    }
    __syncthreads();
  }
}

__global__ __launch_bounds__(256) void bin_csr(const unsigned long long* __restrict__ ebuf,
                                               const int* __restrict__ boff,
                                               int* __restrict__ off, int* __restrict__ csr,
                                               int N, int E) {
  __shared__ int lcur[1024];
  __shared__ int part[256];
  int b = blockIdx.x;
  int n0 = b << 10;
  int nn = min(1024, N - n0);
  int e0 = boff[b], e1 = boff[b + 1];
  int tid = threadIdx.x;
  for (int i = tid; i < nn; i += 256) lcur[i] = 0;
  __syncthreads();
  for (int e = e0 + tid; e < e1; e += 256) {
    int d = (int)(ebuf[e] >> 32);
    atomicAdd(&lcur[d - n0], 1);
  }
  __syncthreads();
  int base4 = tid * 4;
  int c0 = (base4 < nn) ? lcur[base4] : 0;
  int c1 = (base4 + 1 < nn) ? lcur[base4 + 1] : 0;
  int c2 = (base4 + 2 < nn) ? lcur[base4 + 2] : 0;
  int c3 = (base4 + 3 < nn) ? lcur[base4 + 3] : 0;
  int tot = c0 + c1 + c2 + c3;
  part[tid] = tot;
  __syncthreads();
  for (int st = 1; st < 256; st <<= 1) {
    int t = (tid >= st) ? part[tid - st] : 0;
    __syncthreads();
    part[tid] += t;
    __syncthreads();
  }
  int pre = part[tid] - tot;
  __syncthreads();
  if (base4 < nn)     { lcur[base4]     = pre;                off[n0 + base4]     = e0 + pre; }
  if (base4 + 1 < nn) { lcur[base4 + 1] = pre + c0;           off[n0 + base4 + 1] = e0 + pre + c0; }
  if (base4 + 2 < nn) { lcur[base4 + 2] = pre + c0 + c1;      off[n0 + base4 + 2] = e0 + pre + c0 + c1; }
  if (base4 + 3 < nn) { lcur[base4 + 3] = pre + c0 + c1 + c2; off[n0 + base4 + 3] = e0 + pre + c0 + c1 + c2; }
  if (b == 0 && tid == 0) off[N] = E;
  __syncthreads();
  for (int e = e0 + tid; e < e1; e += 256) {
    unsigned long long p = ebuf[e];
    int d = (int)(p >> 32);
    int s = (int)(p & 0xffffffffu);
    int slot = atomicAdd(&lcur[d - n0], 1);
    csr[e0 + slot] = s;
  }
}

// y=0..2: Wcat prep for the 3 layers; y=3: graph offsets (binary search)
__global__ __launch_bounds__(256) void wcat_goff(const float* __restrict__ Wl1, const float* __restrict__ Wr1,
                                                 unsigned short* __restrict__ Wc1,
                                                 const float* __restrict__ Wl2, const float* __restrict__ Wr2,
                                                 unsigned short* __restrict__ Wc2,
                                                 const float* __restrict__ Wl3, const float* __restrict__ Wr3,
                                                 unsigned short* __restrict__ Wc3,
                                                 const int* __restrict__ batch, int* __restrict__ goff, int N, int B) {
  int set = blockIdx.y;
  if (set == 3) {
    int b = blockIdx.x * 256 + threadIdx.x;
    if (b > B) return;
    int lo = 0, hi = N;
    while (lo < hi) {
      int mid = (lo + hi) >> 1;
      if (batch[mid] < b) lo = mid + 1; else hi = mid;
    }
    goff[b] = lo;
    return;
  }
  const float* Wl = set == 0 ? Wl1 : (set == 1 ? Wl2 : Wl3);
  const float* Wr = set == 0 ? Wr1 : (set == 1 ? Wr2 : Wr3);
  unsigned short* Wc = set == 0 ? Wc1 : (set == 1 ? Wc2 : Wc3);
  int CIN = set == 0 ? 8 : 32;
  int idx = blockIdx.x * 256 + threadIdx.x;
  if (idx >= 352 * 64) return;
  int row = idx >> 6, k = idx & 63;
  int d = row >> 5, o = row & 31;
  float v = 0.f;
  if (k < CIN) v = Wl[((size_t)d * 32 + o) * CIN + k];
  else if (k < 2 * CIN) v = Wr[((size_t)d * 32 + o) * CIN + (k - CIN)];
  Wc[idx] = f2bf(v);
}

// layer-1 prep: agg1[n][8] = neighbor-sum(x), x1[n][8] = bf16(x). Compact.
__global__ __launch_bounds__(256) void prep_hx1(const float* __restrict__ x, const int* __restrict__ off,
                                                const int* __restrict__ csr,
                                                unsigned short* __restrict__ x1, unsigned short* __restrict__ agg1, int N) {
  int n = blockIdx.x * 256 + threadIdx.x;
  if (n >= N) return;
  int a = off[n], b = off[n + 1];
  float ag[8] = {};
  for (int j = a; j < b; j++) {
    const float* xr = x + (size_t)csr[j] * 8;
#pragma unroll
    for (int t = 0; t < 8; t++) ag[t] += xr[t];
  }
  const float* xo = x + (size_t)n * 8;
  s16x8 w0, w1;
#pragma unroll
  for (int t = 0; t < 8; t++) {
    w0[t] = (short)f2bf(ag[t]);
    w1[t] = (short)f2bf(xo[t]);
  }
  *(s16x8*)(agg1 + (size_t)n * 8) = w0;
  *(s16x8*)(x1 + (size_t)n * 8) = w1;
}

// neighbor-sum over compact X[N][32] -> AGG[N][32]
__global__ __launch_bounds__(256) void gather_c(const unsigned short* __restrict__ X, const int* __restrict__ off,
                                                const int* __restrict__ csr, unsigned short* __restrict__ AGG, int N) {
  long long tid = (long long)blockIdx.x * 256 + threadIdx.x;
  if (tid >= (long long)N * 4) return;
  int n = (int)(tid >> 2), q = (int)(tid & 3);
  int a = off[n], b = off[n + 1];
  float s[8] = {};
  for (int j = a; j < b; j++) {
    const s16x8 v = *(const s16x8*)(X + (size_t)csr[j] * 32 + q * 8);
#pragma unroll
    for (int t = 0; t < 8; t++) {
      unsigned int u = ((unsigned int)(unsigned short)v[t]) << 16;
      s[t] += *(float*)&u;
    }
  }
  s16x8 w;
#pragma unroll
  for (int t = 0; t < 8; t++) w[t] = (short)f2bf(s[t]);
  *(s16x8*)(AGG + (size_t)n * 32 + q * 8) = w;
}

// MFMA all-degree transform. A rows = [agg(CIN) | x(CIN)] staged from two compact buffers.
// ACH = 16B chunks per A row (4 for CIN=8 w/ garbage pad vs zero B-cols; 8 for CIN=32).
template <int KS, int ACH, int OUTMODE>
__global__ __launch_bounds__(512, 4) void mfconv_mfma(const unsigned short* __restrict__ xin,
                                                      const unsigned short* __restrict__ agg,
                                                      const unsigned short* __restrict__ Wcat,
                                                      const float* __restrict__ bl,
                                                      const int* __restrict__ off,
                                                      void* __restrict__ outp, int N) {
  __shared__ __align__(16) unsigned short As[128 * ACH * 8];
  __shared__ __align__(16) unsigned short Bs[352 * 64];
  __shared__ float sbias[352];
  __shared__ int sdeg[128];
  const int tid = threadIdx.x;
  const int wid = tid >> 6, lane = tid & 63;

  for (int s = wid; s < 44; s += 8) {
    int c = s * 64 + lane;
    int cs = c ^ ((c >> 3) & 7);
    __builtin_amdgcn_global_load_lds((const __attribute__((address_space(1))) void*)((const char*)Wcat + (size_t)cs * 16),
                                     (__attribute__((address_space(3))) void*)((char*)Bs + s * 1024), 16, 0, 0);
  }
  for (int i = tid; i < 352; i += 512) sbias[i] = bl[i];

  const int ntiles = N >> 7;
  for (int t = blockIdx.x; t < ntiles; t += (int)gridDim.x) {
    const int row0 = t << 7;
    __syncthreads();
    for (int s = wid; s < 2 * ACH; s += 8) {
      int c = s * 64 + lane;
      int row = c / ACH, ch = c & (ACH - 1);
      int cs = ch ^ (row & (ACH - 1));
      size_t grow = (size_t)(row0 + row);
      const char* srcp;
      if (ACH == 4) {
        // row = [agg(8)|x(8)|pad(16)]; pad chunks read agg (garbage; B cols 16-63 are zero)
        srcp = (cs == 1) ? (const char*)xin + grow * 16 : (const char*)agg + grow * 16;
      } else {
        srcp = (cs < 4) ? (const char*)agg + grow * 64 + (size_t)cs * 16
                        : (const char*)xin + grow * 64 + (size_t)(cs - 4) * 16;
      }
      __builtin_amdgcn_global_load_lds((const __attribute__((address_space(1))) void*)srcp,
                                       (__attribute__((address_space(3))) void*)((char*)As + s * 1024), 16, 0, 0);
    }
    if (tid < 128) sdeg[tid] = min(off[row0 + tid + 1] - off[row0 + tid], 10);
    __syncthreads();

    const int ra = wid * 16 + (lane & 15);
    const int g4 = lane >> 4;
    const int rl0 = wid * 16 + g4 * 4;
    int dj[4];
#pragma unroll
    for (int j = 0; j < 4; j++) dj[j] = sdeg[rl0 + j];

#pragma unroll
    for (int h = 0; h < 2; h++) {
      f32x4 acc[11] = {};
#pragma unroll
      for (int kk = 0; kk < KS; kk++) {
        int cha = (kk * 4 + g4) ^ (ra & (ACH - 1));
        s16x8 af = *(const s16x8*)((const char*)As + (size_t)(ra * ACH + cha) * 16);
#pragma unroll
        for (int nn = 0; nn < 11; nn++) {
          int rb = (h * 11 + nn) * 16 + (lane & 15);
          int cb = rb * 8 + kk * 4 + g4;
          s16x8 bf = *(const s16x8*)((const char*)Bs + (size_t)(cb ^ (rb & 7)) * 16);
          acc[nn] = __builtin_amdgcn_mfma_f32_16x16x32_bf16(af, bf, acc[nn], 0, 0, 0);
        }
      }
#pragma unroll
      for (int nn = 0; nn < 11; nn++) {
        int n = h * 11 + nn;
        int dsel = n >> 1;
        int o = (n & 1) * 16 + (lane & 15);
        float bv = sbias[dsel * 32 + o];
#pragma unroll
        for (int j = 0; j < 4; j++) {
          if (dj[j] == dsel) {
            float v = acc[nn][j] + bv;
            size_t gr = (size_t)row0 + rl0 + j;
            if (OUTMODE == 0) {
              v = fmaxf(v, 0.f);
              ((unsigned short*)outp)[gr * 32 + o] = f2bf(v);
            } else {
              ((float*)outp)[gr * 32 + o] = v;
            }
          }
        }
      }
    }
  }
}

// fused A+W fp32->bf16 conversion (K padded 862->896)
__global__ __launch_bounds__(256) void cvt2(const float* __restrict__ xm, const float* __restrict__ Wf1,
                                            unsigned short* __restrict__ Abf, unsigned short* __restrict__ Bbf1, int B) {
  const int q = 224;
  int t = blockIdx.x * 256 + threadIdx.x;
  if (t >= (B + 512) * q) return;
  int r = t / q, c4 = (t % q) * 4;
  const float* srow = (r < B) ? xm + (size_t)r * MORD : Wf1 + (size_t)(r - B) * MORD;
  unsigned short* drow = (r < B) ? Abf + (size_t)r * 896 : Bbf1 + (size_t)(r - B) * 896;
#pragma unroll
  for (int j = 0; j < 4; j++) {
    int k = c4 + j;
    float v = (k < MORD) ? srow[k] : 0.f;
    drow[k] = f2bf(v);
  }
}

// fc1: bf16 MFMA GEMM 128x128 BK=64 global_load_lds; relu+bias -> bf16; fused colstats.
__global__ __launch_bounds__(256) void gemm_fc1b(const unsigned short* __restrict__ A,
                                                 const unsigned short* __restrict__ Bw,
                                                 const float* __restrict__ bias,
                                                 unsigned short* __restrict__ Cout,
                                                 float* __restrict__ csum, float* __restrict__ csq,
                                                 int M, int Nn, int Kp) {
  __shared__ __align__(16) unsigned short As[128 * 64];
  __shared__ __align__(16) unsigned short Bs[128 * 64];
  __shared__ float scs[128], sqs[128];
  int tid = threadIdx.x;
  int wid = tid >> 6, lane = tid & 63;
  int m0 = blockIdx.y * 128, n0 = blockIdx.x * 128;
  int wr = wid >> 1, wc = wid & 1;
  f32x4 acc[4][4] = {};

  int srow_l = lane >> 3;
  int scol = (lane & 7) * 8;
  int aReadBase = ((wr * 64 + (lane & 15)) * 128) + ((lane >> 4) * 16);
  int bReadBase = ((wc * 64 + (lane & 15)) * 128) + ((lane >> 4) * 16);

  const unsigned short* Ablk = A + (size_t)m0 * Kp;
  const unsigned short* Bblk = Bw + (size_t)n0 * Kp;

  for (int k0 = 0; k0 < Kp; k0 += 64) {
#pragma unroll
    for (int i = 0; i < 4; i++) {
      int s = wid * 4 + i;
      int row = s * 8 + srow_l;
      const unsigned short* ga = Ablk + (size_t)row * Kp + k0 + scol;
      const unsigned short* gb = Bblk + (size_t)row * Kp + k0 + scol;
      __builtin_amdgcn_global_load_lds((const __attribute__((address_space(1))) void*)ga,
                                       (__attribute__((address_space(3))) void*)(As + s * 512), 16, 0, 0);
      __builtin_amdgcn_global_load_lds((const __attribute__((address_space(1))) void*)gb,
                                       (__attribute__((address_space(3))) void*)(Bs + s * 512), 16, 0, 0);
    }
    __syncthreads();
#pragma unroll
    for (int kk = 0; kk < 2; kk++) {
      s16x8 af[4], bfr[4];
#pragma unroll
      for (int m = 0; m < 4; m++)
        af[m] = *(const s16x8*)((const char*)As + aReadBase + m * (16 * 128) + kk * 64);
#pragma unroll
      for (int n = 0; n < 4; n++)
        bfr[n] = *(const s16x8*)((const char*)Bs + bReadBase + n * (16 * 128) + kk * 64);
#pragma unroll
      for (int m = 0; m < 4; m++)
#pragma unroll
        for (int n = 0; n < 4; n++)
          acc[m][n] = __builtin_amdgcn_mfma_f32_16x16x32_bf16(af[m], bfr[n], acc[m][n], 0, 0, 0);
    }
    __syncthreads();
  }

  if (tid < 128) { scs[tid] = 0.f; sqs[tid] = 0.f; }
  __syncthreads();
  int rbase = m0 + wr * 64 + (lane >> 4) * 4;
  int lc = lane & 15;
#pragma unroll
  for (int n = 0; n < 4; n++) {
    int colb = wc * 64 + n * 16 + lc;
    float bv = bias[n0 + colb];
    float s = 0.f, q = 0.f;
#pragma unroll
    for (int m = 0; m < 4; m++) {
#pragma unroll
      for (int j = 0; j < 4; j++) {
        int row = rbase + m * 16 + j;
        float v = fmaxf(acc[m][n][j] + bv, 0.f);
        Cout[(size_t)row * Nn + n0 + colb] = f2bf(v);
        s += v;
        q = fmaf(v, v, q);
      }
    }
    s += __shfl_xor(s, 16); q += __shfl_xor(q, 16);
    s += __shfl_xor(s, 32); q += __shfl_xor(q, 32);
    if ((lane >> 4) == 0) { atomicAdd(&scs[colb], s); atomicAdd(&sqs[colb], q); }
  }
  __syncthreads();
  if (tid < 128) { atomicAdd(&csum[n0 + tid], scs[tid]); atomicAdd(&csq[n0 + tid], sqs[tid]); }
}

// prepW2 with BN1 folded (a1/h1 computed in-kernel from s1/q1)
__global__ __launch_bounds__(256) void prepW2_bn(const float* __restrict__ W2, const float* __restrict__ b2,
                                                 const float* __restrict__ s1, const float* __restrict__ q1,
                                                 const float* __restrict__ g1, const float* __restrict__ be1,
                                                 unsigned short* __restrict__ W2p, float* __restrict__ b2p,
                                                 int Nn, int K, float invM) {
  __shared__ float a1l[512], h1l[512];
  for (int c = threadIdx.x; c < K; c += 256) {
    float mu = s1[c] * invM;
    float var = q1[c] * invM - mu * mu;
    float sc = g1[c] * rsqrtf(var + 1e-5f);
    a1l[c] = sc;
    h1l[c] = be1[c] - mu * sc;
  }
  __syncthreads();
  int wid = threadIdx.x >> 6, lane = threadIdx.x & 63;
  int n = blockIdx.x * 4 + wid;
  if (n >= Nn) return;
  float part = 0.f;
  for (int k = lane; k < K; k += 64) {
    float w = W2[(size_t)n * K + k];
    W2p[(size_t)n * K + k] = f2bf(w * a1l[k]);
    part = fmaf(w, h1l[k], part);
  }
#pragma unroll
  for (int off = 32; off > 0; off >>= 1) part += __shfl_down(part, off, 64);
  if (lane == 0) b2p[n] = b2[n] + part;
}

// fc2: bf16 MFMA GEMM 128x128, f32 out, relu, fused colstats (grid x = 1)
__global__ __launch_bounds__(256) void gemm_fc2(const unsigned short* __restrict__ A,
                                                const unsigned short* __restrict__ Bw,
                                                const float* __restrict__ bias,
                                                float* __restrict__ Cout,
                                                float* __restrict__ csum, float* __restrict__ csq,
                                                int M, int Nn, int Kp) {
  __shared__ __align__(16) unsigned short As[128 * 64];
  __shared__ __align__(16) unsigned short Bs[128 * 64];
  __shared__ float scs[128], sqs[128];
  int tid = threadIdx.x;
  int wid = tid >> 6, lane = tid & 63;
  int m0 = blockIdx.y * 128;
  int wr = wid >> 1, wc = wid & 1;
  f32x4 acc[4][4] = {};

  int srow_l = lane >> 3;
  int scol = (lane & 7) * 8;
  int aReadBase = ((wr * 64 + (lane & 15)) * 128) + ((lane >> 4) * 16);
  int bReadBase = ((wc * 64 + (lane & 15)) * 128) + ((lane >> 4) * 16);

  const unsigned short* Ablk = A + (size_t)m0 * Kp;

  for (int k0 = 0; k0 < Kp; k0 += 64) {
#pragma unroll
    for (int i = 0; i < 4; i++) {
      int s = wid * 4 + i;
      int row = s * 8 + srow_l;
      const unsigned short* ga = Ablk + (size_t)row * Kp + k0 + scol;
      const unsigned short* gb = Bw + (size_t)row * Kp + k0 + scol;
      __builtin_amdgcn_global_load_lds((const __attribute__((address_space(1))) void*)ga,
                                       (__attribute__((address_space(3))) void*)(As + s * 512), 16, 0, 0);
      __builtin_amdgcn_global_load_lds((const __attribute__((address_space(1))) void*)gb,
                                       (__attribute__((address_space(3))) void*)(Bs + s * 512), 16, 0, 0);
    }
    __syncthreads();
#pragma unroll
    for (int kk = 0; kk < 2; kk++) {
      s16x8 af[4], bfr[4];
#pragma unroll
      for (int m = 0; m < 4; m++)
        af[m] = *(const s16x8*)((const char*)As + aReadBase + m * (16 * 128) + kk * 64);
#pragma unroll
      for (int n = 0; n < 4; n++)
        bfr[n] = *(const s16x8*)((const char*)Bs + bReadBase + n * (16 * 128) + kk * 64);
#pragma unroll
      for (int m = 0; m < 4; m++)
#pragma unroll
        for (int n = 0; n < 4; n++)
          acc[m][n] = __builtin_amdgcn_mfma_f32_16x16x32_bf16(af[m], bfr[n], acc[m][n], 0, 0, 0);
    }
    __syncthreads();
  }

  if (tid < 128) { scs[tid] = 0.f; sqs[tid] = 0.f; }
  __syncthreads();
  int rbase = m0 + wr * 64 + (lane >> 4) * 4;
  int lc = lane & 15;
#pragma unroll
  for (int n = 0; n < 4; n++) {
    int colb = wc * 64 + n * 16 + lc;
    float bv = bias[colb];
    float s = 0.f, q = 0.f;
#pragma unroll
    for (int m = 0; m < 4; m++) {
#pragma unroll
      for (int j = 0; j < 4; j++) {
        int row = rbase + m * 16 + j;
        float v = fmaxf(acc[m][n][j] + bv, 0.f);
        Cout[(size_t)row * Nn + colb] = v;
        s += v;
        q = fmaf(v, v, q);
      }
    }
    s += __shfl_xor(s, 16); q += __shfl_xor(q, 16);
    s += __shfl_xor(s, 32); q += __shfl_xor(q, 32);
    if ((lane >> 4) == 0) { atomicAdd(&scs[colb], s); atomicAdd(&sqs[colb], q); }
  }
  __syncthreads();
  if (tid < 128) { atomicAdd(&csum[tid], scs[tid]); atomicAdd(&csq[tid], sqs[tid]); }
}

// fc3: fp32 GEMM with BN2 applied to input (from s2/q2) + relu + fused colstats (s3/q3)
__global__ __launch_bounds__(256) void gemm_fc3(const float* __restrict__ A, const float* __restrict__ Bw,
                                                const float* __restrict__ bias,
                                                const float* __restrict__ s2v, const float* __restrict__ q2v,
                                                const float* __restrict__ g2, const float* __restrict__ be2,
                                                float* __restrict__ C, float* __restrict__ s3, float* __restrict__ q3,
                                                int M, float invM) {
  const int BM = 64, BN = 64, BK = 16, K = 128;
  __shared__ float As[BK][BM + 1];
  __shared__ float Bs[BK][BN + 1];
  __shared__ float a2l[128], h2l[128];
  __shared__ float scs[64], sqs[64];
  int tid = threadIdx.x;
  for (int c = tid; c < 128; c += 256) {
    float mu = s2v[c] * invM;
    float var = q2v[c] * invM - mu * mu;
    float sc = g2[c] * rsqrtf(var + 1e-5f);
    a2l[c] = sc;
    h2l[c] = be2[c] - mu * sc;
  }
  if (tid < 64) { scs[tid] = 0.f; sqs[tid] = 0.f; }
  __syncthreads();
  int bm = blockIdx.y * BM;
  int tr = tid / 16, tc = tid % 16;
  float acc[4][4] = {};
  for (int k0 = 0; k0 < K; k0 += BK) {
    for (int i = tid; i < BM * BK; i += 256) {
      int m = i / BK, k = i % BK;
      float v = A[(size_t)(bm + m) * K + k0 + k];
      As[k][m] = fmaf(v, a2l[k0 + k], h2l[k0 + k]);
    }
    for (int i = tid; i < BN * BK; i += 256) {
      int n = i / BK, k = i % BK;
      Bs[k][n] = Bw[(size_t)n * K + k0 + k];
    }
    __syncthreads();
#pragma unroll
    for (int k = 0; k < BK; k++) {
      float a4[4], b4[4];
#pragma unroll
      for (int xx = 0; xx < 4; xx++) a4[xx] = As[k][tr * 4 + xx];
#pragma unroll
      for (int yy = 0; yy < 4; yy++) b4[yy] = Bs[k][tc * 4 + yy];
#pragma unroll
      for (int xx = 0; xx < 4; xx++)
#pragma unroll
        for (int yy = 0; yy < 4; yy++) acc[xx][yy] = fmaf(a4[xx], b4[yy], acc[xx][yy]);
    }
    __syncthreads();
  }
#pragma unroll
  for (int yy = 0; yy < 4; yy++) {
    int n = tc * 4 + yy;
    float bv = bias[n];
    float s = 0.f, q = 0.f;
#pragma unroll
    for (int xx = 0; xx < 4; xx++) {
      int m = bm + tr * 4 + xx;
      float v = fmaxf(acc[xx][yy] + bv, 0.f);
      C[(size_t)m * 64 + n] = v;
      s += v;
      q = fmaf(v, v, q);
    }
    atomicAdd(&scs[n], s);
    atomicAdd(&sqs[n], q);
  }
  __syncthreads();
  if (tid < 64) { atomicAdd(&s3[tid], scs[tid]); atomicAdd(&q3[tid], sqs[tid]); }
}

// fused mean-pool + BN3 + output head. one wave per graph.
__global__ __launch_bounds__(256) void pool_head(const float* __restrict__ H3, const int* __restrict__ goff,
                                                 const float* __restrict__ m3,
                                                 const float* __restrict__ s3, const float* __restrict__ q3,
                                                 const float* __restrict__ g3, const float* __restrict__ be3,
                                                 const float* __restrict__ Wout, const float* __restrict__ bout,
                                                 float* __restrict__ out, int B, float invM) {
  __shared__ float a3l[64], h3l[64];
  if (threadIdx.x < 64) {
    int c = threadIdx.x;
    float mu = s3[c] * invM;
    float var = q3[c] * invM - mu * mu;
    float sc = g3[c] * rsqrtf(var + 1e-5f);
    a3l[c] = sc;
    h3l[c] = be3[c] - mu * sc;
  }
  __syncthreads();
  int w = (int)((blockIdx.x * 256 + threadIdx.x) >> 6);
  if (w >= B) return;
  int lane = threadIdx.x & 63;
  int c = lane & 31, r2 = lane >> 5;
  int a = goff[w], b = goff[w + 1];
  float s = 0.f;
  for (int r = a + r2; r < b; r += 2) s += H3[(size_t)r * 32 + c];
  s += __shfl_down(s, 32);
  float val = 0.f;
  if (r2 == 0) val = (s / fmaxf((float)(b - a), 1.f)) * Wout[c];
  float mv = m3[(size_t)w * 64 + lane];
  val += fmaf(mv, a3l[lane], h3l[lane]) * Wout[32 + lane];
#pragma unroll
  for (int off = 32; off > 0; off >>= 1) val += __shfl_down(val, off);
  if (lane == 0) out[w] = 1.f / (1.f + expf(-(val + bout[0])));
}

extern "C" void kernel_launch(void* const* d_in, const int* in_sizes, int n_in,
                              void* d_out, int out_size, void* d_ws, size_t ws_size,
                              hipStream_t stream) {
  const float* x = (const float*)d_in[0];
  const int* eidx = (const int*)d_in[1];
  const int* batch = (const int*)d_in[2];
  const float* xmord = (const float*)d_in[3];
  const float* Wl1 = (const float*)d_in[4];
  const float* bl1 = (const float*)d_in[5];
  const float* Wr1 = (const float*)d_in[6];
  const float* Wl2 = (const float*)d_in[7];
  const float* bl2 = (const float*)d_in[8];
  const float* Wr2 = (const float*)d_in[9];
  const float* Wl3 = (const float*)d_in[10];
  const float* bl3 = (const float*)d_in[11];
  const float* Wr3 = (const float*)d_in[12];
  const float* Wf1 = (const float*)d_in[13];
  const float* bf1 = (const float*)d_in[14];
  const float* g1 = (const float*)d_in[15];
  const float* be1 = (const float*)d_in[16];
  const float* Wf2 = (const float*)d_in[17];
  const float* bf2 = (const float*)d_in[18];
  const float* g2 = (const float*)d_in[19];
  const float* be2 = (const float*)d_in[20];
  const float* Wf3 = (const float*)d_in[21];
  const float* bf3 = (const float*)d_in[22];
  const float* g3 = (const float*)d_in[23];
  const float* be3 = (const float*)d_in[24];
  const float* Wout = (const float*)d_in[25];
  const float* bout = (const float*)d_in[26];
  float* out = (float*)d_out;

  const int N = in_sizes[2];
  const int E = in_sizes[1] / 2;
  const int B = in_sizes[3] / MORD;
  const int nbins = (N + 1023) >> 10;
  const int* src = eidx;
  const int* dst = eidx + E;

  char* ws = (char*)d_ws;
  size_t off_ = 0;
  auto alloc = [&](size_t bytes) { size_t o = off_; off_ += (bytes + 255) & ~(size_t)255; return o; };
  size_t oX1 = alloc((size_t)N * 8 * 2);
  size_t oAGG1 = alloc((size_t)N * 8 * 2);
  size_t oX2 = alloc((size_t)N * 32 * 2);
  size_t oX3 = alloc((size_t)N * 32 * 2);
  size_t oAGG = alloc((size_t)N * 32 * 2);
  size_t oOff = alloc((size_t)(N + 1) * 4);
  size_t oCsr = alloc((size_t)E * 4);
  size_t oEbuf = alloc((size_t)E * 8);
  size_t oH3 = alloc((size_t)N * 32 * 4);
  size_t oGoff = alloc((size_t)(B + 1) * 4);
  size_t oStats = alloc(8192 * 4);
  size_t oWc1 = alloc(352 * 64 * 2);
  size_t oWc2 = alloc(352 * 64 * 2);
  size_t oWc3 = alloc(352 * 64 * 2);
  (void)ws_size;

  unsigned short* X1 = (unsigned short*)(ws + oX1);
  unsigned short* AGG1 = (unsigned short*)(ws + oAGG1);
  unsigned short* X2 = (unsigned short*)(ws + oX2);
  unsigned short* X3 = (unsigned short*)(ws + oX3);
  unsigned short* AGG = (unsigned short*)(ws + oAGG);
  int* offp = (int*)(ws + oOff);
  int* csr = (int*)(ws + oCsr);
  unsigned long long* ebuf = (unsigned long long*)(ws + oEbuf);
  float* H3 = (float*)(ws + oH3);
  int* goff = (int*)(ws + oGoff);
  float* st = (float*)(ws + oStats);
  int* bhist = (int*)(st + 4096);
  int* boff = (int*)(st + 4608);
  int* gcur = (int*)(st + 5184);
  unsigned short* Wc1 = (unsigned short*)(ws + oWc1);
  unsigned short* Wc2 = (unsigned short*)(ws + oWc2);
  unsigned short* Wc3 = (unsigned short*)(ws + oWc3);
  float *s1 = st, *q1 = st + 512;
  float *s2 = st + 2048, *q2 = st + 2176;
  float *s3 = st + 2560, *q3 = st + 2624;

  // MLP overlays: Abf/Bbf1/W2p/b2p in X2+X3 span (dead after mfconv3); m1/m2 in AGG; m3 in off/csr.
  unsigned short* Abf = (unsigned short*)(ws + oX2);
  unsigned short* Bbf1 = (unsigned short*)(ws + oX2 + 29360128);
  unsigned short* W2p = (unsigned short*)(ws + oX2 + 29360128 + 917504);
  float* b2p = (float*)(ws + oX2 + 29360128 + 917504 + 131072);
  unsigned short* m1 = (unsigned short*)(ws + oAGG);
  float* m2 = (float*)(ws + oAGG + 16777216);
  float* m3 = (float*)(ws + oOff);

  hipMemsetAsync(st, 0, 4608 * 4, stream);

  // CSR build
  bin_hist<<<400, 256, 0, stream>>>(dst, bhist, E, nbins);
  bin_scan<<<1, 512, 0, stream>>>(bhist, boff, gcur, nbins, E);
  bin_split<<<400, 256, 0, stream>>>(src, dst, gcur, ebuf, E, nbins);
  bin_csr<<<nbins, 256, 0, stream>>>(ebuf, boff, offp, csr, N, E);
  wcat_goff<<<dim3(88, 4), 256, 0, stream>>>(Wl1, Wr1, Wc1, Wl2, Wr2, Wc2, Wl3, Wr3, Wc3, batch, goff, N, B);

  // GNN layers (compact buffers)
  prep_hx1<<<(N + 255) / 256, 256, 0, stream>>>(x, offp, csr, X1, AGG1, N);
  mfconv_mfma<1, 4, 0><<<512, 512, 0, stream>>>(X1, AGG1, Wc1, bl1, offp, X2, N);
  gather_c<<<(int)(((long long)N * 4 + 255) / 256), 256, 0, stream>>>(X2, offp, csr, AGG, N);
  mfconv_mfma<2, 8, 0><<<512, 512, 0, stream>>>(X2, AGG, Wc2, bl2, offp, X3, N);
  gather_c<<<(int)(((long long)N * 4 + 255) / 256), 256, 0, stream>>>(X3, offp, csr, AGG, N);
  mfconv_mfma<2, 8, 1><<<512, 512, 0, stream>>>(X3, AGG, Wc3, bl3, offp, H3, N);

  // MLP head
  cvt2<<<((B + 512) * 224 + 255) / 256, 256, 0, stream>>>(xmord, Wf1, Abf, Bbf1, B);
  gemm_fc1b<<<dim3(4, B / 128), 256, 0, stream>>>(Abf, Bbf1, bf1, m1, s1, q1, B, 512, 896);
  prepW2_bn<<<32, 256, 0, stream>>>(Wf2, bf2, s1, q1, g1, be1, W2p, b2p, 128, 512, 1.f / B);
  gemm_fc2<<<dim3(1, B / 128), 256, 0, stream>>>(m1, W2p, b2p, m2, s2, q2, B, 128, 512);
  gemm_fc3<<<dim3(1, B / 64), 256, 0, stream>>>(m2, Wf3, bf3, s2, q2, g2, be2, m3, s3, q3, B, 1.f / B);
  pool_head<<<(B * 64 + 255) / 256, 256, 0, stream>>>(H3, goff, m3, s3, q3, g3, be3, Wout, bout, out, B, 1.f / B);
}

// Round 12
// 334.339 us; speedup vs baseline: 1.2643x; 1.0188x over previous
//
#include <hip/hip_runtime.h>
#include <hip/hip_bf16.h>
#include <math.h>

#define MORD 862

typedef short s16x8 __attribute__((ext_vector_type(8)));
typedef float f32x4 __attribute__((ext_vector_type(4)));

static __device__ __forceinline__ unsigned short f2bf(float v) {
  __hip_bfloat16 h = __float2bfloat16(v);
  return *(unsigned short*)&h;
}
static __device__ __forceinline__ float bf2f(unsigned short u) {
  unsigned int x = ((unsigned int)u) << 16;
  return *(float*)&x;
}

// ---- Binned CSR build ----
__global__ __launch_bounds__(512) void bin_scan(const int* __restrict__ bhist, int* __restrict__ boff,
                                                int* __restrict__ gcur, int nbins, int E) {
  __shared__ int ts[512];
  int tid = threadIdx.x;
  int v = (tid < nbins) ? bhist[tid] : 0;
  ts[tid] = v;
  __syncthreads();
  for (int st = 1; st < 512; st <<= 1) {
    int t = (tid >= st) ? ts[tid - st] : 0;
    __syncthreads();
    ts[tid] += t;
    __syncthreads();
  }
  int ex = ts[tid] - v;
  if (tid < nbins) { boff[tid] = ex; gcur[tid] = ex; }
  if (tid == 0) boff[nbins] = E;
}

__global__ __launch_bounds__(256) void bin_split(const int* __restrict__ srcA, const int* __restrict__ dstA,
                                                 int* __restrict__ gcur, unsigned long long* __restrict__ ebuf,
                                                 int E, int nbins) {
  __shared__ unsigned long long sbuf[512 * 8];
  __shared__ int lcur[512];
  int tid = threadIdx.x;
  for (int base = blockIdx.x * 1024; base < E; base += (int)gridDim.x * 1024) {
    for (int i = tid; i < nbins; i += 256) lcur[i] = 0;
    __syncthreads();
    int e0 = base + tid * 4;
#pragma unroll
    for (int j = 0; j < 4; j++) {
      int e = e0 + j;
      if (e < E) {
        int d = dstA[e], s = srcA[e];
        int bin = d >> 10;
        unsigned long long p = ((unsigned long long)(unsigned int)d << 32) | (unsigned int)s;
        int slot = atomicAdd(&lcur[bin], 1);
        if (slot < 8) sbuf[bin * 8 + slot] = p;
        else { int g = atomicAdd(&gcur[bin], 1); ebuf[g] = p; }
      }
    }
    __syncthreads();
    for (int b = tid; b < nbins; b += 256) {
      int cnt = min(lcur[b], 8);
      if (cnt > 0) {
        int g = atomicAdd(&gcur[b], cnt);
        for (int k = 0; k < cnt; k++) ebuf[g + k] = sbuf[b * 8 + k];
      }
    }
    __syncthreads();
  }
}

__global__ __launch_bounds__(256) void bin_csr(const unsigned long long* __restrict__ ebuf,
                                               const int* __restrict__ boff,
                                               int* __restrict__ off, int* __restrict__ csr,
                                               int N, int E) {
  __shared__ int lcur[1024];
  __shared__ int part[256];
  int b = blockIdx.x;
  int n0 = b << 10;
  int nn = min(1024, N - n0);
  int e0 = boff[b], e1 = boff[b + 1];
  int tid = threadIdx.x;
  for (int i = tid; i < nn; i += 256) lcur[i] = 0;
  __syncthreads();
  for (int e = e0 + tid; e < e1; e += 256) {
    int d = (int)(ebuf[e] >> 32);
    atomicAdd(&lcur[d - n0], 1);
  }
  __syncthreads();
  int base4 = tid * 4;
  int c0 = (base4 < nn) ? lcur[base4] : 0;
  int c1 = (base4 + 1 < nn) ? lcur[base4 + 1] : 0;
  int c2 = (base4 + 2 < nn) ? lcur[base4 + 2] : 0;
  int c3 = (base4 + 3 < nn) ? lcur[base4 + 3] : 0;
  int tot = c0 + c1 + c2 + c3;
  part[tid] = tot;
  __syncthreads();
  for (int st = 1; st < 256; st <<= 1) {
    int t = (tid >= st) ? part[tid - st] : 0;
    __syncthreads();
    part[tid] += t;
    __syncthreads();
  }
  int pre = part[tid] - tot;
  __syncthreads();
  if (base4 < nn)     { lcur[base4]     = pre;                off[n0 + base4]     = e0 + pre; }
  if (base4 + 1 < nn) { lcur[base4 + 1] = pre + c0;           off[n0 + base4 + 1] = e0 + pre + c0; }
  if (base4 + 2 < nn) { lcur[base4 + 2] = pre + c0 + c1;      off[n0 + base4 + 2] = e0 + pre + c0 + c1; }
  if (base4 + 3 < nn) { lcur[base4 + 3] = pre + c0 + c1 + c2; off[n0 + base4 + 3] = e0 + pre + c0 + c1 + c2; }
  if (b == 0 && tid == 0) off[N] = E;
  __syncthreads();
  for (int e = e0 + tid; e < e1; e += 256) {
    unsigned long long p = ebuf[e];
    int d = (int)(p >> 32);
    int s = (int)(p & 0xffffffffu);
    int slot = atomicAdd(&lcur[d - n0], 1);
    csr[e0 + slot] = s;
  }
}

// y=0: bin histogram.  y=1: x<88*3 -> Wcat prep (3 sets); x>=264 -> graph offsets.
__global__ __launch_bounds__(256) void mega_prep(const int* __restrict__ dstA, int* __restrict__ bhist, int E, int nbins,
                                                 const float* __restrict__ Wl1, const float* __restrict__ Wr1,
                                                 unsigned short* __restrict__ Wc1,
                                                 const float* __restrict__ Wl2, const float* __restrict__ Wr2,
                                                 unsigned short* __restrict__ Wc2,
                                                 const float* __restrict__ Wl3, const float* __restrict__ Wr3,
                                                 unsigned short* __restrict__ Wc3,
                                                 const int* __restrict__ batch, int* __restrict__ goff, int N, int B) {
  if (blockIdx.y == 0) {
    __shared__ int lh[512];
    for (int i = threadIdx.x; i < nbins; i += 256) lh[i] = 0;
    __syncthreads();
    for (int e = blockIdx.x * 256 + threadIdx.x; e < E; e += gridDim.x * 256)
      atomicAdd(&lh[dstA[e] >> 10], 1);
    __syncthreads();
    for (int i = threadIdx.x; i < nbins; i += 256)
      if (lh[i]) atomicAdd(&bhist[i], lh[i]);
    return;
  }
  int bx = blockIdx.x;
  if (bx >= 264) {
    int b = (bx - 264) * 256 + threadIdx.x;
    if (b > B) return;
    int lo = 0, hi = N;
    while (lo < hi) {
      int mid = (lo + hi) >> 1;
      if (batch[mid] < b) lo = mid + 1; else hi = mid;
    }
    goff[b] = lo;
    return;
  }
  if (bx >= 88 * 3) return;
  int set = bx / 88;
  const float* Wl = set == 0 ? Wl1 : (set == 1 ? Wl2 : Wl3);
  const float* Wr = set == 0 ? Wr1 : (set == 1 ? Wr2 : Wr3);
  unsigned short* Wc = set == 0 ? Wc1 : (set == 1 ? Wc2 : Wc3);
  int CIN = set == 0 ? 8 : 32;
  int idx = (bx - set * 88) * 256 + threadIdx.x;
  if (idx >= 352 * 64) return;
  int row = idx >> 6, k = idx & 63;
  int d = row >> 5, o = row & 31;
  float v = 0.f;
  if (k < CIN) v = Wl[((size_t)d * 32 + o) * CIN + k];
  else if (k < 2 * CIN) v = Wr[((size_t)d * 32 + o) * CIN + (k - CIN)];
  Wc[idx] = f2bf(v);
}

// layer-1 prep: agg1[n][8] = neighbor-sum(x), x1[n][8] = bf16(x)
__global__ __launch_bounds__(256) void prep_hx1(const float* __restrict__ x, const int* __restrict__ off,
                                                const int* __restrict__ csr,
                                                unsigned short* __restrict__ x1, unsigned short* __restrict__ agg1, int N) {
  int n = blockIdx.x * 256 + threadIdx.x;
  if (n >= N) return;
  int a = off[n], b = off[n + 1];
  float ag[8] = {};
  for (int j = a; j < b; j++) {
    const float* xr = x + (size_t)csr[j] * 8;
#pragma unroll
    for (int t = 0; t < 8; t++) ag[t] += xr[t];
  }
  const float* xo = x + (size_t)n * 8;
  s16x8 w0, w1;
#pragma unroll
  for (int t = 0; t < 8; t++) {
    w0[t] = (short)f2bf(ag[t]);
    w1[t] = (short)f2bf(xo[t]);
  }
  *(s16x8*)(agg1 + (size_t)n * 8) = w0;
  *(s16x8*)(x1 + (size_t)n * 8) = w1;
}

// neighbor-sum over compact X[N][32] -> AGG[N][32]
__global__ __launch_bounds__(256) void gather_c(const unsigned short* __restrict__ X, const int* __restrict__ off,
                                                const int* __restrict__ csr, unsigned short* __restrict__ AGG, int N) {
  long long tid = (long long)blockIdx.x * 256 + threadIdx.x;
  if (tid >= (long long)N * 4) return;
  int n = (int)(tid >> 2), q = (int)(tid & 3);
  int a = off[n], b = off[n + 1];
  float s[8] = {};
  for (int j = a; j < b; j++) {
    const s16x8 v = *(const s16x8*)(X + (size_t)csr[j] * 32 + q * 8);
#pragma unroll
    for (int t = 0; t < 8; t++) s[t] += bf2f((unsigned short)v[t]);
  }
  s16x8 w;
#pragma unroll
  for (int t = 0; t < 8; t++) w[t] = (short)f2bf(s[t]);
  *(s16x8*)(AGG + (size_t)n * 32 + q * 8) = w;
}

// MFMA all-degree transform. OUTMODE 0: relu->bf16 X_next; 1: +bias->bf16 H3 (no relu)
template <int KS, int ACH, int OUTMODE>
__global__ __launch_bounds__(512, 4) void mfconv_mfma(const unsigned short* __restrict__ xin,
                                                      const unsigned short* __restrict__ agg,
                                                      const unsigned short* __restrict__ Wcat,
                                                      const float* __restrict__ bl,
                                                      const int* __restrict__ off,
                                                      unsigned short* __restrict__ outp, int N) {
  __shared__ __align__(16) unsigned short As[128 * ACH * 8];
  __shared__ __align__(16) unsigned short Bs[352 * 64];
  __shared__ float sbias[352];
  __shared__ int sdeg[128];
  const int tid = threadIdx.x;
  const int wid = tid >> 6, lane = tid & 63;

  for (int s = wid; s < 44; s += 8) {
    int c = s * 64 + lane;
    int cs = c ^ ((c >> 3) & 7);
    __builtin_amdgcn_global_load_lds((const __attribute__((address_space(1))) void*)((const char*)Wcat + (size_t)cs * 16),
                                     (__attribute__((address_space(3))) void*)((char*)Bs + s * 1024), 16, 0, 0);
  }
  for (int i = tid; i < 352; i += 512) sbias[i] = bl[i];

  const int ntiles = N >> 7;
  for (int t = blockIdx.x; t < ntiles; t += (int)gridDim.x) {
    const int row0 = t << 7;
    __syncthreads();
    for (int s = wid; s < 2 * ACH; s += 8) {
      int c = s * 64 + lane;
      int row = c / ACH, ch = c & (ACH - 1);
      int cs = ch ^ (row & (ACH - 1));
      size_t grow = (size_t)(row0 + row);
      const char* srcp;
      if (ACH == 4) {
        srcp = (cs == 1) ? (const char*)xin + grow * 16 : (const char*)agg + grow * 16;
      } else {
        srcp = (cs < 4) ? (const char*)agg + grow * 64 + (size_t)cs * 16
                        : (const char*)xin + grow * 64 + (size_t)(cs - 4) * 16;
      }
      __builtin_amdgcn_global_load_lds((const __attribute__((address_space(1))) void*)srcp,
                                       (__attribute__((address_space(3))) void*)((char*)As + s * 1024), 16, 0, 0);
    }
    if (tid < 128) sdeg[tid] = min(off[row0 + tid + 1] - off[row0 + tid], 10);
    __syncthreads();

    const int ra = wid * 16 + (lane & 15);
    const int g4 = lane >> 4;
    const int rl0 = wid * 16 + g4 * 4;
    int dj[4];
#pragma unroll
    for (int j = 0; j < 4; j++) dj[j] = sdeg[rl0 + j];

#pragma unroll
    for (int h = 0; h < 2; h++) {
      f32x4 acc[11] = {};
#pragma unroll
      for (int kk = 0; kk < KS; kk++) {
        int cha = (kk * 4 + g4) ^ (ra & (ACH - 1));
        s16x8 af = *(const s16x8*)((const char*)As + (size_t)(ra * ACH + cha) * 16);
#pragma unroll
        for (int nn = 0; nn < 11; nn++) {
          int rb = (h * 11 + nn) * 16 + (lane & 15);
          int cb = rb * 8 + kk * 4 + g4;
          s16x8 bf = *(const s16x8*)((const char*)Bs + (size_t)(cb ^ (rb & 7)) * 16);
          acc[nn] = __builtin_amdgcn_mfma_f32_16x16x32_bf16(af, bf, acc[nn], 0, 0, 0);
        }
      }
#pragma unroll
      for (int nn = 0; nn < 11; nn++) {
        int n = h * 11 + nn;
        int dsel = n >> 1;
        int o = (n & 1) * 16 + (lane & 15);
        float bv = sbias[dsel * 32 + o];
#pragma unroll
        for (int j = 0; j < 4; j++) {
          if (dj[j] == dsel) {
            float v = acc[nn][j] + bv;
            size_t gr = (size_t)row0 + rl0 + j;
            if (OUTMODE == 0) v = fmaxf(v, 0.f);
            outp[gr * 32 + o] = f2bf(v);
          }
        }
      }
    }
  }
}

// fused A+W fp32->bf16 conversion (K padded 862->896)
__global__ __launch_bounds__(256) void cvt2(const float* __restrict__ xm, const float* __restrict__ Wf1,
                                            unsigned short* __restrict__ Abf, unsigned short* __restrict__ Bbf1, int B) {
  const int q = 224;
  int t = blockIdx.x * 256 + threadIdx.x;
  if (t >= (B + 512) * q) return;
  int r = t / q, c4 = (t % q) * 4;
  const float* srow = (r < B) ? xm + (size_t)r * MORD : Wf1 + (size_t)(r - B) * MORD;
  unsigned short* drow = (r < B) ? Abf + (size_t)r * 896 : Bbf1 + (size_t)(r - B) * 896;
#pragma unroll
  for (int j = 0; j < 4; j++) {
    int k = c4 + j;
    float v = (k < MORD) ? srow[k] : 0.f;
    drow[k] = f2bf(v);
  }
}

// fc1: bf16 MFMA GEMM 128x128 BK=64 global_load_lds; relu+bias -> bf16; fused colstats.
__global__ __launch_bounds__(256) void gemm_fc1b(const unsigned short* __restrict__ A,
                                                 const unsigned short* __restrict__ Bw,
                                                 const float* __restrict__ bias,
                                                 unsigned short* __restrict__ Cout,
                                                 float* __restrict__ csum, float* __restrict__ csq,
                                                 int M, int Nn, int Kp) {
  __shared__ __align__(16) unsigned short As[128 * 64];
  __shared__ __align__(16) unsigned short Bs[128 * 64];
  __shared__ float scs[128], sqs[128];
  int tid = threadIdx.x;
  int wid = tid >> 6, lane = tid & 63;
  int m0 = blockIdx.y * 128, n0 = blockIdx.x * 128;
  int wr = wid >> 1, wc = wid & 1;
  f32x4 acc[4][4] = {};

  int srow_l = lane >> 3;
  int scol = (lane & 7) * 8;
  int aReadBase = ((wr * 64 + (lane & 15)) * 128) + ((lane >> 4) * 16);
  int bReadBase = ((wc * 64 + (lane & 15)) * 128) + ((lane >> 4) * 16);

  const unsigned short* Ablk = A + (size_t)m0 * Kp;
  const unsigned short* Bblk = Bw + (size_t)n0 * Kp;

  for (int k0 = 0; k0 < Kp; k0 += 64) {
#pragma unroll
    for (int i = 0; i < 4; i++) {
      int s = wid * 4 + i;
      int row = s * 8 + srow_l;
      const unsigned short* ga = Ablk + (size_t)row * Kp + k0 + scol;
      const unsigned short* gb = Bblk + (size_t)row * Kp + k0 + scol;
      __builtin_amdgcn_global_load_lds((const __attribute__((address_space(1))) void*)ga,
                                       (__attribute__((address_space(3))) void*)(As + s * 512), 16, 0, 0);
      __builtin_amdgcn_global_load_lds((const __attribute__((address_space(1))) void*)gb,
                                       (__attribute__((address_space(3))) void*)(Bs + s * 512), 16, 0, 0);
    }
    __syncthreads();
#pragma unroll
    for (int kk = 0; kk < 2; kk++) {
      s16x8 af[4], bfr[4];
#pragma unroll
      for (int m = 0; m < 4; m++)
        af[m] = *(const s16x8*)((const char*)As + aReadBase + m * (16 * 128) + kk * 64);
#pragma unroll
      for (int n = 0; n < 4; n++)
        bfr[n] = *(const s16x8*)((const char*)Bs + bReadBase + n * (16 * 128) + kk * 64);
#pragma unroll
      for (int m = 0; m < 4; m++)
#pragma unroll
        for (int n = 0; n < 4; n++)
          acc[m][n] = __builtin_amdgcn_mfma_f32_16x16x32_bf16(af[m], bfr[n], acc[m][n], 0, 0, 0);
    }
    __syncthreads();
  }

  if (tid < 128) { scs[tid] = 0.f; sqs[tid] = 0.f; }
  __syncthreads();
  int rbase = m0 + wr * 64 + (lane >> 4) * 4;
  int lc = lane & 15;
#pragma unroll
  for (int n = 0; n < 4; n++) {
    int colb = wc * 64 + n * 16 + lc;
    float bv = bias[n0 + colb];
    float s = 0.f, q = 0.f;
#pragma unroll
    for (int m = 0; m < 4; m++) {
#pragma unroll
      for (int j = 0; j < 4; j++) {
        int row = rbase + m * 16 + j;
        float v = fmaxf(acc[m][n][j] + bv, 0.f);
        Cout[(size_t)row * Nn + n0 + colb] = f2bf(v);
        s += v;
        q = fmaf(v, v, q);
      }
    }
    s += __shfl_xor(s, 16); q += __shfl_xor(q, 16);
    s += __shfl_xor(s, 32); q += __shfl_xor(q, 32);
    if ((lane >> 4) == 0) { atomicAdd(&scs[colb], s); atomicAdd(&sqs[colb], q); }
  }
  __syncthreads();
  if (tid < 128) { atomicAdd(&csum[n0 + tid], scs[tid]); atomicAdd(&csq[n0 + tid], sqs[tid]); }
}

// prepW2 with BN1 folded
__global__ __launch_bounds__(256) void prepW2_bn(const float* __restrict__ W2, const float* __restrict__ b2,
                                                 const float* __restrict__ s1, const float* __restrict__ q1,
                                                 const float* __restrict__ g1, const float* __restrict__ be1,
                                                 unsigned short* __restrict__ W2p, float* __restrict__ b2p,
                                                 int Nn, int K, float invM) {
  __shared__ float a1l[512], h1l[512];
  for (int c = threadIdx.x; c < K; c += 256) {
    float mu = s1[c] * invM;
    float var = q1[c] * invM - mu * mu;
    float sc = g1[c] * rsqrtf(var + 1e-5f);
    a1l[c] = sc;
    h1l[c] = be1[c] - mu * sc;
  }
  __syncthreads();
  int wid = threadIdx.x >> 6, lane = threadIdx.x & 63;
  int n = blockIdx.x * 4 + wid;
  if (n >= Nn) return;
  float part = 0.f;
  for (int k = lane; k < K; k += 64) {
    float w = W2[(size_t)n * K + k];
    W2p[(size_t)n * K + k] = f2bf(w * a1l[k]);
    part = fmaf(w, h1l[k], part);
  }
#pragma unroll
  for (int off = 32; off > 0; off >>= 1) part += __shfl_down(part, off, 64);
  if (lane == 0) b2p[n] = b2[n] + part;
}

// fc2: bf16 MFMA GEMM 128x128, f32 out, relu, fused colstats (grid x = 1)
__global__ __launch_bounds__(256) void gemm_fc2(const unsigned short* __restrict__ A,
                                                const unsigned short* __restrict__ Bw,
                                                const float* __restrict__ bias,
                                                float* __restrict__ Cout,
                                                float* __restrict__ csum, float* __restrict__ csq,
                                                int M, int Nn, int Kp) {
  __shared__ __align__(16) unsigned short As[128 * 64];
  __shared__ __align__(16) unsigned short Bs[128 * 64];
  __shared__ float scs[128], sqs[128];
  int tid = threadIdx.x;
  int wid = tid >> 6, lane = tid & 63;
  int m0 = blockIdx.y * 128;
  int wr = wid >> 1, wc = wid & 1;
  f32x4 acc[4][4] = {};

  int srow_l = lane >> 3;
  int scol = (lane & 7) * 8;
  int aReadBase = ((wr * 64 + (lane & 15)) * 128) + ((lane >> 4) * 16);
  int bReadBase = ((wc * 64 + (lane & 15)) * 128) + ((lane >> 4) * 16);

  const unsigned short* Ablk = A + (size_t)m0 * Kp;

  for (int k0 = 0; k0 < Kp; k0 += 64) {
#pragma unroll
    for (int i = 0; i < 4; i++) {
      int s = wid * 4 + i;
      int row = s * 8 + srow_l;
      const unsigned short* ga = Ablk + (size_t)row * Kp + k0 + scol;
      const unsigned short* gb = Bw + (size_t)row * Kp + k0 + scol;
      __builtin_amdgcn_global_load_lds((const __attribute__((address_space(1))) void*)ga,
                                       (__attribute__((address_space(3))) void*)(As + s * 512), 16, 0, 0);
      __builtin_amdgcn_global_load_lds((const __attribute__((address_space(1))) void*)gb,
                                       (__attribute__((address_space(3))) void*)(Bs + s * 512), 16, 0, 0);
    }
    __syncthreads();
#pragma unroll
    for (int kk = 0; kk < 2; kk++) {
      s16x8 af[4], bfr[4];
#pragma unroll
      for (int m = 0; m < 4; m++)
        af[m] = *(const s16x8*)((const char*)As + aReadBase + m * (16 * 128) + kk * 64);
#pragma unroll
      for (int n = 0; n < 4; n++)
        bfr[n] = *(const s16x8*)((const char*)Bs + bReadBase + n * (16 * 128) + kk * 64);
#pragma unroll
      for (int m = 0; m < 4; m++)
#pragma unroll
        for (int n = 0; n < 4; n++)
          acc[m][n] = __builtin_amdgcn_mfma_f32_16x16x32_bf16(af[m], bfr[n], acc[m][n], 0, 0, 0);
    }
    __syncthreads();
  }

  if (tid < 128) { scs[tid] = 0.f; sqs[tid] = 0.f; }
  __syncthreads();
  int rbase = m0 + wr * 64 + (lane >> 4) * 4;
  int lc = lane & 15;
#pragma unroll
  for (int n = 0; n < 4; n++) {
    int colb = wc * 64 + n * 16 + lc;
    float bv = bias[colb];
    float s = 0.f, q = 0.f;
#pragma unroll
    for (int m = 0; m < 4; m++) {
#pragma unroll
      for (int j = 0; j < 4; j++) {
        int row = rbase + m * 16 + j;
        float v = fmaxf(acc[m][n][j] + bv, 0.f);
        Cout[(size_t)row * Nn + colb] = v;
        s += v;
        q = fmaf(v, v, q);
      }
    }
    s += __shfl_xor(s, 16); q += __shfl_xor(q, 16);
    s += __shfl_xor(s, 32); q += __shfl_xor(q, 32);
    if ((lane >> 4) == 0) { atomicAdd(&scs[colb], s); atomicAdd(&sqs[colb], q); }
  }
  __syncthreads();
  if (tid < 128) { atomicAdd(&csum[tid], scs[tid]); atomicAdd(&csq[tid], sqs[tid]); }
}

// fc3: fp32 GEMM with BN2 applied to input + relu + fused colstats
__global__ __launch_bounds__(256) void gemm_fc3(const float* __restrict__ A, const float* __restrict__ Bw,
                                                const float* __restrict__ bias,
                                                const float* __restrict__ s2v, const float* __restrict__ q2v,
                                                const float* __restrict__ g2, const float* __restrict__ be2,
                                                float* __restrict__ C, float* __restrict__ s3, float* __restrict__ q3,
                                                int M, float invM) {
  const int BM = 64, BN = 64, BK = 16, K = 128;
  __shared__ float As[BK][BM + 1];
  __shared__ float Bs[BK][BN + 1];
  __shared__ float a2l[128], h2l[128];
  __shared__ float scs[64], sqs[64];
  int tid = threadIdx.x;
  for (int c = tid; c < 128; c += 256) {
    float mu = s2v[c] * invM;
    float var = q2v[c] * invM - mu * mu;
    float sc = g2[c] * rsqrtf(var + 1e-5f);
    a2l[c] = sc;
    h2l[c] = be2[c] - mu * sc;
  }
  if (tid < 64) { scs[tid] = 0.f; sqs[tid] = 0.f; }
  __syncthreads();
  int bm = blockIdx.y * BM;
  int tr = tid / 16, tc = tid % 16;
  float acc[4][4] = {};
  for (int k0 = 0; k0 < K; k0 += BK) {
    for (int i = tid; i < BM * BK; i += 256) {
      int m = i / BK, k = i % BK;
      float v = A[(size_t)(bm + m) * K + k0 + k];
      As[k][m] = fmaf(v, a2l[k0 + k], h2l[k0 + k]);
    }
    for (int i = tid; i < BN * BK; i += 256) {
      int n = i / BK, k = i % BK;
      Bs[k][n] = Bw[(size_t)n * K + k0 + k];
    }
    __syncthreads();
#pragma unroll
    for (int k = 0; k < BK; k++) {
      float a4[4], b4[4];
#pragma unroll
      for (int xx = 0; xx < 4; xx++) a4[xx] = As[k][tr * 4 + xx];
#pragma unroll
      for (int yy = 0; yy < 4; yy++) b4[yy] = Bs[k][tc * 4 + yy];
#pragma unroll
      for (int xx = 0; xx < 4; xx++)
#pragma unroll
        for (int yy = 0; yy < 4; yy++) acc[xx][yy] = fmaf(a4[xx], b4[yy], acc[xx][yy]);
    }
    __syncthreads();
  }
#pragma unroll
  for (int yy = 0; yy < 4; yy++) {
    int n = tc * 4 + yy;
    float bv = bias[n];
    float s = 0.f, q = 0.f;
#pragma unroll
    for (int xx = 0; xx < 4; xx++) {
      int m = bm + tr * 4 + xx;
      float v = fmaxf(acc[xx][yy] + bv, 0.f);
      C[(size_t)m * 64 + n] = v;
      s += v;
      q = fmaf(v, v, q);
    }
    atomicAdd(&scs[n], s);
    atomicAdd(&sqs[n], q);
  }
  __syncthreads();
  if (tid < 64) { atomicAdd(&s3[tid], scs[tid]); atomicAdd(&q3[tid], sqs[tid]); }
}

// fused mean-pool (bf16 H3) + BN3 + output head. one wave per graph.
__global__ __launch_bounds__(256) void pool_head(const unsigned short* __restrict__ H3, const int* __restrict__ goff,
                                                 const float* __restrict__ m3,
                                                 const float* __restrict__ s3, const float* __restrict__ q3,
                                                 const float* __restrict__ g3, const float* __restrict__ be3,
                                                 const float* __restrict__ Wout, const float* __restrict__ bout,
                                                 float* __restrict__ out, int B, float invM) {
  __shared__ float a3l[64], h3l[64];
  if (threadIdx.x < 64) {
    int c = threadIdx.x;
    float mu = s3[c] * invM;
    float var = q3[c] * invM - mu * mu;
    float sc = g3[c] * rsqrtf(var + 1e-5f);
    a3l[c] = sc;
    h3l[c] = be3[c] - mu * sc;
  }
  __syncthreads();
  int w = (int)((blockIdx.x * 256 + threadIdx.x) >> 6);
  if (w >= B) return;
  int lane = threadIdx.x & 63;
  int c = lane & 31, r2 = lane >> 5;
  int a = goff[w], b = goff[w + 1];
  float s = 0.f;
  for (int r = a + r2; r < b; r += 2) s += bf2f(H3[(size_t)r * 32 + c]);
  s += __shfl_down(s, 32);
  float val = 0.f;
  if (r2 == 0) val = (s / fmaxf((float)(b - a), 1.f)) * Wout[c];
  float mv = m3[(size_t)w * 64 + lane];
  val += fmaf(mv, a3l[lane], h3l[lane]) * Wout[32 + lane];
#pragma unroll
  for (int off = 32; off > 0; off >>= 1) val += __shfl_down(val, off);
  if (lane == 0) out[w] = 1.f / (1.f + expf(-(val + bout[0])));
}

extern "C" void kernel_launch(void* const* d_in, const int* in_sizes, int n_in,
                              void* d_out, int out_size, void* d_ws, size_t ws_size,
                              hipStream_t stream) {
  const float* x = (const float*)d_in[0];
  const int* eidx = (const int*)d_in[1];
  const int* batch = (const int*)d_in[2];
  const float* xmord = (const float*)d_in[3];
  const float* Wl1 = (const float*)d_in[4];
  const float* bl1 = (const float*)d_in[5];
  const float* Wr1 = (const float*)d_in[6];
  const float* Wl2 = (const float*)d_in[7];
  const float* bl2 = (const float*)d_in[8];
  const float* Wr2 = (const float*)d_in[9];
  const float* Wl3 = (const float*)d_in[10];
  const float* bl3 = (const float*)d_in[11];
  const float* Wr3 = (const float*)d_in[12];
  const float* Wf1 = (const float*)d_in[13];
  const float* bf1 = (const float*)d_in[14];
  const float* g1 = (const float*)d_in[15];
  const float* be1 = (const float*)d_in[16];
  const float* Wf2 = (const float*)d_in[17];
  const float* bf2 = (const float*)d_in[18];
  const float* g2 = (const float*)d_in[19];
  const float* be2 = (const float*)d_in[20];
  const float* Wf3 = (const float*)d_in[21];
  const float* bf3 = (const float*)d_in[22];
  const float* g3 = (const float*)d_in[23];
  const float* be3 = (const float*)d_in[24];
  const float* Wout = (const float*)d_in[25];
  const float* bout = (const float*)d_in[26];
  float* out = (float*)d_out;

  const int N = in_sizes[2];
  const int E = in_sizes[1] / 2;
  const int B = in_sizes[3] / MORD;
  const int nbins = (N + 1023) >> 10;
  const int* src = eidx;
  const int* dst = eidx + E;

  char* ws = (char*)d_ws;
  size_t off_ = 0;
  auto alloc = [&](size_t bytes) { size_t o = off_; off_ += (bytes + 255) & ~(size_t)255; return o; };
  size_t oX1 = alloc((size_t)N * 8 * 2);
  size_t oAGG1 = alloc((size_t)N * 8 * 2);
  size_t oX2 = alloc((size_t)N * 32 * 2);
  size_t oX3 = alloc((size_t)N * 32 * 2);
  size_t oAGG = alloc((size_t)N * 32 * 2);
  size_t oOff = alloc((size_t)(N + 1) * 4);
  size_t oCsr = alloc((size_t)E * 4);
  size_t oEbuf = alloc((size_t)E * 8);
  size_t oH3 = alloc((size_t)N * 32 * 2);
  size_t oGoff = alloc((size_t)(B + 1) * 4);
  size_t oStats = alloc(8192 * 4);
  size_t oWc1 = alloc(352 * 64 * 2);
  size_t oWc2 = alloc(352 * 64 * 2);
  size_t oWc3 = alloc(352 * 64 * 2);
  (void)ws_size;

  unsigned short* X1 = (unsigned short*)(ws + oX1);
  unsigned short* AGG1 = (unsigned short*)(ws + oAGG1);
  unsigned short* X2 = (unsigned short*)(ws + oX2);
  unsigned short* X3 = (unsigned short*)(ws + oX3);
  unsigned short* AGG = (unsigned short*)(ws + oAGG);
  int* offp = (int*)(ws + oOff);
  int* csr = (int*)(ws + oCsr);
  unsigned long long* ebuf = (unsigned long long*)(ws + oEbuf);
  unsigned short* H3 = (unsigned short*)(ws + oH3);
  int* goff = (int*)(ws + oGoff);
  float* st = (float*)(ws + oStats);
  int* bhist = (int*)(st + 4096);
  int* boff = (int*)(st + 4608);
  int* gcur = (int*)(st + 5184);
  unsigned short* Wc1 = (unsigned short*)(ws + oWc1);
  unsigned short* Wc2 = (unsigned short*)(ws + oWc2);
  unsigned short* Wc3 = (unsigned short*)(ws + oWc3);
  float *s1 = st, *q1 = st + 512;
  float *s2 = st + 2048, *q2 = st + 2176;
  float *s3 = st + 2560, *q3 = st + 2624;

  // MLP overlays: Abf/Bbf1/W2p/b2p in X2+X3 span (dead after mfconv3); m1/m2 in AGG; m3 in off/csr.
  unsigned short* Abf = (unsigned short*)(ws + oX2);
  unsigned short* Bbf1 = (unsigned short*)(ws + oX2 + 29360128);
  unsigned short* W2p = (unsigned short*)(ws + oX2 + 29360128 + 917504);
  float* b2p = (float*)(ws + oX2 + 29360128 + 917504 + 131072);
  unsigned short* m1 = (unsigned short*)(ws + oAGG);
  float* m2 = (float*)(ws + oAGG + 16777216);
  float* m3 = (float*)(ws + oOff);

  hipMemsetAsync(st, 0, 4608 * 4, stream);

  // CSR build + weight/goff prep
  mega_prep<<<dim3(400, 2), 256, 0, stream>>>(dst, bhist, E, nbins,
                                              Wl1, Wr1, Wc1, Wl2, Wr2, Wc2, Wl3, Wr3, Wc3,
                                              batch, goff, N, B);
  bin_scan<<<1, 512, 0, stream>>>(bhist, boff, gcur, nbins, E);
  bin_split<<<400, 256, 0, stream>>>(src, dst, gcur, ebuf, E, nbins);
  bin_csr<<<nbins, 256, 0, stream>>>(ebuf, boff, offp, csr, N, E);

  // GNN layers (compact buffers)
  prep_hx1<<<(N + 255) / 256, 256, 0, stream>>>(x, offp, csr, X1, AGG1, N);
  mfconv_mfma<1, 4, 0><<<512, 512, 0, stream>>>(X1, AGG1, Wc1, bl1, offp, X2, N);
  gather_c<<<(int)(((long long)N * 4 + 255) / 256), 256, 0, stream>>>(X2, offp, csr, AGG, N);
  mfconv_mfma<2, 8, 0><<<512, 512, 0, stream>>>(X2, AGG, Wc2, bl2, offp, X3, N);
  gather_c<<<(int)(((long long)N * 4 + 255) / 256), 256, 0, stream>>>(X3, offp, csr, AGG, N);
  mfconv_mfma<2, 8, 1><<<512, 512, 0, stream>>>(X3, AGG, Wc3, bl3, offp, H3, N);

  // MLP head
  cvt2<<<((B + 512) * 224 + 255) / 256, 256, 0, stream>>>(xmord, Wf1, Abf, Bbf1, B);
  gemm_fc1b<<<dim3(4, B / 128), 256, 0, stream>>>(Abf, Bbf1, bf1, m1, s1, q1, B, 512, 896);
  prepW2_bn<<<32, 256, 0, stream>>>(Wf2, bf2, s1, q1, g1, be1, W2p, b2p, 128, 512, 1.f / B);
  gemm_fc2<<<dim3(1, B / 128), 256, 0, stream>>>(m1, W2p, b2p, m2, s2, q2, B, 128, 512);
  gemm_fc3<<<dim3(1, B / 64), 256, 0, stream>>>(m2, Wf3, bf3, s2, q2, g2, be2, m3, s3, q3, B, 1.f / B);
  pool_head<<<(B * 64 + 255) / 256, 256, 0, stream>>>(H3, goff, m3, s3, q3, g3, be3, Wout, bout, out, B, 1.f / B);
}

// Round 13
// 326.991 us; speedup vs baseline: 1.2927x; 1.0225x over previous
//
#include <hip/hip_runtime.h>
#include <hip/hip_bf16.h>
#include <math.h>

#define MORD 862

typedef short s16x8 __attribute__((ext_vector_type(8)));
typedef float f32x4 __attribute__((ext_vector_type(4)));
typedef float f32x4a __attribute__((ext_vector_type(4), aligned(4)));

static __device__ __forceinline__ unsigned short f2bf(float v) {
  __hip_bfloat16 h = __float2bfloat16(v);
  return *(unsigned short*)&h;
}
static __device__ __forceinline__ float bf2f(unsigned short u) {
  unsigned int x = ((unsigned int)u) << 16;
  return *(float*)&x;
}

// ---- Binned CSR build ----
__global__ __launch_bounds__(512) void bin_scan(const int* __restrict__ bhist, int* __restrict__ boff,
                                                int* __restrict__ gcur, int nbins, int E) {
  __shared__ int ts[512];
  int tid = threadIdx.x;
  int v = (tid < nbins) ? bhist[tid] : 0;
  ts[tid] = v;
  __syncthreads();
  for (int st = 1; st < 512; st <<= 1) {
    int t = (tid >= st) ? ts[tid - st] : 0;
    __syncthreads();
    ts[tid] += t;
    __syncthreads();
  }
  int ex = ts[tid] - v;
  if (tid < nbins) { boff[tid] = ex; gcur[tid] = ex; }
  if (tid == 0) boff[nbins] = E;
}

__global__ __launch_bounds__(256) void bin_split(const int* __restrict__ srcA, const int* __restrict__ dstA,
                                                 int* __restrict__ gcur, unsigned long long* __restrict__ ebuf,
                                                 int E, int nbins) {
  __shared__ unsigned long long sbuf[512 * 8];
  __shared__ int lcur[512];
  int tid = threadIdx.x;
  for (int base = blockIdx.x * 1024; base < E; base += (int)gridDim.x * 1024) {
    for (int i = tid; i < nbins; i += 256) lcur[i] = 0;
    __syncthreads();
    int e0 = base + tid * 4;
#pragma unroll
    for (int j = 0; j < 4; j++) {
      int e = e0 + j;
      if (e < E) {
        int d = dstA[e], s = srcA[e];
        int bin = d >> 10;
        unsigned long long p = ((unsigned long long)(unsigned int)d << 32) | (unsigned int)s;
        int slot = atomicAdd(&lcur[bin], 1);
        if (slot < 8) sbuf[bin * 8 + slot] = p;
        else { int g = atomicAdd(&gcur[bin], 1); ebuf[g] = p; }
      }
    }
    __syncthreads();
    for (int b = tid; b < nbins; b += 256) {
      int cnt = min(lcur[b], 8);
      if (cnt > 0) {
        int g = atomicAdd(&gcur[b], cnt);
        for (int k = 0; k < cnt; k++) ebuf[g + k] = sbuf[b * 8 + k];
      }
    }
    __syncthreads();
  }
}

__global__ __launch_bounds__(256) void bin_csr(const unsigned long long* __restrict__ ebuf,
                                               const int* __restrict__ boff,
                                               int* __restrict__ off, int* __restrict__ csr,
                                               int N, int E) {
  __shared__ int lcur[1024];
  __shared__ int part[256];
  int b = blockIdx.x;
  int n0 = b << 10;
  int nn = min(1024, N - n0);
  int e0 = boff[b], e1 = boff[b + 1];
  int tid = threadIdx.x;
  for (int i = tid; i < nn; i += 256) lcur[i] = 0;
  __syncthreads();
  for (int e = e0 + tid; e < e1; e += 256) {
    int d = (int)(ebuf[e] >> 32);
    atomicAdd(&lcur[d - n0], 1);
  }
  __syncthreads();
  int base4 = tid * 4;
  int c0 = (base4 < nn) ? lcur[base4] : 0;
  int c1 = (base4 + 1 < nn) ? lcur[base4 + 1] : 0;
  int c2 = (base4 + 2 < nn) ? lcur[base4 + 2] : 0;
  int c3 = (base4 + 3 < nn) ? lcur[base4 + 3] : 0;
  int tot = c0 + c1 + c2 + c3;
  part[tid] = tot;
  __syncthreads();
  for (int st = 1; st < 256; st <<= 1) {
    int t = (tid >= st) ? part[tid - st] : 0;
    __syncthreads();
    part[tid] += t;
    __syncthreads();
  }
  int pre = part[tid] - tot;
  __syncthreads();
  if (base4 < nn)     { lcur[base4]     = pre;                off[n0 + base4]     = e0 + pre; }
  if (base4 + 1 < nn) { lcur[base4 + 1] = pre + c0;           off[n0 + base4 + 1] = e0 + pre + c0; }
  if (base4 + 2 < nn) { lcur[base4 + 2] = pre + c0 + c1;      off[n0 + base4 + 2] = e0 + pre + c0 + c1; }
  if (base4 + 3 < nn) { lcur[base4 + 3] = pre + c0 + c1 + c2; off[n0 + base4 + 3] = e0 + pre + c0 + c1 + c2; }
  if (b == 0 && tid == 0) off[N] = E;
  __syncthreads();
  for (int e = e0 + tid; e < e1; e += 256) {
    unsigned long long p = ebuf[e];
    int d = (int)(p >> 32);
    int s = (int)(p & 0xffffffffu);
    int slot = atomicAdd(&lcur[d - n0], 1);
    csr[e0 + slot] = s;
  }
}

// y=0 (bx<400): bin histogram.  y=1: bx<264 -> Wcat prep; 264<=bx<330 -> graph offsets;
// 330<=bx<778 -> Wf1 fp32->bf16 (padded 896).
__global__ __launch_bounds__(256) void mega_prep(const int* __restrict__ dstA, int* __restrict__ bhist, int E, int nbins,
                                                 const float* __restrict__ Wl1, const float* __restrict__ Wr1,
                                                 unsigned short* __restrict__ Wc1,
                                                 const float* __restrict__ Wl2, const float* __restrict__ Wr2,
                                                 unsigned short* __restrict__ Wc2,
                                                 const float* __restrict__ Wl3, const float* __restrict__ Wr3,
                                                 unsigned short* __restrict__ Wc3,
                                                 const int* __restrict__ batch, int* __restrict__ goff, int N, int B,
                                                 const float* __restrict__ Wf1, unsigned short* __restrict__ Bbf1) {
  if (blockIdx.y == 0) {
    if (blockIdx.x >= 400) return;
    __shared__ int lh[512];
    for (int i = threadIdx.x; i < nbins; i += 256) lh[i] = 0;
    __syncthreads();
    for (int e = blockIdx.x * 256 + threadIdx.x; e < E; e += 400 * 256)
      atomicAdd(&lh[dstA[e] >> 10], 1);
    __syncthreads();
    for (int i = threadIdx.x; i < nbins; i += 256)
      if (lh[i]) atomicAdd(&bhist[i], lh[i]);
    return;
  }
  int bx = blockIdx.x;
  if (bx >= 330) {
    int idx = (bx - 330) * 256 + threadIdx.x;
    if (idx >= 512 * 224) return;
    int r = idx / 224, c4 = (idx % 224) * 4;
#pragma unroll
    for (int j = 0; j < 4; j++) {
      int k = c4 + j;
      float v = (k < MORD) ? Wf1[(size_t)r * MORD + k] : 0.f;
      Bbf1[(size_t)r * 896 + k] = f2bf(v);
    }
    return;
  }
  if (bx >= 264) {
    int b = (bx - 264) * 256 + threadIdx.x;
    if (b > B) return;
    int lo = 0, hi = N;
    while (lo < hi) {
      int mid = (lo + hi) >> 1;
      if (batch[mid] < b) lo = mid + 1; else hi = mid;
    }
    goff[b] = lo;
    return;
  }
  int set = bx / 88;
  const float* Wl = set == 0 ? Wl1 : (set == 1 ? Wl2 : Wl3);
  const float* Wr = set == 0 ? Wr1 : (set == 1 ? Wr2 : Wr3);
  unsigned short* Wc = set == 0 ? Wc1 : (set == 1 ? Wc2 : Wc3);
  int CIN = set == 0 ? 8 : 32;
  int idx = (bx - set * 88) * 256 + threadIdx.x;
  if (idx >= 352 * 64) return;
  int row = idx >> 6, k = idx & 63;
  int d = row >> 5, o = row & 31;
  float v = 0.f;
  if (k < CIN) v = Wl[((size_t)d * 32 + o) * CIN + k];
  else if (k < 2 * CIN) v = Wr[((size_t)d * 32 + o) * CIN + (k - CIN)];
  Wc[idx] = f2bf(v);
}

// layer-1 prep, 4-wide pipelined gather: agg1[n][8] = neighbor-sum(x), x1[n][8] = bf16(x)
__global__ __launch_bounds__(256) void prep_hx1(const float* __restrict__ x, const int* __restrict__ off,
                                                const int* __restrict__ csr,
                                                unsigned short* __restrict__ x1, unsigned short* __restrict__ agg1, int N) {
  int n = blockIdx.x * 256 + threadIdx.x;
  if (n >= N) return;
  int a = off[n], b = off[n + 1];
  float ag[8] = {};
  for (int base = a; base < b; base += 4) {
    int rem = b - base;
    int j1 = base + (rem > 1 ? 1 : 0);
    int j2 = base + (rem > 2 ? 2 : 0);
    int j3 = base + (rem > 3 ? 3 : 0);
    int cc0 = csr[base], cc1 = csr[j1], cc2 = csr[j2], cc3 = csr[j3];
    f32x4a v0a = *(const f32x4a*)(x + (size_t)cc0 * 8);
    f32x4a v0b = *(const f32x4a*)(x + (size_t)cc0 * 8 + 4);
    f32x4a v1a = *(const f32x4a*)(x + (size_t)cc1 * 8);
    f32x4a v1b = *(const f32x4a*)(x + (size_t)cc1 * 8 + 4);
    f32x4a v2a = *(const f32x4a*)(x + (size_t)cc2 * 8);
    f32x4a v2b = *(const f32x4a*)(x + (size_t)cc2 * 8 + 4);
    f32x4a v3a = *(const f32x4a*)(x + (size_t)cc3 * 8);
    f32x4a v3b = *(const f32x4a*)(x + (size_t)cc3 * 8 + 4);
    float m1 = rem > 1 ? 1.f : 0.f;
    float m2 = rem > 2 ? 1.f : 0.f;
    float m3 = rem > 3 ? 1.f : 0.f;
#pragma unroll
    for (int t = 0; t < 4; t++) {
      ag[t] += v0a[t];
      ag[t] = fmaf(m1, v1a[t], ag[t]);
      ag[t] = fmaf(m2, v2a[t], ag[t]);
      ag[t] = fmaf(m3, v3a[t], ag[t]);
      ag[t + 4] += v0b[t];
      ag[t + 4] = fmaf(m1, v1b[t], ag[t + 4]);
      ag[t + 4] = fmaf(m2, v2b[t], ag[t + 4]);
      ag[t + 4] = fmaf(m3, v3b[t], ag[t + 4]);
    }
  }
  const float* xo = x + (size_t)n * 8;
  s16x8 w0, w1;
#pragma unroll
  for (int t = 0; t < 8; t++) {
    w0[t] = (short)f2bf(ag[t]);
    w1[t] = (short)f2bf(xo[t]);
  }
  *(s16x8*)(agg1 + (size_t)n * 8) = w0;
  *(s16x8*)(x1 + (size_t)n * 8) = w1;
}

// neighbor-sum over compact X[N][32] -> AGG[N][32], 4-wide pipelined
__global__ __launch_bounds__(256) void gather_c(const unsigned short* __restrict__ X, const int* __restrict__ off,
                                                const int* __restrict__ csr, unsigned short* __restrict__ AGG, int N) {
  long long tid = (long long)blockIdx.x * 256 + threadIdx.x;
  if (tid >= (long long)N * 4) return;
  int n = (int)(tid >> 2), q = (int)(tid & 3);
  int a = off[n], b = off[n + 1];
  float s[8] = {};
  for (int base = a; base < b; base += 4) {
    int rem = b - base;
    int j1 = base + (rem > 1 ? 1 : 0);
    int j2 = base + (rem > 2 ? 2 : 0);
    int j3 = base + (rem > 3 ? 3 : 0);
    int cc0 = csr[base], cc1 = csr[j1], cc2 = csr[j2], cc3 = csr[j3];
    const s16x8 v0 = *(const s16x8*)(X + (size_t)cc0 * 32 + q * 8);
    const s16x8 v1 = *(const s16x8*)(X + (size_t)cc1 * 32 + q * 8);
    const s16x8 v2 = *(const s16x8*)(X + (size_t)cc2 * 32 + q * 8);
    const s16x8 v3 = *(const s16x8*)(X + (size_t)cc3 * 32 + q * 8);
    float m1 = rem > 1 ? 1.f : 0.f;
    float m2 = rem > 2 ? 1.f : 0.f;
    float m3 = rem > 3 ? 1.f : 0.f;
#pragma unroll
    for (int t = 0; t < 8; t++) {
      s[t] += bf2f((unsigned short)v0[t]);
      s[t] = fmaf(m1, bf2f((unsigned short)v1[t]), s[t]);
      s[t] = fmaf(m2, bf2f((unsigned short)v2[t]), s[t]);
      s[t] = fmaf(m3, bf2f((unsigned short)v3[t]), s[t]);
    }
  }
  s16x8 w;
#pragma unroll
  for (int t = 0; t < 8; t++) w[t] = (short)f2bf(s[t]);
  *(s16x8*)(AGG + (size_t)n * 32 + q * 8) = w;
}

// MFMA all-degree transform. OUTMODE 0: relu->bf16 X_next; 1: +bias->bf16 H3 (no relu)
template <int KS, int ACH, int OUTMODE>
__global__ __launch_bounds__(512, 4) void mfconv_mfma(const unsigned short* __restrict__ xin,
                                                      const unsigned short* __restrict__ agg,
                                                      const unsigned short* __restrict__ Wcat,
                                                      const float* __restrict__ bl,
                                                      const int* __restrict__ off,
                                                      unsigned short* __restrict__ outp, int N) {
  __shared__ __align__(16) unsigned short As[128 * ACH * 8];
  __shared__ __align__(16) unsigned short Bs[352 * 64];
  __shared__ float sbias[352];
  __shared__ int sdeg[128];
  const int tid = threadIdx.x;
  const int wid = tid >> 6, lane = tid & 63;

  for (int s = wid; s < 44; s += 8) {
    int c = s * 64 + lane;
    int cs = c ^ ((c >> 3) & 7);
    __builtin_amdgcn_global_load_lds((const __attribute__((address_space(1))) void*)((const char*)Wcat + (size_t)cs * 16),
                                     (__attribute__((address_space(3))) void*)((char*)Bs + s * 1024), 16, 0, 0);
  }
  for (int i = tid; i < 352; i += 512) sbias[i] = bl[i];

  const int ntiles = N >> 7;
  for (int t = blockIdx.x; t < ntiles; t += (int)gridDim.x) {
    const int row0 = t << 7;
    __syncthreads();
    for (int s = wid; s < 2 * ACH; s += 8) {
      int c = s * 64 + lane;
      int row = c / ACH, ch = c & (ACH - 1);
      int cs = ch ^ (row & (ACH - 1));
      size_t grow = (size_t)(row0 + row);
      const char* srcp;
      if (ACH == 4) {
        srcp = (cs == 1) ? (const char*)xin + grow * 16 : (const char*)agg + grow * 16;
      } else {
        srcp = (cs < 4) ? (const char*)agg + grow * 64 + (size_t)cs * 16
                        : (const char*)xin + grow * 64 + (size_t)(cs - 4) * 16;
      }
      __builtin_amdgcn_global_load_lds((const __attribute__((address_space(1))) void*)srcp,
                                       (__attribute__((address_space(3))) void*)((char*)As + s * 1024), 16, 0, 0);
    }
    if (tid < 128) sdeg[tid] = min(off[row0 + tid + 1] - off[row0 + tid], 10);
    __syncthreads();

    const int ra = wid * 16 + (lane & 15);
    const int g4 = lane >> 4;
    const int rl0 = wid * 16 + g4 * 4;
    int dj[4];
#pragma unroll
    for (int j = 0; j < 4; j++) dj[j] = sdeg[rl0 + j];

#pragma unroll
    for (int h = 0; h < 2; h++) {
      f32x4 acc[11] = {};
#pragma unroll
      for (int kk = 0; kk < KS; kk++) {
        int cha = (kk * 4 + g4) ^ (ra & (ACH - 1));
        s16x8 af = *(const s16x8*)((const char*)As + (size_t)(ra * ACH + cha) * 16);
#pragma unroll
        for (int nn = 0; nn < 11; nn++) {
          int rb = (h * 11 + nn) * 16 + (lane & 15);
          int cb = rb * 8 + kk * 4 + g4;
          s16x8 bf = *(const s16x8*)((const char*)Bs + (size_t)(cb ^ (rb & 7)) * 16);
          acc[nn] = __builtin_amdgcn_mfma_f32_16x16x32_bf16(af, bf, acc[nn], 0, 0, 0);
        }
      }
#pragma unroll
      for (int nn = 0; nn < 11; nn++) {
        int n = h * 11 + nn;
        int dsel = n >> 1;
        int o = (n & 1) * 16 + (lane & 15);
        float bv = sbias[dsel * 32 + o];
#pragma unroll
        for (int j = 0; j < 4; j++) {
          if (dj[j] == dsel) {
            float v = acc[nn][j] + bv;
            size_t gr = (size_t)row0 + rl0 + j;
            if (OUTMODE == 0) v = fmaxf(v, 0.f);
            outp[gr * 32 + o] = f2bf(v);
          }
        }
      }
    }
  }
}

// A (xmord) fp32->bf16 conversion (K padded 862->896)
__global__ __launch_bounds__(256) void cvtA(const float* __restrict__ xm, unsigned short* __restrict__ Abf, int B) {
  const int q = 224;
  int t = blockIdx.x * 256 + threadIdx.x;
  if (t >= B * q) return;
  int r = t / q, c4 = (t % q) * 4;
#pragma unroll
  for (int j = 0; j < 4; j++) {
    int k = c4 + j;
    float v = (k < MORD) ? xm[(size_t)r * MORD + k] : 0.f;
    Abf[(size_t)r * 896 + k] = f2bf(v);
  }
}

// fc1: bf16 MFMA GEMM 128x128 BK=64 global_load_lds; relu+bias -> bf16; fused colstats.
// XCD-chunked block swizzle (512 blocks, 8 XCDs -> 64-block chunks; same-A-panel blocks colocate).
__global__ __launch_bounds__(256) void gemm_fc1b(const unsigned short* __restrict__ A,
                                                 const unsigned short* __restrict__ Bw,
                                                 const float* __restrict__ bias,
                                                 unsigned short* __restrict__ Cout,
                                                 float* __restrict__ csum, float* __restrict__ csq,
                                                 int M, int Nn, int Kp) {
  __shared__ __align__(16) unsigned short As[128 * 64];
  __shared__ __align__(16) unsigned short Bs[128 * 64];
  __shared__ float scs[128], sqs[128];
  int tid = threadIdx.x;
  int wid = tid >> 6, lane = tid & 63;
  int lin = blockIdx.x + blockIdx.y * 4;
  int swz = (lin & 7) * 64 + (lin >> 3);
  int m0 = (swz >> 2) * 128, n0 = (swz & 3) * 128;
  int wr = wid >> 1, wc = wid & 1;
  f32x4 acc[4][4] = {};

  int srow_l = lane >> 3;
  int scol = (lane & 7) * 8;
  int aReadBase = ((wr * 64 + (lane & 15)) * 128) + ((lane >> 4) * 16);
  int bReadBase = ((wc * 64 + (lane & 15)) * 128) + ((lane >> 4) * 16);

  const unsigned short* Ablk = A + (size_t)m0 * Kp;
  const unsigned short* Bblk = Bw + (size_t)n0 * Kp;

  for (int k0 = 0; k0 < Kp; k0 += 64) {
#pragma unroll
    for (int i = 0; i < 4; i++) {
      int s = wid * 4 + i;
      int row = s * 8 + srow_l;
      const unsigned short* ga = Ablk + (size_t)row * Kp + k0 + scol;
      const unsigned short* gb = Bblk + (size_t)row * Kp + k0 + scol;
      __builtin_amdgcn_global_load_lds((const __attribute__((address_space(1))) void*)ga,
                                       (__attribute__((address_space(3))) void*)(As + s * 512), 16, 0, 0);
      __builtin_amdgcn_global_load_lds((const __attribute__((address_space(1))) void*)gb,
                                       (__attribute__((address_space(3))) void*)(Bs + s * 512), 16, 0, 0);
    }
    __syncthreads();
#pragma unroll
    for (int kk = 0; kk < 2; kk++) {
      s16x8 af[4], bfr[4];
#pragma unroll
      for (int m = 0; m < 4; m++)
        af[m] = *(const s16x8*)((const char*)As + aReadBase + m * (16 * 128) + kk * 64);
#pragma unroll
      for (int n = 0; n < 4; n++)
        bfr[n] = *(const s16x8*)((const char*)Bs + bReadBase + n * (16 * 128) + kk * 64);
#pragma unroll
      for (int m = 0; m < 4; m++)
#pragma unroll
        for (int n = 0; n < 4; n++)
          acc[m][n] = __builtin_amdgcn_mfma_f32_16x16x32_bf16(af[m], bfr[n], acc[m][n], 0, 0, 0);
    }
    __syncthreads();
  }

  if (tid < 128) { scs[tid] = 0.f; sqs[tid] = 0.f; }
  __syncthreads();
  int rbase = m0 + wr * 64 + (lane >> 4) * 4;
  int lc = lane & 15;
#pragma unroll
  for (int n = 0; n < 4; n++) {
    int colb = wc * 64 + n * 16 + lc;
    float bv = bias[n0 + colb];
    float s = 0.f, q = 0.f;
#pragma unroll
    for (int m = 0; m < 4; m++) {
#pragma unroll
      for (int j = 0; j < 4; j++) {
        int row = rbase + m * 16 + j;
        float v = fmaxf(acc[m][n][j] + bv, 0.f);
        Cout[(size_t)row * Nn + n0 + colb] = f2bf(v);
        s += v;
        q = fmaf(v, v, q);
      }
    }
    s += __shfl_xor(s, 16); q += __shfl_xor(q, 16);
    s += __shfl_xor(s, 32); q += __shfl_xor(q, 32);
    if ((lane >> 4) == 0) { atomicAdd(&scs[colb], s); atomicAdd(&sqs[colb], q); }
  }
  __syncthreads();
  if (tid < 128) { atomicAdd(&csum[n0 + tid], scs[tid]); atomicAdd(&csq[n0 + tid], sqs[tid]); }
}

// prepW2 with BN1 folded
__global__ __launch_bounds__(256) void prepW2_bn(const float* __restrict__ W2, const float* __restrict__ b2,
                                                 const float* __restrict__ s1, const float* __restrict__ q1,
                                                 const float* __restrict__ g1, const float* __restrict__ be1,
                                                 unsigned short* __restrict__ W2p, float* __restrict__ b2p,
                                                 int Nn, int K, float invM) {
  __shared__ float a1l[512], h1l[512];
  for (int c = threadIdx.x; c < K; c += 256) {
    float mu = s1[c] * invM;
    float var = q1[c] * invM - mu * mu;
    float sc = g1[c] * rsqrtf(var + 1e-5f);
    a1l[c] = sc;
    h1l[c] = be1[c] - mu * sc;
  }
  __syncthreads();
  int wid = threadIdx.x >> 6, lane = threadIdx.x & 63;
  int n = blockIdx.x * 4 + wid;
  if (n >= Nn) return;
  float part = 0.f;
  for (int k = lane; k < K; k += 64) {
    float w = W2[(size_t)n * K + k];
    W2p[(size_t)n * K + k] = f2bf(w * a1l[k]);
    part = fmaf(w, h1l[k], part);
  }
#pragma unroll
  for (int off = 32; off > 0; off >>= 1) part += __shfl_down(part, off, 64);
  if (lane == 0) b2p[n] = b2[n] + part;
}

// fc2: bf16 MFMA GEMM 128x128, f32 out, relu, fused colstats (grid x = 1)
__global__ __launch_bounds__(256) void gemm_fc2(const unsigned short* __restrict__ A,
                                                const unsigned short* __restrict__ Bw,
                                                const float* __restrict__ bias,
                                                float* __restrict__ Cout,
                                                float* __restrict__ csum, float* __restrict__ csq,
                                                int M, int Nn, int Kp) {
  __shared__ __align__(16) unsigned short As[128 * 64];
  __shared__ __align__(16) unsigned short Bs[128 * 64];
  __shared__ float scs[128], sqs[128];
  int tid = threadIdx.x;
  int wid = tid >> 6, lane = tid & 63;
  int m0 = blockIdx.y * 128;
  int wr = wid >> 1, wc = wid & 1;
  f32x4 acc[4][4] = {};

  int srow_l = lane >> 3;
  int scol = (lane & 7) * 8;
  int aReadBase = ((wr * 64 + (lane & 15)) * 128) + ((lane >> 4) * 16);
  int bReadBase = ((wc * 64 + (lane & 15)) * 128) + ((lane >> 4) * 16);

  const unsigned short* Ablk = A + (size_t)m0 * Kp;

  for (int k0 = 0; k0 < Kp; k0 += 64) {
#pragma unroll
    for (int i = 0; i < 4; i++) {
      int s = wid * 4 + i;
      int row = s * 8 + srow_l;
      const unsigned short* ga = Ablk + (size_t)row * Kp + k0 + scol;
      const unsigned short* gb = Bw + (size_t)row * Kp + k0 + scol;
      __builtin_amdgcn_global_load_lds((const __attribute__((address_space(1))) void*)ga,
                                       (__attribute__((address_space(3))) void*)(As + s * 512), 16, 0, 0);
      __builtin_amdgcn_global_load_lds((const __attribute__((address_space(1))) void*)gb,
                                       (__attribute__((address_space(3))) void*)(Bs + s * 512), 16, 0, 0);
    }
    __syncthreads();
#pragma unroll
    for (int kk = 0; kk < 2; kk++) {
      s16x8 af[4], bfr[4];
#pragma unroll
      for (int m = 0; m < 4; m++)
        af[m] = *(const s16x8*)((const char*)As + aReadBase + m * (16 * 128) + kk * 64);
#pragma unroll
      for (int n = 0; n < 4; n++)
        bfr[n] = *(const s16x8*)((const char*)Bs + bReadBase + n * (16 * 128) + kk * 64);
#pragma unroll
      for (int m = 0; m < 4; m++)
#pragma unroll
        for (int n = 0; n < 4; n++)
          acc[m][n] = __builtin_amdgcn_mfma_f32_16x16x32_bf16(af[m], bfr[n], acc[m][n], 0, 0, 0);
    }
    __syncthreads();
  }

  if (tid < 128) { scs[tid] = 0.f; sqs[tid] = 0.f; }
  __syncthreads();
  int rbase = m0 + wr * 64 + (lane >> 4) * 4;
  int lc = lane & 15;
#pragma unroll
  for (int n = 0; n < 4; n++) {
    int colb = wc * 64 + n * 16 + lc;
    float bv = bias[colb];
    float s = 0.f, q = 0.f;
#pragma unroll
    for (int m = 0; m < 4; m++) {
#pragma unroll
      for (int j = 0; j < 4; j++) {
        int row = rbase + m * 16 + j;
        float v = fmaxf(acc[m][n][j] + bv, 0.f);
        Cout[(size_t)row * Nn + colb] = v;
        s += v;
        q = fmaf(v, v, q);
      }
    }
    s += __shfl_xor(s, 16); q += __shfl_xor(q, 16);
    s += __shfl_xor(s, 32); q += __shfl_xor(q, 32);
    if ((lane >> 4) == 0) { atomicAdd(&scs[colb], s); atomicAdd(&sqs[colb], q); }
  }
  __syncthreads();
  if (tid < 128) { atomicAdd(&csum[tid], scs[tid]); atomicAdd(&csq[tid], sqs[tid]); }
}

// fc3: fp32 GEMM with BN2 applied to input + relu + fused colstats
__global__ __launch_bounds__(256) void gemm_fc3(const float* __restrict__ A, const float* __restrict__ Bw,
                                                const float* __restrict__ bias,
                                                const float* __restrict__ s2v, const float* __restrict__ q2v,
                                                const float* __restrict__ g2, const float* __restrict__ be2,
                                                float* __restrict__ C, float* __restrict__ s3, float* __restrict__ q3,
                                                int M, float invM) {
  const int BM = 64, BN = 64, BK = 16, K = 128;
  __shared__ float As[BK][BM + 1];
  __shared__ float Bs[BK][BN + 1];
  __shared__ float a2l[128], h2l[128];
  __shared__ float scs[64], sqs[64];
  int tid = threadIdx.x;
  for (int c = tid; c < 128; c += 256) {
    float mu = s2v[c] * invM;
    float var = q2v[c] * invM - mu * mu;
    float sc = g2[c] * rsqrtf(var + 1e-5f);
    a2l[c] = sc;
    h2l[c] = be2[c] - mu * sc;
  }
  if (tid < 64) { scs[tid] = 0.f; sqs[tid] = 0.f; }
  __syncthreads();
  int bm = blockIdx.y * BM;
  int tr = tid / 16, tc = tid % 16;
  float acc[4][4] = {};
  for (int k0 = 0; k0 < K; k0 += BK) {
    for (int i = tid; i < BM * BK; i += 256) {
      int m = i / BK, k = i % BK;
      float v = A[(size_t)(bm + m) * K + k0 + k];
      As[k][m] = fmaf(v, a2l[k0 + k], h2l[k0 + k]);
    }
    for (int i = tid; i < BN * BK; i += 256) {
      int n = i / BK, k = i % BK;
      Bs[k][n] = Bw[(size_t)n * K + k0 + k];
    }
    __syncthreads();
#pragma unroll
    for (int k = 0; k < BK; k++) {
      float a4[4], b4[4];
#pragma unroll
      for (int xx = 0; xx < 4; xx++) a4[xx] = As[k][tr * 4 + xx];
#pragma unroll
      for (int yy = 0; yy < 4; yy++) b4[yy] = Bs[k][tc * 4 + yy];
#pragma unroll
      for (int xx = 0; xx < 4; xx++)
#pragma unroll
        for (int yy = 0; yy < 4; yy++) acc[xx][yy] = fmaf(a4[xx], b4[yy], acc[xx][yy]);
    }
    __syncthreads();
  }
#pragma unroll
  for (int yy = 0; yy < 4; yy++) {
    int n = tc * 4 + yy;
    float bv = bias[n];
    float s = 0.f, q = 0.f;
#pragma unroll
    for (int xx = 0; xx < 4; xx++) {
      int m = bm + tr * 4 + xx;
      float v = fmaxf(acc[xx][yy] + bv, 0.f);
      C[(size_t)m * 64 + n] = v;
      s += v;
      q = fmaf(v, v, q);
    }
    atomicAdd(&scs[n], s);
    atomicAdd(&sqs[n], q);
  }
  __syncthreads();
  if (tid < 64) { atomicAdd(&s3[tid], scs[tid]); atomicAdd(&q3[tid], sqs[tid]); }
}

// fused mean-pool (bf16 H3) + BN3 + output head. one wave per graph.
__global__ __launch_bounds__(256) void pool_head(const unsigned short* __restrict__ H3, const int* __restrict__ goff,
                                                 const float* __restrict__ m3,
                                                 const float* __restrict__ s3, const float* __restrict__ q3,
                                                 const float* __restrict__ g3, const float* __restrict__ be3,
                                                 const float* __restrict__ Wout, const float* __restrict__ bout,
                                                 float* __restrict__ out, int B, float invM) {
  __shared__ float a3l[64], h3l[64];
  if (threadIdx.x < 64) {
    int c = threadIdx.x;
    float mu = s3[c] * invM;
    float var = q3[c] * invM - mu * mu;
    float sc = g3[c] * rsqrtf(var + 1e-5f);
    a3l[c] = sc;
    h3l[c] = be3[c] - mu * sc;
  }
  __syncthreads();
  int w = (int)((blockIdx.x * 256 + threadIdx.x) >> 6);
  if (w >= B) return;
  int lane = threadIdx.x & 63;
  int c = lane & 31, r2 = lane >> 5;
  int a = goff[w], b = goff[w + 1];
  float s = 0.f;
  for (int r = a + r2; r < b; r += 2) s += bf2f(H3[(size_t)r * 32 + c]);
  s += __shfl_down(s, 32);
  float val = 0.f;
  if (r2 == 0) val = (s / fmaxf((float)(b - a), 1.f)) * Wout[c];
  float mv = m3[(size_t)w * 64 + lane];
  val += fmaf(mv, a3l[lane], h3l[lane]) * Wout[32 + lane];
#pragma unroll
  for (int off = 32; off > 0; off >>= 1) val += __shfl_down(val, off);
  if (lane == 0) out[w] = 1.f / (1.f + expf(-(val + bout[0])));
}

extern "C" void kernel_launch(void* const* d_in, const int* in_sizes, int n_in,
                              void* d_out, int out_size, void* d_ws, size_t ws_size,
                              hipStream_t stream) {
  const float* x = (const float*)d_in[0];
  const int* eidx = (const int*)d_in[1];
  const int* batch = (const int*)d_in[2];
  const float* xmord = (const float*)d_in[3];
  const float* Wl1 = (const float*)d_in[4];
  const float* bl1 = (const float*)d_in[5];
  const float* Wr1 = (const float*)d_in[6];
  const float* Wl2 = (const float*)d_in[7];
  const float* bl2 = (const float*)d_in[8];
  const float* Wr2 = (const float*)d_in[9];
  const float* Wl3 = (const float*)d_in[10];
  const float* bl3 = (const float*)d_in[11];
  const float* Wr3 = (const float*)d_in[12];
  const float* Wf1 = (const float*)d_in[13];
  const float* bf1 = (const float*)d_in[14];
  const float* g1 = (const float*)d_in[15];
  const float* be1 = (const float*)d_in[16];
  const float* Wf2 = (const float*)d_in[17];
  const float* bf2 = (const float*)d_in[18];
  const float* g2 = (const float*)d_in[19];
  const float* be2 = (const float*)d_in[20];
  const float* Wf3 = (const float*)d_in[21];
  const float* bf3 = (const float*)d_in[22];
  const float* g3 = (const float*)d_in[23];
  const float* be3 = (const float*)d_in[24];
  const float* Wout = (const float*)d_in[25];
  const float* bout = (const float*)d_in[26];
  float* out = (float*)d_out;

  const int N = in_sizes[2];
  const int E = in_sizes[1] / 2;
  const int B = in_sizes[3] / MORD;
  const int nbins = (N + 1023) >> 10;
  const int* src = eidx;
  const int* dst = eidx + E;

  char* ws = (char*)d_ws;
  size_t off_ = 0;
  auto alloc = [&](size_t bytes) { size_t o = off_; off_ += (bytes + 255) & ~(size_t)255; return o; };
  size_t oX1 = alloc((size_t)N * 8 * 2);
  size_t oAGG1 = alloc((size_t)N * 8 * 2);
  size_t oX2 = alloc((size_t)N * 32 * 2);
  size_t oX3 = alloc((size_t)N * 32 * 2);
  size_t oAGG = alloc((size_t)N * 32 * 2);
  size_t oOff = alloc((size_t)(N + 1) * 4);
  size_t oCsr = alloc((size_t)E * 4);
  size_t oEbuf = alloc((size_t)E * 8);
  size_t oH3 = alloc((size_t)N * 32 * 2);
  size_t oGoff = alloc((size_t)(B + 1) * 4);
  size_t oStats = alloc(8192 * 4);
  size_t oWc1 = alloc(352 * 64 * 2);
  size_t oWc2 = alloc(352 * 64 * 2);
  size_t oWc3 = alloc(352 * 64 * 2);
  size_t oBbf1 = alloc(512 * 896 * 2);
  size_t oW2p = alloc(128 * 512 * 2 + 1024);
  (void)ws_size;

  unsigned short* X1 = (unsigned short*)(ws + oX1);
  unsigned short* AGG1 = (unsigned short*)(ws + oAGG1);
  unsigned short* X2 = (unsigned short*)(ws + oX2);
  unsigned short* X3 = (unsigned short*)(ws + oX3);
  unsigned short* AGG = (unsigned short*)(ws + oAGG);
  int* offp = (int*)(ws + oOff);
  int* csr = (int*)(ws + oCsr);
  unsigned long long* ebuf = (unsigned long long*)(ws + oEbuf);
  unsigned short* H3 = (unsigned short*)(ws + oH3);
  int* goff = (int*)(ws + oGoff);
  float* st = (float*)(ws + oStats);
  int* bhist = (int*)(st + 4096);
  int* boff = (int*)(st + 4608);
  int* gcur = (int*)(st + 5184);
  unsigned short* Wc1 = (unsigned short*)(ws + oWc1);
  unsigned short* Wc2 = (unsigned short*)(ws + oWc2);
  unsigned short* Wc3 = (unsigned short*)(ws + oWc3);
  unsigned short* Bbf1 = (unsigned short*)(ws + oBbf1);
  unsigned short* W2p = (unsigned short*)(ws + oW2p);
  float* b2p = (float*)(ws + oW2p + 131072);
  float *s1 = st, *q1 = st + 512;
  float *s2 = st + 2048, *q2 = st + 2176;
  float *s3 = st + 2560, *q3 = st + 2624;

  // MLP overlays: Abf in X2+X3 span (dead after mfconv3); m1/m2 in AGG; m3 in off/csr.
  unsigned short* Abf = (unsigned short*)(ws + oX2);
  unsigned short* m1 = (unsigned short*)(ws + oAGG);
  float* m2 = (float*)(ws + oAGG + 16777216);
  float* m3 = (float*)(ws + oOff);

  hipMemsetAsync(st, 0, 4608 * 4, stream);

  // CSR build + weight/goff/Wf1 prep (one launch)
  mega_prep<<<dim3(778, 2), 256, 0, stream>>>(dst, bhist, E, nbins,
                                              Wl1, Wr1, Wc1, Wl2, Wr2, Wc2, Wl3, Wr3, Wc3,
                                              batch, goff, N, B, Wf1, Bbf1);
  bin_scan<<<1, 512, 0, stream>>>(bhist, boff, gcur, nbins, E);
  bin_split<<<400, 256, 0, stream>>>(src, dst, gcur, ebuf, E, nbins);
  bin_csr<<<nbins, 256, 0, stream>>>(ebuf, boff, offp, csr, N, E);

  // GNN layers (compact buffers)
  prep_hx1<<<(N + 255) / 256, 256, 0, stream>>>(x, offp, csr, X1, AGG1, N);
  mfconv_mfma<1, 4, 0><<<512, 512, 0, stream>>>(X1, AGG1, Wc1, bl1, offp, X2, N);
  gather_c<<<(int)(((long long)N * 4 + 255) / 256), 256, 0, stream>>>(X2, offp, csr, AGG, N);
  mfconv_mfma<2, 8, 0><<<512, 512, 0, stream>>>(X2, AGG, Wc2, bl2, offp, X3, N);
  gather_c<<<(int)(((long long)N * 4 + 255) / 256), 256, 0, stream>>>(X3, offp, csr, AGG, N);
  mfconv_mfma<2, 8, 1><<<512, 512, 0, stream>>>(X3, AGG, Wc3, bl3, offp, H3, N);

  // MLP head
  cvtA<<<(B * 224 + 255) / 256, 256, 0, stream>>>(xmord, Abf, B);
  gemm_fc1b<<<dim3(4, B / 128), 256, 0, stream>>>(Abf, Bbf1, bf1, m1, s1, q1, B, 512, 896);
  prepW2_bn<<<32, 256, 0, stream>>>(Wf2, bf2, s1, q1, g1, be1, W2p, b2p, 128, 512, 1.f / B);
  gemm_fc2<<<dim3(1, B / 128), 256, 0, stream>>>(m1, W2p, b2p, m2, s2, q2, B, 128, 512);
  gemm_fc3<<<dim3(1, B / 64), 256, 0, stream>>>(m2, Wf3, bf3, s2, q2, g2, be2, m3, s3, q3, B, 1.f / B);
  pool_head<<<(B * 64 + 255) / 256, 256, 0, stream>>>(H3, goff, m3, s3, q3, g3, be3, Wout, bout, out, B, 1.f / B);
}

// Round 14
// 315.090 us; speedup vs baseline: 1.3415x; 1.0378x over previous
//
#include <hip/hip_runtime.h>
#include <hip/hip_bf16.h>
#include <math.h>

#define MORD 862

typedef short s16x8 __attribute__((ext_vector_type(8)));
typedef float f32x4 __attribute__((ext_vector_type(4)));
typedef float f32x4a __attribute__((ext_vector_type(4), aligned(4)));

static __device__ __forceinline__ unsigned short f2bf(float v) {
  __hip_bfloat16 h = __float2bfloat16(v);
  return *(unsigned short*)&h;
}
static __device__ __forceinline__ float bf2f(unsigned short u) {
  unsigned int x = ((unsigned int)u) << 16;
  return *(float*)&x;
}

// ---- Binned CSR build ----
__global__ __launch_bounds__(512) void bin_scan(const int* __restrict__ bhist, int* __restrict__ boff,
                                                int* __restrict__ gcur, int nbins, int E) {
  __shared__ int ts[512];
  int tid = threadIdx.x;
  int v = (tid < nbins) ? bhist[tid] : 0;
  ts[tid] = v;
  __syncthreads();
  for (int st = 1; st < 512; st <<= 1) {
    int t = (tid >= st) ? ts[tid - st] : 0;
    __syncthreads();
    ts[tid] += t;
    __syncthreads();
  }
  int ex = ts[tid] - v;
  if (tid < nbins) { boff[tid] = ex; gcur[tid] = ex; }
  if (tid == 0) boff[nbins] = E;
}

__global__ __launch_bounds__(256) void bin_split(const int* __restrict__ srcA, const int* __restrict__ dstA,
                                                 int* __restrict__ gcur, unsigned long long* __restrict__ ebuf,
                                                 int E, int nbins) {
  __shared__ unsigned long long sbuf[512 * 8];
  __shared__ int lcur[512];
  int tid = threadIdx.x;
  for (int base = blockIdx.x * 1024; base < E; base += (int)gridDim.x * 1024) {
    for (int i = tid; i < nbins; i += 256) lcur[i] = 0;
    __syncthreads();
    int e0 = base + tid * 4;
#pragma unroll
    for (int j = 0; j < 4; j++) {
      int e = e0 + j;
      if (e < E) {
        int d = dstA[e], s = srcA[e];
        int bin = d >> 10;
        unsigned long long p = ((unsigned long long)(unsigned int)d << 32) | (unsigned int)s;
        int slot = atomicAdd(&lcur[bin], 1);
        if (slot < 8) sbuf[bin * 8 + slot] = p;
        else { int g = atomicAdd(&gcur[bin], 1); ebuf[g] = p; }
      }
    }
    __syncthreads();
    for (int b = tid; b < nbins; b += 256) {
      int cnt = min(lcur[b], 8);
      if (cnt > 0) {
        int g = atomicAdd(&gcur[b], cnt);
        for (int k = 0; k < cnt; k++) ebuf[g + k] = sbuf[b * 8 + k];
      }
    }
    __syncthreads();
  }
}

// bin_csr + fused degree histogram (dcnt[11])
__global__ __launch_bounds__(256) void bin_csr(const unsigned long long* __restrict__ ebuf,
                                               const int* __restrict__ boff,
                                               int* __restrict__ off, int* __restrict__ csr,
                                               int* __restrict__ dcnt,
                                               int N, int E) {
  __shared__ int lcur[1024];
  __shared__ int part[256];
  __shared__ int ldc[11];
  int b = blockIdx.x;
  int n0 = b << 10;
  int nn = min(1024, N - n0);
  int e0 = boff[b], e1 = boff[b + 1];
  int tid = threadIdx.x;
  for (int i = tid; i < nn; i += 256) lcur[i] = 0;
  if (tid < 11) ldc[tid] = 0;
  __syncthreads();
  for (int e = e0 + tid; e < e1; e += 256) {
    int d = (int)(ebuf[e] >> 32);
    atomicAdd(&lcur[d - n0], 1);
  }
  __syncthreads();
  int base4 = tid * 4;
  int c0 = (base4 < nn) ? lcur[base4] : 0;
  int c1 = (base4 + 1 < nn) ? lcur[base4 + 1] : 0;
  int c2 = (base4 + 2 < nn) ? lcur[base4 + 2] : 0;
  int c3 = (base4 + 3 < nn) ? lcur[base4 + 3] : 0;
  int tot = c0 + c1 + c2 + c3;
  if (base4 < nn) atomicAdd(&ldc[min(c0, 10)], 1);
  if (base4 + 1 < nn) atomicAdd(&ldc[min(c1, 10)], 1);
  if (base4 + 2 < nn) atomicAdd(&ldc[min(c2, 10)], 1);
  if (base4 + 3 < nn) atomicAdd(&ldc[min(c3, 10)], 1);
  part[tid] = tot;
  __syncthreads();
  for (int st = 1; st < 256; st <<= 1) {
    int t = (tid >= st) ? part[tid - st] : 0;
    __syncthreads();
    part[tid] += t;
    __syncthreads();
  }
  int pre = part[tid] - tot;
  __syncthreads();
  if (base4 < nn)     { lcur[base4]     = pre;                off[n0 + base4]     = e0 + pre; }
  if (base4 + 1 < nn) { lcur[base4 + 1] = pre + c0;           off[n0 + base4 + 1] = e0 + pre + c0; }
  if (base4 + 2 < nn) { lcur[base4 + 2] = pre + c0 + c1;      off[n0 + base4 + 2] = e0 + pre + c0 + c1; }
  if (base4 + 3 < nn) { lcur[base4 + 3] = pre + c0 + c1 + c2; off[n0 + base4 + 3] = e0 + pre + c0 + c1 + c2; }
  if (b == 0 && tid == 0) off[N] = E;
  __syncthreads();
  if (tid < 11 && ldc[tid]) atomicAdd(&dcnt[tid], ldc[tid]);
  for (int e = e0 + tid; e < e1; e += 256) {
    unsigned long long p = ebuf[e];
    int d = (int)(p >> 32);
    int s = (int)(p & 0xffffffffu);
    int slot = atomicAdd(&lcur[d - n0], 1);
    csr[e0 + slot] = s;
  }
}

__global__ void scan11(const int* __restrict__ dcnt, int* __restrict__ dcur) {
  if (threadIdx.x == 0) {
    int run = 0;
    for (int d = 0; d < 11; d++) { dcur[d] = run; run += dcnt[d]; }
  }
}

// degree-sorted permutation: perm[p] = node, degp[p] = degree. Block multisplit.
__global__ __launch_bounds__(256) void perm_scatter(const int* __restrict__ off, int* __restrict__ dcur,
                                                    int* __restrict__ perm, int* __restrict__ degp, int N) {
  __shared__ int ldc[11];
  __shared__ int lbase[11];
  int tid = threadIdx.x;
  if (tid < 11) ldc[tid] = 0;
  __syncthreads();
  int n0 = blockIdx.x * 1024;
  int d[4], slot[4];
#pragma unroll
  for (int j = 0; j < 4; j++) {
    int n = n0 + tid * 4 + j;
    d[j] = -1;
    if (n < N) {
      d[j] = min(off[n + 1] - off[n], 10);
      slot[j] = atomicAdd(&ldc[d[j]], 1);
    }
  }
  __syncthreads();
  if (tid < 11) lbase[tid] = ldc[tid] ? atomicAdd(&dcur[tid], ldc[tid]) : 0;
  __syncthreads();
#pragma unroll
  for (int j = 0; j < 4; j++) {
    int n = n0 + tid * 4 + j;
    if (n < N) {
      int p = lbase[d[j]] + slot[j];
      perm[p] = n;
      degp[p] = d[j];
    }
  }
}

// y=0 (bx<400): bin histogram.  y=1: bx<264 -> Wcat prep; 264<=bx<330 -> graph offsets;
// 330<=bx<778 -> Wf1 fp32->bf16 (padded 896).
__global__ __launch_bounds__(256) void mega_prep(const int* __restrict__ dstA, int* __restrict__ bhist, int E, int nbins,
                                                 const float* __restrict__ Wl1, const float* __restrict__ Wr1,
                                                 unsigned short* __restrict__ Wc1,
                                                 const float* __restrict__ Wl2, const float* __restrict__ Wr2,
                                                 unsigned short* __restrict__ Wc2,
                                                 const float* __restrict__ Wl3, const float* __restrict__ Wr3,
                                                 unsigned short* __restrict__ Wc3,
                                                 const int* __restrict__ batch, int* __restrict__ goff, int N, int B,
                                                 const float* __restrict__ Wf1, unsigned short* __restrict__ Bbf1) {
  if (blockIdx.y == 0) {
    if (blockIdx.x >= 400) return;
    __shared__ int lh[512];
    for (int i = threadIdx.x; i < nbins; i += 256) lh[i] = 0;
    __syncthreads();
    for (int e = blockIdx.x * 256 + threadIdx.x; e < E; e += 400 * 256)
      atomicAdd(&lh[dstA[e] >> 10], 1);
    __syncthreads();
    for (int i = threadIdx.x; i < nbins; i += 256)
      if (lh[i]) atomicAdd(&bhist[i], lh[i]);
    return;
  }
  int bx = blockIdx.x;
  if (bx >= 330) {
    int idx = (bx - 330) * 256 + threadIdx.x;
    if (idx >= 512 * 224) return;
    int r = idx / 224, c4 = (idx % 224) * 4;
#pragma unroll
    for (int j = 0; j < 4; j++) {
      int k = c4 + j;
      float v = (k < MORD) ? Wf1[(size_t)r * MORD + k] : 0.f;
      Bbf1[(size_t)r * 896 + k] = f2bf(v);
    }
    return;
  }
  if (bx >= 264) {
    int b = (bx - 264) * 256 + threadIdx.x;
    if (b > B) return;
    int lo = 0, hi = N;
    while (lo < hi) {
      int mid = (lo + hi) >> 1;
      if (batch[mid] < b) lo = mid + 1; else hi = mid;
    }
    goff[b] = lo;
    return;
  }
  int set = bx / 88;
  const float* Wl = set == 0 ? Wl1 : (set == 1 ? Wl2 : Wl3);
  const float* Wr = set == 0 ? Wr1 : (set == 1 ? Wr2 : Wr3);
  unsigned short* Wc = set == 0 ? Wc1 : (set == 1 ? Wc2 : Wc3);
  int CIN = set == 0 ? 8 : 32;
  int idx = (bx - set * 88) * 256 + threadIdx.x;
  if (idx >= 352 * 64) return;
  int row = idx >> 6, k = idx & 63;
  int d = row >> 5, o = row & 31;
  float v = 0.f;
  if (k < CIN) v = Wl[((size_t)d * 32 + o) * CIN + k];
  else if (k < 2 * CIN) v = Wr[((size_t)d * 32 + o) * CIN + (k - CIN)];
  Wc[idx] = f2bf(v);
}

// layer-1 prep, 4-wide pipelined gather
__global__ __launch_bounds__(256) void prep_hx1(const float* __restrict__ x, const int* __restrict__ off,
                                                const int* __restrict__ csr,
                                                unsigned short* __restrict__ x1, unsigned short* __restrict__ agg1, int N) {
  int n = blockIdx.x * 256 + threadIdx.x;
  if (n >= N) return;
  int a = off[n], b = off[n + 1];
  float ag[8] = {};
  for (int base = a; base < b; base += 4) {
    int rem = b - base;
    int j1 = base + (rem > 1 ? 1 : 0);
    int j2 = base + (rem > 2 ? 2 : 0);
    int j3 = base + (rem > 3 ? 3 : 0);
    int cc0 = csr[base], cc1 = csr[j1], cc2 = csr[j2], cc3 = csr[j3];
    f32x4a v0a = *(const f32x4a*)(x + (size_t)cc0 * 8);
    f32x4a v0b = *(const f32x4a*)(x + (size_t)cc0 * 8 + 4);
    f32x4a v1a = *(const f32x4a*)(x + (size_t)cc1 * 8);
    f32x4a v1b = *(const f32x4a*)(x + (size_t)cc1 * 8 + 4);
    f32x4a v2a = *(const f32x4a*)(x + (size_t)cc2 * 8);
    f32x4a v2b = *(const f32x4a*)(x + (size_t)cc2 * 8 + 4);
    f32x4a v3a = *(const f32x4a*)(x + (size_t)cc3 * 8);
    f32x4a v3b = *(const f32x4a*)(x + (size_t)cc3 * 8 + 4);
    float m1 = rem > 1 ? 1.f : 0.f;
    float m2 = rem > 2 ? 1.f : 0.f;
    float m3 = rem > 3 ? 1.f : 0.f;
#pragma unroll
    for (int t = 0; t < 4; t++) {
      ag[t] += v0a[t];
      ag[t] = fmaf(m1, v1a[t], ag[t]);
      ag[t] = fmaf(m2, v2a[t], ag[t]);
      ag[t] = fmaf(m3, v3a[t], ag[t]);
      ag[t + 4] += v0b[t];
      ag[t + 4] = fmaf(m1, v1b[t], ag[t + 4]);
      ag[t + 4] = fmaf(m2, v2b[t], ag[t + 4]);
      ag[t + 4] = fmaf(m3, v3b[t], ag[t + 4]);
    }
  }
  const float* xo = x + (size_t)n * 8;
  s16x8 w0, w1;
#pragma unroll
  for (int t = 0; t < 8; t++) {
    w0[t] = (short)f2bf(ag[t]);
    w1[t] = (short)f2bf(xo[t]);
  }
  *(s16x8*)(agg1 + (size_t)n * 8) = w0;
  *(s16x8*)(x1 + (size_t)n * 8) = w1;
}

// neighbor-sum over compact X[N][32] -> AGG[N][32], 4-wide pipelined
__global__ __launch_bounds__(256) void gather_c(const unsigned short* __restrict__ X, const int* __restrict__ off,
                                                const int* __restrict__ csr, unsigned short* __restrict__ AGG, int N) {
  long long tid = (long long)blockIdx.x * 256 + threadIdx.x;
  if (tid >= (long long)N * 4) return;
  int n = (int)(tid >> 2), q = (int)(tid & 3);
  int a = off[n], b = off[n + 1];
  float s[8] = {};
  for (int base = a; base < b; base += 4) {
    int rem = b - base;
    int j1 = base + (rem > 1 ? 1 : 0);
    int j2 = base + (rem > 2 ? 2 : 0);
    int j3 = base + (rem > 3 ? 3 : 0);
    int cc0 = csr[base], cc1 = csr[j1], cc2 = csr[j2], cc3 = csr[j3];
    const s16x8 v0 = *(const s16x8*)(X + (size_t)cc0 * 32 + q * 8);
    const s16x8 v1 = *(const s16x8*)(X + (size_t)cc1 * 32 + q * 8);
    const s16x8 v2 = *(const s16x8*)(X + (size_t)cc2 * 32 + q * 8);
    const s16x8 v3 = *(const s16x8*)(X + (size_t)cc3 * 32 + q * 8);
    float m1 = rem > 1 ? 1.f : 0.f;
    float m2 = rem > 2 ? 1.f : 0.f;
    float m3 = rem > 3 ? 1.f : 0.f;
#pragma unroll
    for (int t = 0; t < 8; t++) {
      s[t] += bf2f((unsigned short)v0[t]);
      s[t] = fmaf(m1, bf2f((unsigned short)v1[t]), s[t]);
      s[t] = fmaf(m2, bf2f((unsigned short)v2[t]), s[t]);
      s[t] = fmaf(m3, bf2f((unsigned short)v3[t]), s[t]);
    }
  }
  s16x8 w;
#pragma unroll
  for (int t = 0; t < 8; t++) w[t] = (short)f2bf(s[t]);
  *(s16x8*)(AGG + (size_t)n * 32 + q * 8) = w;
}

// MFMA degree-sorted transform: tiles of 128 permuted rows; only the tile's degree range computed.
template <int KS, int ACH, int OUTMODE>
__global__ __launch_bounds__(512, 4) void mfconv_mfma(const unsigned short* __restrict__ xin,
                                                      const unsigned short* __restrict__ agg,
                                                      const unsigned short* __restrict__ Wcat,
                                                      const float* __restrict__ bl,
                                                      const int* __restrict__ perm,
                                                      const int* __restrict__ degp,
                                                      unsigned short* __restrict__ outp, int N) {
  __shared__ __align__(16) unsigned short As[128 * ACH * 8];
  __shared__ __align__(16) unsigned short Bs[352 * 64];
  __shared__ float sbias[352];
  const int tid = threadIdx.x;
  const int wid = tid >> 6, lane = tid & 63;

  for (int s = wid; s < 44; s += 8) {
    int c = s * 64 + lane;
    int cs = c ^ ((c >> 3) & 7);
    __builtin_amdgcn_global_load_lds((const __attribute__((address_space(1))) void*)((const char*)Wcat + (size_t)cs * 16),
                                     (__attribute__((address_space(3))) void*)((char*)Bs + s * 1024), 16, 0, 0);
  }
  for (int i = tid; i < 352; i += 512) sbias[i] = bl[i];

  const int ra = wid * 16 + (lane & 15);
  const int g4 = lane >> 4;
  const int lc = lane & 15;
  const int rl0 = wid * 16 + g4 * 4;

  const int ntiles = N >> 7;
  for (int t = blockIdx.x; t < ntiles; t += (int)gridDim.x) {
    const int row0 = t << 7;
    __syncthreads();
    // stage A rows via perm gather (per-lane global source)
    for (int s = wid; s < 2 * ACH; s += 8) {
      int c = s * 64 + lane;
      int row = c / ACH, ch = c & (ACH - 1);
      int cs = ch ^ (row & (ACH - 1));
      size_t g = (size_t)perm[row0 + row];
      const char* srcp;
      if (ACH == 4) {
        srcp = (cs == 1) ? (const char*)xin + g * 16 : (const char*)agg + g * 16;
      } else {
        srcp = (cs < 4) ? (const char*)agg + g * 64 + (size_t)cs * 16
                        : (const char*)xin + g * 64 + (size_t)(cs - 4) * 16;
      }
      __builtin_amdgcn_global_load_lds((const __attribute__((address_space(1))) void*)srcp,
                                       (__attribute__((address_space(3))) void*)((char*)As + s * 1024), 16, 0, 0);
    }
    int dj[4], pj[4];
#pragma unroll
    for (int j = 0; j < 4; j++) {
      int rr = row0 + rl0 + j;
      dj[j] = degp[rr];
      pj[j] = perm[rr];
    }
    int dmin = degp[row0], dmax = degp[row0 + 127];
    __syncthreads();

    s16x8 af[KS];
#pragma unroll
    for (int kk = 0; kk < KS; kk++) {
      int cha = (kk * 4 + g4) ^ (ra & (ACH - 1));
      af[kk] = *(const s16x8*)((const char*)As + (size_t)(ra * ACH + cha) * 16);
    }

    for (int nn2 = dmin * 2; nn2 <= dmax * 2 + 1; nn2++) {
      f32x4 acc = {};
      int rb = nn2 * 16 + lc;
#pragma unroll
      for (int kk = 0; kk < KS; kk++) {
        int cb = rb * 8 + kk * 4 + g4;
        s16x8 bf = *(const s16x8*)((const char*)Bs + (size_t)(cb ^ (rb & 7)) * 16);
        acc = __builtin_amdgcn_mfma_f32_16x16x32_bf16(af[kk], bf, acc, 0, 0, 0);
      }
      int dsel = nn2 >> 1;
      int o = (nn2 & 1) * 16 + lc;
      float bv = sbias[dsel * 32 + o];
#pragma unroll
      for (int j = 0; j < 4; j++) {
        if (dj[j] == dsel) {
          float v = acc[j] + bv;
          if (OUTMODE == 0) v = fmaxf(v, 0.f);
          outp[(size_t)pj[j] * 32 + o] = f2bf(v);
        }
      }
    }
  }
}

// A (xmord) fp32->bf16 conversion (K padded 862->896)
__global__ __launch_bounds__(256) void cvtA(const float* __restrict__ xm, unsigned short* __restrict__ Abf, int B) {
  const int q = 224;
  int t = blockIdx.x * 256 + threadIdx.x;
  if (t >= B * q) return;
  int r = t / q, c4 = (t % q) * 4;
#pragma unroll
  for (int j = 0; j < 4; j++) {
    int k = c4 + j;
    float v = (k < MORD) ? xm[(size_t)r * MORD + k] : 0.f;
    Abf[(size_t)r * 896 + k] = f2bf(v);
  }
}

// fc1: bf16 MFMA GEMM 128x128 BK=64 global_load_lds; relu+bias -> bf16; fused colstats; XCD swizzle.
__global__ __launch_bounds__(256) void gemm_fc1b(const unsigned short* __restrict__ A,
                                                 const unsigned short* __restrict__ Bw,
                                                 const float* __restrict__ bias,
                                                 unsigned short* __restrict__ Cout,
                                                 float* __restrict__ csum, float* __restrict__ csq,
                                                 int M, int Nn, int Kp) {
  __shared__ __align__(16) unsigned short As[128 * 64];
  __shared__ __align__(16) unsigned short Bs[128 * 64];
  __shared__ float scs[128], sqs[128];
  int tid = threadIdx.x;
  int wid = tid >> 6, lane = tid & 63;
  int lin = blockIdx.x + blockIdx.y * 4;
  int swz = (lin & 7) * 64 + (lin >> 3);
  int m0 = (swz >> 2) * 128, n0 = (swz & 3) * 128;
  int wr = wid >> 1, wc = wid & 1;
  f32x4 acc[4][4] = {};

  int srow_l = lane >> 3;
  int scol = (lane & 7) * 8;
  int aReadBase = ((wr * 64 + (lane & 15)) * 128) + ((lane >> 4) * 16);
  int bReadBase = ((wc * 64 + (lane & 15)) * 128) + ((lane >> 4) * 16);

  const unsigned short* Ablk = A + (size_t)m0 * Kp;
  const unsigned short* Bblk = Bw + (size_t)n0 * Kp;

  for (int k0 = 0; k0 < Kp; k0 += 64) {
#pragma unroll
    for (int i = 0; i < 4; i++) {
      int s = wid * 4 + i;
      int row = s * 8 + srow_l;
      const unsigned short* ga = Ablk + (size_t)row * Kp + k0 + scol;
      const unsigned short* gb = Bblk + (size_t)row * Kp + k0 + scol;
      __builtin_amdgcn_global_load_lds((const __attribute__((address_space(1))) void*)ga,
                                       (__attribute__((address_space(3))) void*)(As + s * 512), 16, 0, 0);
      __builtin_amdgcn_global_load_lds((const __attribute__((address_space(1))) void*)gb,
                                       (__attribute__((address_space(3))) void*)(Bs + s * 512), 16, 0, 0);
    }
    __syncthreads();
#pragma unroll
    for (int kk = 0; kk < 2; kk++) {
      s16x8 af[4], bfr[4];
#pragma unroll
      for (int m = 0; m < 4; m++)
        af[m] = *(const s16x8*)((const char*)As + aReadBase + m * (16 * 128) + kk * 64);
#pragma unroll
      for (int n = 0; n < 4; n++)
        bfr[n] = *(const s16x8*)((const char*)Bs + bReadBase + n * (16 * 128) + kk * 64);
#pragma unroll
      for (int m = 0; m < 4; m++)
#pragma unroll
        for (int n = 0; n < 4; n++)
          acc[m][n] = __builtin_amdgcn_mfma_f32_16x16x32_bf16(af[m], bfr[n], acc[m][n], 0, 0, 0);
    }
    __syncthreads();
  }

  if (tid < 128) { scs[tid] = 0.f; sqs[tid] = 0.f; }
  __syncthreads();
  int rbase = m0 + wr * 64 + (lane >> 4) * 4;
  int lc = lane & 15;
#pragma unroll
  for (int n = 0; n < 4; n++) {
    int colb = wc * 64 + n * 16 + lc;
    float bv = bias[n0 + colb];
    float s = 0.f, q = 0.f;
#pragma unroll
    for (int m = 0; m < 4; m++) {
#pragma unroll
      for (int j = 0; j < 4; j++) {
        int row = rbase + m * 16 + j;
        float v = fmaxf(acc[m][n][j] + bv, 0.f);
        Cout[(size_t)row * Nn + n0 + colb] = f2bf(v);
        s += v;
        q = fmaf(v, v, q);
      }
    }
    s += __shfl_xor(s, 16); q += __shfl_xor(q, 16);
    s += __shfl_xor(s, 32); q += __shfl_xor(q, 32);
    if ((lane >> 4) == 0) { atomicAdd(&scs[colb], s); atomicAdd(&sqs[colb], q); }
  }
  __syncthreads();
  if (tid < 128) { atomicAdd(&csum[n0 + tid], scs[tid]); atomicAdd(&csq[n0 + tid], sqs[tid]); }
}

// prepW2 with BN1 folded
__global__ __launch_bounds__(256) void prepW2_bn(const float* __restrict__ W2, const float* __restrict__ b2,
                                                 const float* __restrict__ s1, const float* __restrict__ q1,
                                                 const float* __restrict__ g1, const float* __restrict__ be1,
                                                 unsigned short* __restrict__ W2p, float* __restrict__ b2p,
                                                 int Nn, int K, float invM) {
  __shared__ float a1l[512], h1l[512];
  for (int c = threadIdx.x; c < K; c += 256) {
    float mu = s1[c] * invM;
    float var = q1[c] * invM - mu * mu;
    float sc = g1[c] * rsqrtf(var + 1e-5f);
    a1l[c] = sc;
    h1l[c] = be1[c] - mu * sc;
  }
  __syncthreads();
  int wid = threadIdx.x >> 6, lane = threadIdx.x & 63;
  int n = blockIdx.x * 4 + wid;
  if (n >= Nn) return;
  float part = 0.f;
  for (int k = lane; k < K; k += 64) {
    float w = W2[(size_t)n * K + k];
    W2p[(size_t)n * K + k] = f2bf(w * a1l[k]);
    part = fmaf(w, h1l[k], part);
  }
#pragma unroll
  for (int off = 32; off > 0; off >>= 1) part += __shfl_down(part, off, 64);
  if (lane == 0) b2p[n] = b2[n] + part;
}

// fc2: bf16 MFMA GEMM 128x128, f32 out, relu, fused colstats
__global__ __launch_bounds__(256) void gemm_fc2(const unsigned short* __restrict__ A,
                                                const unsigned short* __restrict__ Bw,
                                                const float* __restrict__ bias,
                                                float* __restrict__ Cout,
                                                float* __restrict__ csum, float* __restrict__ csq,
                                                int M, int Nn, int Kp) {
  __shared__ __align__(16) unsigned short As[128 * 64];
  __shared__ __align__(16) unsigned short Bs[128 * 64];
  __shared__ float scs[128], sqs[128];
  int tid = threadIdx.x;
  int wid = tid >> 6, lane = tid & 63;
  int m0 = blockIdx.y * 128;
  int wr = wid >> 1, wc = wid & 1;
  f32x4 acc[4][4] = {};

  int srow_l = lane >> 3;
  int scol = (lane & 7) * 8;
  int aReadBase = ((wr * 64 + (lane & 15)) * 128) + ((lane >> 4) * 16);
  int bReadBase = ((wc * 64 + (lane & 15)) * 128) + ((lane >> 4) * 16);

  const unsigned short* Ablk = A + (size_t)m0 * Kp;

  for (int k0 = 0; k0 < Kp; k0 += 64) {
#pragma unroll
    for (int i = 0; i < 4; i++) {
      int s = wid * 4 + i;
      int row = s * 8 + srow_l;
      const unsigned short* ga = Ablk + (size_t)row * Kp + k0 + scol;
      const unsigned short* gb = Bw + (size_t)row * Kp + k0 + scol;
      __builtin_amdgcn_global_load_lds((const __attribute__((address_space(1))) void*)ga,
                                       (__attribute__((address_space(3))) void*)(As + s * 512), 16, 0, 0);
      __builtin_amdgcn_global_load_lds((const __attribute__((address_space(1))) void*)gb,
                                       (__attribute__((address_space(3))) void*)(Bs + s * 512), 16, 0, 0);
    }
    __syncthreads();
#pragma unroll
    for (int kk = 0; kk < 2; kk++) {
      s16x8 af[4], bfr[4];
#pragma unroll
      for (int m = 0; m < 4; m++)
        af[m] = *(const s16x8*)((const char*)As + aReadBase + m * (16 * 128) + kk * 64);
#pragma unroll
      for (int n = 0; n < 4; n++)
        bfr[n] = *(const s16x8*)((const char*)Bs + bReadBase + n * (16 * 128) + kk * 64);
#pragma unroll
      for (int m = 0; m < 4; m++)
#pragma unroll
        for (int n = 0; n < 4; n++)
          acc[m][n] = __builtin_amdgcn_mfma_f32_16x16x32_bf16(af[m], bfr[n], acc[m][n], 0, 0, 0);
    }
    __syncthreads();
  }

  if (tid < 128) { scs[tid] = 0.f; sqs[tid] = 0.f; }
  __syncthreads();
  int rbase = m0 + wr * 64 + (lane >> 4) * 4;
  int lc = lane & 15;
#pragma unroll
  for (int n = 0; n < 4; n++) {
    int colb = wc * 64 + n * 16 + lc;
    float bv = bias[colb];
    float s = 0.f, q = 0.f;
#pragma unroll
    for (int m = 0; m < 4; m++) {
#pragma unroll
      for (int j = 0; j < 4; j++) {
        int row = rbase + m * 16 + j;
        float v = fmaxf(acc[m][n][j] + bv, 0.f);
        Cout[(size_t)row * Nn + colb] = v;
        s += v;
        q = fmaf(v, v, q);
      }
    }
    s += __shfl_xor(s, 16); q += __shfl_xor(q, 16);
    s += __shfl_xor(s, 32); q += __shfl_xor(q, 32);
    if ((lane >> 4) == 0) { atomicAdd(&scs[colb], s); atomicAdd(&sqs[colb], q); }
  }
  __syncthreads();
  if (tid < 128) { atomicAdd(&csum[tid], scs[tid]); atomicAdd(&csq[tid], sqs[tid]); }
}

// fc3: fp32 GEMM with BN2 applied to input + relu + fused colstats
__global__ __launch_bounds__(256) void gemm_fc3(const float* __restrict__ A, const float* __restrict__ Bw,
                                                const float* __restrict__ bias,
                                                const float* __restrict__ s2v, const float* __restrict__ q2v,
                                                const float* __restrict__ g2, const float* __restrict__ be2,
                                                float* __restrict__ C, float* __restrict__ s3, float* __restrict__ q3,
                                                int M, float invM) {
  const int BM = 64, BN = 64, BK = 16, K = 128;
  __shared__ float As[BK][BM + 1];
  __shared__ float Bs[BK][BN + 1];
  __shared__ float a2l[128], h2l[128];
  __shared__ float scs[64], sqs[64];
  int tid = threadIdx.x;
  for (int c = tid; c < 128; c += 256) {
    float mu = s2v[c] * invM;
    float var = q2v[c] * invM - mu * mu;
    float sc = g2[c] * rsqrtf(var + 1e-5f);
    a2l[c] = sc;
    h2l[c] = be2[c] - mu * sc;
  }
  if (tid < 64) { scs[tid] = 0.f; sqs[tid] = 0.f; }
  __syncthreads();
  int bm = blockIdx.y * BM;
  int tr = tid / 16, tc = tid % 16;
  float acc[4][4] = {};
  for (int k0 = 0; k0 < K; k0 += BK) {
    for (int i = tid; i < BM * BK; i += 256) {
      int m = i / BK, k = i % BK;
      float v = A[(size_t)(bm + m) * K + k0 + k];
      As[k][m] = fmaf(v, a2l[k0 + k], h2l[k0 + k]);
    }
    for (int i = tid; i < BN * BK; i += 256) {
      int n = i / BK, k = i % BK;
      Bs[k][n] = Bw[(size_t)n * K + k0 + k];
    }
    __syncthreads();
#pragma unroll
    for (int k = 0; k < BK; k++) {
      float a4[4], b4[4];
#pragma unroll
      for (int xx = 0; xx < 4; xx++) a4[xx] = As[k][tr * 4 + xx];
#pragma unroll
      for (int yy = 0; yy < 4; yy++) b4[yy] = Bs[k][tc * 4 + yy];
#pragma unroll
      for (int xx = 0; xx < 4; xx++)
#pragma unroll
        for (int yy = 0; yy < 4; yy++) acc[xx][yy] = fmaf(a4[xx], b4[yy], acc[xx][yy]);
    }
    __syncthreads();
  }
#pragma unroll
  for (int yy = 0; yy < 4; yy++) {
    int n = tc * 4 + yy;
    float bv = bias[n];
    float s = 0.f, q = 0.f;
#pragma unroll
    for (int xx = 0; xx < 4; xx++) {
      int m = bm + tr * 4 + xx;
      float v = fmaxf(acc[xx][yy] + bv, 0.f);
      C[(size_t)m * 64 + n] = v;
      s += v;
      q = fmaf(v, v, q);
    }
    atomicAdd(&scs[n], s);
    atomicAdd(&sqs[n], q);
  }
  __syncthreads();
  if (tid < 64) { atomicAdd(&s3[tid], scs[tid]); atomicAdd(&q3[tid], sqs[tid]); }
}

// fused mean-pool (bf16 H3) + BN3 + output head. one wave per graph.
__global__ __launch_bounds__(256) void pool_head(const unsigned short* __restrict__ H3, const int* __restrict__ goff,
                                                 const float* __restrict__ m3,
                                                 const float* __restrict__ s3, const float* __restrict__ q3,
                                                 const float* __restrict__ g3, const float* __restrict__ be3,
                                                 const float* __restrict__ Wout, const float* __restrict__ bout,
                                                 float* __restrict__ out, int B, float invM) {
  __shared__ float a3l[64], h3l[64];
  if (threadIdx.x < 64) {
    int c = threadIdx.x;
    float mu = s3[c] * invM;
    float var = q3[c] * invM - mu * mu;
    float sc = g3[c] * rsqrtf(var + 1e-5f);
    a3l[c] = sc;
    h3l[c] = be3[c] - mu * sc;
  }
  __syncthreads();
  int w = (int)((blockIdx.x * 256 + threadIdx.x) >> 6);
  if (w >= B) return;
  int lane = threadIdx.x & 63;
  int c = lane & 31, r2 = lane >> 5;
  int a = goff[w], b = goff[w + 1];
  float s = 0.f;
  for (int r = a + r2; r < b; r += 2) s += bf2f(H3[(size_t)r * 32 + c]);
  s += __shfl_down(s, 32);
  float val = 0.f;
  if (r2 == 0) val = (s / fmaxf((float)(b - a), 1.f)) * Wout[c];
  float mv = m3[(size_t)w * 64 + lane];
  val += fmaf(mv, a3l[lane], h3l[lane]) * Wout[32 + lane];
#pragma unroll
  for (int off = 32; off > 0; off >>= 1) val += __shfl_down(val, off);
  if (lane == 0) out[w] = 1.f / (1.f + expf(-(val + bout[0])));
}

extern "C" void kernel_launch(void* const* d_in, const int* in_sizes, int n_in,
                              void* d_out, int out_size, void* d_ws, size_t ws_size,
                              hipStream_t stream) {
  const float* x = (const float*)d_in[0];
  const int* eidx = (const int*)d_in[1];
  const int* batch = (const int*)d_in[2];
  const float* xmord = (const float*)d_in[3];
  const float* Wl1 = (const float*)d_in[4];
  const float* bl1 = (const float*)d_in[5];
  const float* Wr1 = (const float*)d_in[6];
  const float* Wl2 = (const float*)d_in[7];
  const float* bl2 = (const float*)d_in[8];
  const float* Wr2 = (const float*)d_in[9];
  const float* Wl3 = (const float*)d_in[10];
  const float* bl3 = (const float*)d_in[11];
  const float* Wr3 = (const float*)d_in[12];
  const float* Wf1 = (const float*)d_in[13];
  const float* bf1 = (const float*)d_in[14];
  const float* g1 = (const float*)d_in[15];
  const float* be1 = (const float*)d_in[16];
  const float* Wf2 = (const float*)d_in[17];
  const float* bf2 = (const float*)d_in[18];
  const float* g2 = (const float*)d_in[19];
  const float* be2 = (const float*)d_in[20];
  const float* Wf3 = (const float*)d_in[21];
  const float* bf3 = (const float*)d_in[22];
  const float* g3 = (const float*)d_in[23];
  const float* be3 = (const float*)d_in[24];
  const float* Wout = (const float*)d_in[25];
  const float* bout = (const float*)d_in[26];
  float* out = (float*)d_out;

  const int N = in_sizes[2];
  const int E = in_sizes[1] / 2;
  const int B = in_sizes[3] / MORD;
  const int nbins = (N + 1023) >> 10;
  const int* src = eidx;
  const int* dst = eidx + E;

  char* ws = (char*)d_ws;
  size_t off_ = 0;
  auto alloc = [&](size_t bytes) { size_t o = off_; off_ += (bytes + 255) & ~(size_t)255; return o; };
  size_t oX1 = alloc((size_t)N * 8 * 2);
  size_t oAGG1 = alloc((size_t)N * 8 * 2);
  size_t oX2 = alloc((size_t)N * 32 * 2);
  size_t oX3 = alloc((size_t)N * 32 * 2);
  size_t oAGG = alloc((size_t)N * 32 * 2);
  size_t oOff = alloc((size_t)(N + 1) * 4);
  size_t oCsr = alloc((size_t)E * 4);
  size_t oEbuf = alloc((size_t)E * 8);
  size_t oH3 = alloc((size_t)N * 32 * 2);
  size_t oGoff = alloc((size_t)(B + 1) * 4);
  size_t oStats = alloc(8192 * 4);
  size_t oWc1 = alloc(352 * 64 * 2);
  size_t oWc2 = alloc(352 * 64 * 2);
  size_t oWc3 = alloc(352 * 64 * 2);
  size_t oBbf1 = alloc(512 * 896 * 2);
  size_t oW2p = alloc(128 * 512 * 2 + 1024);
  size_t oPerm = alloc((size_t)N * 4);
  size_t oDegp = alloc((size_t)N * 4);
  (void)ws_size;

  unsigned short* X1 = (unsigned short*)(ws + oX1);
  unsigned short* AGG1 = (unsigned short*)(ws + oAGG1);
  unsigned short* X2 = (unsigned short*)(ws + oX2);
  unsigned short* X3 = (unsigned short*)(ws + oX3);
  unsigned short* AGG = (unsigned short*)(ws + oAGG);
  int* offp = (int*)(ws + oOff);
  int* csr = (int*)(ws + oCsr);
  unsigned long long* ebuf = (unsigned long long*)(ws + oEbuf);
  unsigned short* H3 = (unsigned short*)(ws + oH3);
  int* goff = (int*)(ws + oGoff);
  float* st = (float*)(ws + oStats);
  int* bhist = (int*)(st + 4096);
  int* boff = (int*)(st + 4608);
  int* gcur = (int*)(st + 5184);
  int* dcnt = (int*)(st + 5696);
  int* dcur = (int*)(st + 5728);
  unsigned short* Wc1 = (unsigned short*)(ws + oWc1);
  unsigned short* Wc2 = (unsigned short*)(ws + oWc2);
  unsigned short* Wc3 = (unsigned short*)(ws + oWc3);
  unsigned short* Bbf1 = (unsigned short*)(ws + oBbf1);
  unsigned short* W2p = (unsigned short*)(ws + oW2p);
  float* b2p = (float*)(ws + oW2p + 131072);
  int* perm = (int*)(ws + oPerm);
  int* degp = (int*)(ws + oDegp);
  float *s1 = st, *q1 = st + 512;
  float *s2 = st + 2048, *q2 = st + 2176;
  float *s3 = st + 2560, *q3 = st + 2624;

  // MLP overlays: Abf in X2+X3 span (dead after mfconv3); m1/m2 in AGG; m3 in off/csr.
  unsigned short* Abf = (unsigned short*)(ws + oX2);
  unsigned short* m1 = (unsigned short*)(ws + oAGG);
  float* m2 = (float*)(ws + oAGG + 16777216);
  float* m3 = (float*)(ws + oOff);

  hipMemsetAsync(st, 0, 5728 * 4, stream);

  // CSR build + weight/goff/Wf1 prep
  mega_prep<<<dim3(778, 2), 256, 0, stream>>>(dst, bhist, E, nbins,
                                              Wl1, Wr1, Wc1, Wl2, Wr2, Wc2, Wl3, Wr3, Wc3,
                                              batch, goff, N, B, Wf1, Bbf1);
  bin_scan<<<1, 512, 0, stream>>>(bhist, boff, gcur, nbins, E);
  bin_split<<<400, 256, 0, stream>>>(src, dst, gcur, ebuf, E, nbins);
  bin_csr<<<nbins, 256, 0, stream>>>(ebuf, boff, offp, csr, dcnt, N, E);
  scan11<<<1, 64, 0, stream>>>(dcnt, dcur);
  perm_scatter<<<(N + 1023) / 1024, 256, 0, stream>>>(offp, dcur, perm, degp, N);

  // GNN layers (degree-sorted MFMA)
  prep_hx1<<<(N + 255) / 256, 256, 0, stream>>>(x, offp, csr, X1, AGG1, N);
  mfconv_mfma<1, 4, 0><<<512, 512, 0, stream>>>(X1, AGG1, Wc1, bl1, perm, degp, X2, N);
  gather_c<<<(int)(((long long)N * 4 + 255) / 256), 256, 0, stream>>>(X2, offp, csr, AGG, N);
  mfconv_mfma<2, 8, 0><<<512, 512, 0, stream>>>(X2, AGG, Wc2, bl2, perm, degp, X3, N);
  gather_c<<<(int)(((long long)N * 4 + 255) / 256), 256, 0, stream>>>(X3, offp, csr, AGG, N);
  mfconv_mfma<2, 8, 1><<<512, 512, 0, stream>>>(X3, AGG, Wc3, bl3, perm, degp, H3, N);

  // MLP head
  cvtA<<<(B * 224 + 255) / 256, 256, 0, stream>>>(xmord, Abf, B);
  gemm_fc1b<<<dim3(4, B / 128), 256, 0, stream>>>(Abf, Bbf1, bf1, m1, s1, q1, B, 512, 896);
  prepW2_bn<<<32, 256, 0, stream>>>(Wf2, bf2, s1, q1, g1, be1, W2p, b2p, 128, 512, 1.f / B);
  gemm_fc2<<<dim3(1, B / 128), 256, 0, stream>>>(m1, W2p, b2p, m2, s2, q2, B, 128, 512);
  gemm_fc3<<<dim3(1, B / 64), 256, 0, stream>>>(m2, Wf3, bf3, s2, q2, g2, be2, m3, s3, q3, B, 1.f / B);
  pool_head<<<(B * 64 + 255) / 256, 256, 0, stream>>>(H3, goff, m3, s3, q3, g3, be3, Wout, bout, out, B, 1.f / B);
}

// Round 15
// 303.392 us; speedup vs baseline: 1.3932x; 1.0386x over previous
//
#include <hip/hip_runtime.h>
#include <hip/hip_bf16.h>
#include <math.h>

#define MORD 862

typedef short s16x8 __attribute__((ext_vector_type(8)));
typedef float f32x4 __attribute__((ext_vector_type(4)));
typedef float f32x4a __attribute__((ext_vector_type(4), aligned(4)));

static __device__ __forceinline__ unsigned short f2bf(float v) {
  __hip_bfloat16 h = __float2bfloat16(v);
  return *(unsigned short*)&h;
}
static __device__ __forceinline__ float bf2f(unsigned short u) {
  unsigned int x = ((unsigned int)u) << 16;
  return *(float*)&x;
}

// ---- Binned CSR build ----
__global__ __launch_bounds__(512) void bin_scan(const int* __restrict__ bhist, int* __restrict__ boff,
                                                int* __restrict__ gcur, int nbins, int E) {
  __shared__ int ts[512];
  int tid = threadIdx.x;
  int v = (tid < nbins) ? bhist[tid] : 0;
  ts[tid] = v;
  __syncthreads();
  for (int st = 1; st < 512; st <<= 1) {
    int t = (tid >= st) ? ts[tid - st] : 0;
    __syncthreads();
    ts[tid] += t;
    __syncthreads();
  }
  int ex = ts[tid] - v;
  if (tid < nbins) { boff[tid] = ex; gcur[tid] = ex; }
  if (tid == 0) boff[nbins] = E;
}

__global__ __launch_bounds__(256) void bin_split(const int* __restrict__ srcA, const int* __restrict__ dstA,
                                                 int* __restrict__ gcur, unsigned long long* __restrict__ ebuf,
                                                 int E, int nbins) {
  __shared__ unsigned long long sbuf[512 * 8];
  __shared__ int lcur[512];
  int tid = threadIdx.x;
  for (int base = blockIdx.x * 1024; base < E; base += (int)gridDim.x * 1024) {
    for (int i = tid; i < nbins; i += 256) lcur[i] = 0;
    __syncthreads();
    int e0 = base + tid * 4;
#pragma unroll
    for (int j = 0; j < 4; j++) {
      int e = e0 + j;
      if (e < E) {
        int d = dstA[e], s = srcA[e];
        int bin = d >> 10;
        unsigned long long p = ((unsigned long long)(unsigned int)d << 32) | (unsigned int)s;
        int slot = atomicAdd(&lcur[bin], 1);
        if (slot < 8) sbuf[bin * 8 + slot] = p;
        else { int g = atomicAdd(&gcur[bin], 1); ebuf[g] = p; }
      }
    }
    __syncthreads();
    for (int b = tid; b < nbins; b += 256) {
      int cnt = min(lcur[b], 8);
      if (cnt > 0) {
        int g = atomicAdd(&gcur[b], cnt);
        for (int k = 0; k < cnt; k++) ebuf[g + k] = sbuf[b * 8 + k];
      }
    }
    __syncthreads();
  }
}

// bin_csr + fused degree histogram (dcnt[11])
__global__ __launch_bounds__(256) void bin_csr(const unsigned long long* __restrict__ ebuf,
                                               const int* __restrict__ boff,
                                               int* __restrict__ off, int* __restrict__ csr,
                                               int* __restrict__ dcnt,
                                               int N, int E) {
  __shared__ int lcur[1024];
  __shared__ int part[256];
  __shared__ int ldc[11];
  int b = blockIdx.x;
  int n0 = b << 10;
  int nn = min(1024, N - n0);
  int e0 = boff[b], e1 = boff[b + 1];
  int tid = threadIdx.x;
  for (int i = tid; i < nn; i += 256) lcur[i] = 0;
  if (tid < 11) ldc[tid] = 0;
  __syncthreads();
  for (int e = e0 + tid; e < e1; e += 256) {
    int d = (int)(ebuf[e] >> 32);
    atomicAdd(&lcur[d - n0], 1);
  }
  __syncthreads();
  int base4 = tid * 4;
  int c0 = (base4 < nn) ? lcur[base4] : 0;
  int c1 = (base4 + 1 < nn) ? lcur[base4 + 1] : 0;
  int c2 = (base4 + 2 < nn) ? lcur[base4 + 2] : 0;
  int c3 = (base4 + 3 < nn) ? lcur[base4 + 3] : 0;
  int tot = c0 + c1 + c2 + c3;
  if (base4 < nn) atomicAdd(&ldc[min(c0, 10)], 1);
  if (base4 + 1 < nn) atomicAdd(&ldc[min(c1, 10)], 1);
  if (base4 + 2 < nn) atomicAdd(&ldc[min(c2, 10)], 1);
  if (base4 + 3 < nn) atomicAdd(&ldc[min(c3, 10)], 1);
  part[tid] = tot;
  __syncthreads();
  for (int st = 1; st < 256; st <<= 1) {
    int t = (tid >= st) ? part[tid - st] : 0;
    __syncthreads();
    part[tid] += t;
    __syncthreads();
  }
  int pre = part[tid] - tot;
  __syncthreads();
  if (base4 < nn)     { lcur[base4]     = pre;                off[n0 + base4]     = e0 + pre; }
  if (base4 + 1 < nn) { lcur[base4 + 1] = pre + c0;           off[n0 + base4 + 1] = e0 + pre + c0; }
  if (base4 + 2 < nn) { lcur[base4 + 2] = pre + c0 + c1;      off[n0 + base4 + 2] = e0 + pre + c0 + c1; }
  if (base4 + 3 < nn) { lcur[base4 + 3] = pre + c0 + c1 + c2; off[n0 + base4 + 3] = e0 + pre + c0 + c1 + c2; }
  if (b == 0 && tid == 0) off[N] = E;
  __syncthreads();
  if (tid < 11 && ldc[tid]) atomicAdd(&dcnt[tid], ldc[tid]);
  for (int e = e0 + tid; e < e1; e += 256) {
    unsigned long long p = ebuf[e];
    int d = (int)(p >> 32);
    int s = (int)(p & 0xffffffffu);
    int slot = atomicAdd(&lcur[d - n0], 1);
    csr[e0 + slot] = s;
  }
}

// y=0 (bx<400): bin histogram.
// y=1: bx<264 Wcat; 264..329 goff; 330..777 Wf1 cvt; 778.. xmord cvt (Abf).
__global__ __launch_bounds__(256) void mega_prep(const int* __restrict__ dstA, int* __restrict__ bhist, int E, int nbins,
                                                 const float* __restrict__ Wl1, const float* __restrict__ Wr1,
                                                 unsigned short* __restrict__ Wc1,
                                                 const float* __restrict__ Wl2, const float* __restrict__ Wr2,
                                                 unsigned short* __restrict__ Wc2,
                                                 const float* __restrict__ Wl3, const float* __restrict__ Wr3,
                                                 unsigned short* __restrict__ Wc3,
                                                 const int* __restrict__ batch, int* __restrict__ goff, int N, int B,
                                                 const float* __restrict__ Wf1, unsigned short* __restrict__ Bbf1,
                                                 const float* __restrict__ xm, unsigned short* __restrict__ Abf) {
  if (blockIdx.y == 0) {
    if (blockIdx.x >= 400) return;
    __shared__ int lh[512];
    for (int i = threadIdx.x; i < nbins; i += 256) lh[i] = 0;
    __syncthreads();
    for (int e = blockIdx.x * 256 + threadIdx.x; e < E; e += 400 * 256)
      atomicAdd(&lh[dstA[e] >> 10], 1);
    __syncthreads();
    for (int i = threadIdx.x; i < nbins; i += 256)
      if (lh[i]) atomicAdd(&bhist[i], lh[i]);
    return;
  }
  int bx = blockIdx.x;
  if (bx >= 778) {
    int idx = (bx - 778) * 256 + threadIdx.x;
    if (idx >= B * 224) return;
    int r = idx / 224, c4 = (idx % 224) * 4;
#pragma unroll
    for (int j = 0; j < 4; j++) {
      int k = c4 + j;
      float v = (k < MORD) ? xm[(size_t)r * MORD + k] : 0.f;
      Abf[(size_t)r * 896 + k] = f2bf(v);
    }
    return;
  }
  if (bx >= 330) {
    int idx = (bx - 330) * 256 + threadIdx.x;
    if (idx >= 512 * 224) return;
    int r = idx / 224, c4 = (idx % 224) * 4;
#pragma unroll
    for (int j = 0; j < 4; j++) {
      int k = c4 + j;
      float v = (k < MORD) ? Wf1[(size_t)r * MORD + k] : 0.f;
      Bbf1[(size_t)r * 896 + k] = f2bf(v);
    }
    return;
  }
  if (bx >= 264) {
    int b = (bx - 264) * 256 + threadIdx.x;
    if (b > B) return;
    int lo = 0, hi = N;
    while (lo < hi) {
      int mid = (lo + hi) >> 1;
      if (batch[mid] < b) lo = mid + 1; else hi = mid;
    }
    goff[b] = lo;
    return;
  }
  int set = bx / 88;
  const float* Wl = set == 0 ? Wl1 : (set == 1 ? Wl2 : Wl3);
  const float* Wr = set == 0 ? Wr1 : (set == 1 ? Wr2 : Wr3);
  unsigned short* Wc = set == 0 ? Wc1 : (set == 1 ? Wc2 : Wc3);
  int CIN = set == 0 ? 8 : 32;
  int idx = (bx - set * 88) * 256 + threadIdx.x;
  if (idx >= 352 * 64) return;
  int row = idx >> 6, k = idx & 63;
  int d = row >> 5, o = row & 31;
  float v = 0.f;
  if (k < CIN) v = Wl[((size_t)d * 32 + o) * CIN + k];
  else if (k < 2 * CIN) v = Wr[((size_t)d * 32 + o) * CIN + (k - CIN)];
  Wc[idx] = f2bf(v);
}

// y=0: layer-1 prep (4-wide pipelined gather). y=1: degree-sorted perm scatter (prefix from dcnt).
__global__ __launch_bounds__(256) void node_prep(const float* __restrict__ x, const int* __restrict__ off,
                                                 const int* __restrict__ csr,
                                                 unsigned short* __restrict__ x1, unsigned short* __restrict__ agg1,
                                                 const int* __restrict__ dcnt, int* __restrict__ dcur0,
                                                 int* __restrict__ perm, int* __restrict__ degp, int N) {
  if (blockIdx.y == 1) {
    __shared__ int ldc[11];
    __shared__ int lbase[11];
    int tid = threadIdx.x;
    int n0 = blockIdx.x * 1024;
    if (n0 >= N) return;
    if (tid < 11) ldc[tid] = 0;
    __syncthreads();
    int d[4], slot[4];
#pragma unroll
    for (int j = 0; j < 4; j++) {
      int n = n0 + tid * 4 + j;
      d[j] = -1;
      if (n < N) {
        d[j] = min(off[n + 1] - off[n], 10);
        slot[j] = atomicAdd(&ldc[d[j]], 1);
      }
    }
    __syncthreads();
    if (tid < 11) {
      int pre = 0;
      for (int d2 = 0; d2 < tid; d2++) pre += dcnt[d2];
      lbase[tid] = pre + (ldc[tid] ? atomicAdd(&dcur0[tid], ldc[tid]) : 0);
    }
    __syncthreads();
#pragma unroll
    for (int j = 0; j < 4; j++) {
      int n = n0 + tid * 4 + j;
      if (n < N) {
        int p = lbase[d[j]] + slot[j];
        perm[p] = n;
        degp[p] = d[j];
      }
    }
    return;
  }
  int n = blockIdx.x * 256 + threadIdx.x;
  if (n >= N) return;
  int a = off[n], b = off[n + 1];
  float ag[8] = {};
  for (int base = a; base < b; base += 4) {
    int rem = b - base;
    int j1 = base + (rem > 1 ? 1 : 0);
    int j2 = base + (rem > 2 ? 2 : 0);
    int j3 = base + (rem > 3 ? 3 : 0);
    int cc0 = csr[base], cc1 = csr[j1], cc2 = csr[j2], cc3 = csr[j3];
    f32x4a v0a = *(const f32x4a*)(x + (size_t)cc0 * 8);
    f32x4a v0b = *(const f32x4a*)(x + (size_t)cc0 * 8 + 4);
    f32x4a v1a = *(const f32x4a*)(x + (size_t)cc1 * 8);
    f32x4a v1b = *(const f32x4a*)(x + (size_t)cc1 * 8 + 4);
    f32x4a v2a = *(const f32x4a*)(x + (size_t)cc2 * 8);
    f32x4a v2b = *(const f32x4a*)(x + (size_t)cc2 * 8 + 4);
    f32x4a v3a = *(const f32x4a*)(x + (size_t)cc3 * 8);
    f32x4a v3b = *(const f32x4a*)(x + (size_t)cc3 * 8 + 4);
    float m1 = rem > 1 ? 1.f : 0.f;
    float m2 = rem > 2 ? 1.f : 0.f;
    float m3 = rem > 3 ? 1.f : 0.f;
#pragma unroll
    for (int t = 0; t < 4; t++) {
      ag[t] += v0a[t];
      ag[t] = fmaf(m1, v1a[t], ag[t]);
      ag[t] = fmaf(m2, v2a[t], ag[t]);
      ag[t] = fmaf(m3, v3a[t], ag[t]);
      ag[t + 4] += v0b[t];
      ag[t + 4] = fmaf(m1, v1b[t], ag[t + 4]);
      ag[t + 4] = fmaf(m2, v2b[t], ag[t + 4]);
      ag[t + 4] = fmaf(m3, v3b[t], ag[t + 4]);
    }
  }
  const float* xo = x + (size_t)n * 8;
  s16x8 w0, w1;
#pragma unroll
  for (int t = 0; t < 8; t++) {
    w0[t] = (short)f2bf(ag[t]);
    w1[t] = (short)f2bf(xo[t]);
  }
  *(s16x8*)(agg1 + (size_t)n * 8) = w0;
  *(s16x8*)(x1 + (size_t)n * 8) = w1;
}

// neighbor-sum over compact X[N][32] -> AGG[N][32], 4-wide pipelined
__global__ __launch_bounds__(256) void gather_c(const unsigned short* __restrict__ X, const int* __restrict__ off,
                                                const int* __restrict__ csr, unsigned short* __restrict__ AGG, int N) {
  long long tid = (long long)blockIdx.x * 256 + threadIdx.x;
  if (tid >= (long long)N * 4) return;
  int n = (int)(tid >> 2), q = (int)(tid & 3);
  int a = off[n], b = off[n + 1];
  float s[8] = {};
  for (int base = a; base < b; base += 4) {
    int rem = b - base;
    int j1 = base + (rem > 1 ? 1 : 0);
    int j2 = base + (rem > 2 ? 2 : 0);
    int j3 = base + (rem > 3 ? 3 : 0);
    int cc0 = csr[base], cc1 = csr[j1], cc2 = csr[j2], cc3 = csr[j3];
    const s16x8 v0 = *(const s16x8*)(X + (size_t)cc0 * 32 + q * 8);
    const s16x8 v1 = *(const s16x8*)(X + (size_t)cc1 * 32 + q * 8);
    const s16x8 v2 = *(const s16x8*)(X + (size_t)cc2 * 32 + q * 8);
    const s16x8 v3 = *(const s16x8*)(X + (size_t)cc3 * 32 + q * 8);
    float m1 = rem > 1 ? 1.f : 0.f;
    float m2 = rem > 2 ? 1.f : 0.f;
    float m3 = rem > 3 ? 1.f : 0.f;
#pragma unroll
    for (int t = 0; t < 8; t++) {
      s[t] += bf2f((unsigned short)v0[t]);
      s[t] = fmaf(m1, bf2f((unsigned short)v1[t]), s[t]);
      s[t] = fmaf(m2, bf2f((unsigned short)v2[t]), s[t]);
      s[t] = fmaf(m3, bf2f((unsigned short)v3[t]), s[t]);
    }
  }
  s16x8 w;
#pragma unroll
  for (int t = 0; t < 8; t++) w[t] = (short)f2bf(s[t]);
  *(s16x8*)(AGG + (size_t)n * 32 + q * 8) = w;
}

// MFMA degree-sorted transform
template <int KS, int ACH, int OUTMODE>
__global__ __launch_bounds__(512, 4) void mfconv_mfma(const unsigned short* __restrict__ xin,
                                                      const unsigned short* __restrict__ agg,
                                                      const unsigned short* __restrict__ Wcat,
                                                      const float* __restrict__ bl,
                                                      const int* __restrict__ perm,
                                                      const int* __restrict__ degp,
                                                      unsigned short* __restrict__ outp, int N) {
  __shared__ __align__(16) unsigned short As[128 * ACH * 8];
  __shared__ __align__(16) unsigned short Bs[352 * 64];
  __shared__ float sbias[352];
  const int tid = threadIdx.x;
  const int wid = tid >> 6, lane = tid & 63;

  for (int s = wid; s < 44; s += 8) {
    int c = s * 64 + lane;
    int cs = c ^ ((c >> 3) & 7);
    __builtin_amdgcn_global_load_lds((const __attribute__((address_space(1))) void*)((const char*)Wcat + (size_t)cs * 16),
                                     (__attribute__((address_space(3))) void*)((char*)Bs + s * 1024), 16, 0, 0);
  }
  for (int i = tid; i < 352; i += 512) sbias[i] = bl[i];

  const int ra = wid * 16 + (lane & 15);
  const int g4 = lane >> 4;
  const int lc = lane & 15;
  const int rl0 = wid * 16 + g4 * 4;

  const int ntiles = N >> 7;
  for (int t = blockIdx.x; t < ntiles; t += (int)gridDim.x) {
    const int row0 = t << 7;
    __syncthreads();
    for (int s = wid; s < 2 * ACH; s += 8) {
      int c = s * 64 + lane;
      int row = c / ACH, ch = c & (ACH - 1);
      int cs = ch ^ (row & (ACH - 1));
      size_t g = (size_t)perm[row0 + row];
      const char* srcp;
      if (ACH == 4) {
        srcp = (cs == 1) ? (const char*)xin + g * 16 : (const char*)agg + g * 16;
      } else {
        srcp = (cs < 4) ? (const char*)agg + g * 64 + (size_t)cs * 16
                        : (const char*)xin + g * 64 + (size_t)(cs - 4) * 16;
      }
      __builtin_amdgcn_global_load_lds((const __attribute__((address_space(1))) void*)srcp,
                                       (__attribute__((address_space(3))) void*)((char*)As + s * 1024), 16, 0, 0);
    }
    int dj[4], pj[4];
#pragma unroll
    for (int j = 0; j < 4; j++) {
      int rr = row0 + rl0 + j;
      dj[j] = degp[rr];
      pj[j] = perm[rr];
    }
    int dmin = degp[row0], dmax = degp[row0 + 127];
    __syncthreads();

    s16x8 af[KS];
#pragma unroll
    for (int kk = 0; kk < KS; kk++) {
      int cha = (kk * 4 + g4) ^ (ra & (ACH - 1));
      af[kk] = *(const s16x8*)((const char*)As + (size_t)(ra * ACH + cha) * 16);
    }

    for (int nn2 = dmin * 2; nn2 <= dmax * 2 + 1; nn2++) {
      f32x4 acc = {};
      int rb = nn2 * 16 + lc;
#pragma unroll
      for (int kk = 0; kk < KS; kk++) {
        int cb = rb * 8 + kk * 4 + g4;
        s16x8 bf = *(const s16x8*)((const char*)Bs + (size_t)(cb ^ (rb & 7)) * 16);
        acc = __builtin_amdgcn_mfma_f32_16x16x32_bf16(af[kk], bf, acc, 0, 0, 0);
      }
      int dsel = nn2 >> 1;
      int o = (nn2 & 1) * 16 + lc;
      float bv = sbias[dsel * 32 + o];
#pragma unroll
      for (int j = 0; j < 4; j++) {
        if (dj[j] == dsel) {
          float v = acc[j] + bv;
          if (OUTMODE == 0) v = fmaxf(v, 0.f);
          outp[(size_t)pj[j] * 32 + o] = f2bf(v);
        }
      }
    }
  }
}

// fc1: bf16 MFMA GEMM 128x128 BK=64 global_load_lds; relu+bias -> bf16; fused colstats; XCD swizzle.
__global__ __launch_bounds__(256) void gemm_fc1b(const unsigned short* __restrict__ A,
                                                 const unsigned short* __restrict__ Bw,
                                                 const float* __restrict__ bias,
                                                 unsigned short* __restrict__ Cout,
                                                 float* __restrict__ csum, float* __restrict__ csq,
                                                 int M, int Nn, int Kp) {
  __shared__ __align__(16) unsigned short As[128 * 64];
  __shared__ __align__(16) unsigned short Bs[128 * 64];
  __shared__ float scs[128], sqs[128];
  int tid = threadIdx.x;
  int wid = tid >> 6, lane = tid & 63;
  int lin = blockIdx.x + blockIdx.y * 4;
  int swz = (lin & 7) * 64 + (lin >> 3);
  int m0 = (swz >> 2) * 128, n0 = (swz & 3) * 128;
  int wr = wid >> 1, wc = wid & 1;
  f32x4 acc[4][4] = {};

  int srow_l = lane >> 3;
  int scol = (lane & 7) * 8;
  int aReadBase = ((wr * 64 + (lane & 15)) * 128) + ((lane >> 4) * 16);
  int bReadBase = ((wc * 64 + (lane & 15)) * 128) + ((lane >> 4) * 16);

  const unsigned short* Ablk = A + (size_t)m0 * Kp;
  const unsigned short* Bblk = Bw + (size_t)n0 * Kp;

  for (int k0 = 0; k0 < Kp; k0 += 64) {
#pragma unroll
    for (int i = 0; i < 4; i++) {
      int s = wid * 4 + i;
      int row = s * 8 + srow_l;
      const unsigned short* ga = Ablk + (size_t)row * Kp + k0 + scol;
      const unsigned short* gb = Bblk + (size_t)row * Kp + k0 + scol;
      __builtin_amdgcn_global_load_lds((const __attribute__((address_space(1))) void*)ga,
                                       (__attribute__((address_space(3))) void*)(As + s * 512), 16, 0, 0);
      __builtin_amdgcn_global_load_lds((const __attribute__((address_space(1))) void*)gb,
                                       (__attribute__((address_space(3))) void*)(Bs + s * 512), 16, 0, 0);
    }
    __syncthreads();
#pragma unroll
    for (int kk = 0; kk < 2; kk++) {
      s16x8 af[4], bfr[4];
#pragma unroll
      for (int m = 0; m < 4; m++)
        af[m] = *(const s16x8*)((const char*)As + aReadBase + m * (16 * 128) + kk * 64);
#pragma unroll
      for (int n = 0; n < 4; n++)
        bfr[n] = *(const s16x8*)((const char*)Bs + bReadBase + n * (16 * 128) + kk * 64);
#pragma unroll
      for (int m = 0; m < 4; m++)
#pragma unroll
        for (int n = 0; n < 4; n++)
          acc[m][n] = __builtin_amdgcn_mfma_f32_16x16x32_bf16(af[m], bfr[n], acc[m][n], 0, 0, 0);
    }
    __syncthreads();
  }

  if (tid < 128) { scs[tid] = 0.f; sqs[tid] = 0.f; }
  __syncthreads();
  int rbase = m0 + wr * 64 + (lane >> 4) * 4;
  int lc = lane & 15;
#pragma unroll
  for (int n = 0; n < 4; n++) {
    int colb = wc * 64 + n * 16 + lc;
    float bv = bias[n0 + colb];
    float s = 0.f, q = 0.f;
#pragma unroll
    for (int m = 0; m < 4; m++) {
#pragma unroll
      for (int j = 0; j < 4; j++) {
        int row = rbase + m * 16 + j;
        float v = fmaxf(acc[m][n][j] + bv, 0.f);
        Cout[(size_t)row * Nn + n0 + colb] = f2bf(v);
        s += v;
        q = fmaf(v, v, q);
      }
    }
    s += __shfl_xor(s, 16); q += __shfl_xor(q, 16);
    s += __shfl_xor(s, 32); q += __shfl_xor(q, 32);
    if ((lane >> 4) == 0) { atomicAdd(&scs[colb], s); atomicAdd(&sqs[colb], q); }
  }
  __syncthreads();
  if (tid < 128) { atomicAdd(&csum[n0 + tid], scs[tid]); atomicAdd(&csq[n0 + tid], sqs[tid]); }
}

// prepW2 with BN1 folded
__global__ __launch_bounds__(256) void prepW2_bn(const float* __restrict__ W2, const float* __restrict__ b2,
                                                 const float* __restrict__ s1, const float* __restrict__ q1,
                                                 const float* __restrict__ g1, const float* __restrict__ be1,
                                                 unsigned short* __restrict__ W2p, float* __restrict__ b2p,
                                                 int Nn, int K, float invM) {
  __shared__ float a1l[512], h1l[512];
  for (int c = threadIdx.x; c < K; c += 256) {
    float mu = s1[c] * invM;
    float var = q1[c] * invM - mu * mu;
    float sc = g1[c] * rsqrtf(var + 1e-5f);
    a1l[c] = sc;
    h1l[c] = be1[c] - mu * sc;
  }
  __syncthreads();
  int wid = threadIdx.x >> 6, lane = threadIdx.x & 63;
  int n = blockIdx.x * 4 + wid;
  if (n >= Nn) return;
  float part = 0.f;
  for (int k = lane; k < K; k += 64) {
    float w = W2[(size_t)n * K + k];
    W2p[(size_t)n * K + k] = f2bf(w * a1l[k]);
    part = fmaf(w, h1l[k], part);
  }
#pragma unroll
  for (int off = 32; off > 0; off >>= 1) part += __shfl_down(part, off, 64);
  if (lane == 0) b2p[n] = b2[n] + part;
}

// fc2: bf16 MFMA GEMM 128x128, f32 out, relu, fused colstats
__global__ __launch_bounds__(256) void gemm_fc2(const unsigned short* __restrict__ A,
                                                const unsigned short* __restrict__ Bw,
                                                const float* __restrict__ bias,
                                                float* __restrict__ Cout,
                                                float* __restrict__ csum, float* __restrict__ csq,
                                                int M, int Nn, int Kp) {
  __shared__ __align__(16) unsigned short As[128 * 64];
  __shared__ __align__(16) unsigned short Bs[128 * 64];
  __shared__ float scs[128], sqs[128];
  int tid = threadIdx.x;
  int wid = tid >> 6, lane = tid & 63;
  int m0 = blockIdx.y * 128;
  int wr = wid >> 1, wc = wid & 1;
  f32x4 acc[4][4] = {};

  int srow_l = lane >> 3;
  int scol = (lane & 7) * 8;
  int aReadBase = ((wr * 64 + (lane & 15)) * 128) + ((lane >> 4) * 16);
  int bReadBase = ((wc * 64 + (lane & 15)) * 128) + ((lane >> 4) * 16);

  const unsigned short* Ablk = A + (size_t)m0 * Kp;

  for (int k0 = 0; k0 < Kp; k0 += 64) {
#pragma unroll
    for (int i = 0; i < 4; i++) {
      int s = wid * 4 + i;
      int row = s * 8 + srow_l;
      const unsigned short* ga = Ablk + (size_t)row * Kp + k0 + scol;
      const unsigned short* gb = Bw + (size_t)row * Kp + k0 + scol;
      __builtin_amdgcn_global_load_lds((const __attribute__((address_space(1))) void*)ga,
                                       (__attribute__((address_space(3))) void*)(As + s * 512), 16, 0, 0);
      __builtin_amdgcn_global_load_lds((const __attribute__((address_space(1))) void*)gb,
                                       (__attribute__((address_space(3))) void*)(Bs + s * 512), 16, 0, 0);
    }
    __syncthreads();
#pragma unroll
    for (int kk = 0; kk < 2; kk++) {
      s16x8 af[4], bfr[4];
#pragma unroll
      for (int m = 0; m < 4; m++)
        af[m] = *(const s16x8*)((const char*)As + aReadBase + m * (16 * 128) + kk * 64);
#pragma unroll
      for (int n = 0; n < 4; n++)
        bfr[n] = *(const s16x8*)((const char*)Bs + bReadBase + n * (16 * 128) + kk * 64);
#pragma unroll
      for (int m = 0; m < 4; m++)
#pragma unroll
        for (int n = 0; n < 4; n++)
          acc[m][n] = __builtin_amdgcn_mfma_f32_16x16x32_bf16(af[m], bfr[n], acc[m][n], 0, 0, 0);
    }
    __syncthreads();
  }

  if (tid < 128) { scs[tid] = 0.f; sqs[tid] = 0.f; }
  __syncthreads();
  int rbase = m0 + wr * 64 + (lane >> 4) * 4;
  int lc = lane & 15;
#pragma unroll
  for (int n = 0; n < 4; n++) {
    int colb = wc * 64 + n * 16 + lc;
    float bv = bias[colb];
    float s = 0.f, q = 0.f;
#pragma unroll
    for (int m = 0; m < 4; m++) {
#pragma unroll
      for (int j = 0; j < 4; j++) {
        int row = rbase + m * 16 + j;
        float v = fmaxf(acc[m][n][j] + bv, 0.f);
        Cout[(size_t)row * Nn + colb] = v;
        s += v;
        q = fmaf(v, v, q);
      }
    }
    s += __shfl_xor(s, 16); q += __shfl_xor(q, 16);
    s += __shfl_xor(s, 32); q += __shfl_xor(q, 32);
    if ((lane >> 4) == 0) { atomicAdd(&scs[colb], s); atomicAdd(&sqs[colb], q); }
  }
  __syncthreads();
  if (tid < 128) { atomicAdd(&csum[tid], scs[tid]); atomicAdd(&csq[tid], sqs[tid]); }
}

// fc3: fp32 GEMM with BN2 applied to input + relu + fused colstats
__global__ __launch_bounds__(256) void gemm_fc3(const float* __restrict__ A, const float* __restrict__ Bw,
                                                const float* __restrict__ bias,
                                                const float* __restrict__ s2v, const float* __restrict__ q2v,
                                                const float* __restrict__ g2, const float* __restrict__ be2,
                                                float* __restrict__ C, float* __restrict__ s3, float* __restrict__ q3,
                                                int M, float invM) {
  const int BM = 64, BN = 64, BK = 16, K = 128;
  __shared__ float As[BK][BM + 1];
  __shared__ float Bs[BK][BN + 1];
  __shared__ float a2l[128], h2l[128];
  __shared__ float scs[64], sqs[64];
  int tid = threadIdx.x;
  for (int c = tid; c < 128; c += 256) {
    float mu = s2v[c] * invM;
    float var = q2v[c] * invM - mu * mu;
    float sc = g2[c] * rsqrtf(var + 1e-5f);
    a2l[c] = sc;
    h2l[c] = be2[c] - mu * sc;
  }
  if (tid < 64) { scs[tid] = 0.f; sqs[tid] = 0.f; }
  __syncthreads();
  int bm = blockIdx.y * BM;
  int tr = tid / 16, tc = tid % 16;
  float acc[4][4] = {};
  for (int k0 = 0; k0 < K; k0 += BK) {
    for (int i = tid; i < BM * BK; i += 256) {
      int m = i / BK, k = i % BK;
      float v = A[(size_t)(bm + m) * K + k0 + k];
      As[k][m] = fmaf(v, a2l[k0 + k], h2l[k0 + k]);
    }
    for (int i = tid; i < BN * BK; i += 256) {
      int n = i / BK, k = i % BK;
      Bs[k][n] = Bw[(size_t)n * K + k0 + k];
    }
    __syncthreads();
#pragma unroll
    for (int k = 0; k < BK; k++) {
      float a4[4], b4[4];
#pragma unroll
      for (int xx = 0; xx < 4; xx++) a4[xx] = As[k][tr * 4 + xx];
#pragma unroll
      for (int yy = 0; yy < 4; yy++) b4[yy] = Bs[k][tc * 4 + yy];
#pragma unroll
      for (int xx = 0; xx < 4; xx++)
#pragma unroll
        for (int yy = 0; yy < 4; yy++) acc[xx][yy] = fmaf(a4[xx], b4[yy], acc[xx][yy]);
    }
    __syncthreads();
  }
#pragma unroll
  for (int yy = 0; yy < 4; yy++) {
    int n = tc * 4 + yy;
    float bv = bias[n];
    float s = 0.f, q = 0.f;
#pragma unroll
    for (int xx = 0; xx < 4; xx++) {
      int m = bm + tr * 4 + xx;
      float v = fmaxf(acc[xx][yy] + bv, 0.f);
      C[(size_t)m * 64 + n] = v;
      s += v;
      q = fmaf(v, v, q);
    }
    atomicAdd(&scs[n], s);
    atomicAdd(&sqs[n], q);
  }
  __syncthreads();
  if (tid < 64) { atomicAdd(&s3[tid], scs[tid]); atomicAdd(&q3[tid], sqs[tid]); }
}

// fused mean-pool (bf16 H3) + BN3 + output head. one wave per graph.
__global__ __launch_bounds__(256) void pool_head(const unsigned short* __restrict__ H3, const int* __restrict__ goff,
                                                 const float* __restrict__ m3,
                                                 const float* __restrict__ s3, const float* __restrict__ q3,
                                                 const float* __restrict__ g3, const float* __restrict__ be3,
                                                 const float* __restrict__ Wout, const float* __restrict__ bout,
                                                 float* __restrict__ out, int B, float invM) {
  __shared__ float a3l[64], h3l[64];
  if (threadIdx.x < 64) {
    int c = threadIdx.x;
    float mu = s3[c] * invM;
    float var = q3[c] * invM - mu * mu;
    float sc = g3[c] * rsqrtf(var + 1e-5f);
    a3l[c] = sc;
    h3l[c] = be3[c] - mu * sc;
  }
  __syncthreads();
  int w = (int)((blockIdx.x * 256 + threadIdx.x) >> 6);
  if (w >= B) return;
  int lane = threadIdx.x & 63;
  int c = lane & 31, r2 = lane >> 5;
  int a = goff[w], b = goff[w + 1];
  float s = 0.f;
  for (int r = a + r2; r < b; r += 2) s += bf2f(H3[(size_t)r * 32 + c]);
  s += __shfl_down(s, 32);
  float val = 0.f;
  if (r2 == 0) val = (s / fmaxf((float)(b - a), 1.f)) * Wout[c];
  float mv = m3[(size_t)w * 64 + lane];
  val += fmaf(mv, a3l[lane], h3l[lane]) * Wout[32 + lane];
#pragma unroll
  for (int off = 32; off > 0; off >>= 1) val += __shfl_down(val, off);
  if (lane == 0) out[w] = 1.f / (1.f + expf(-(val + bout[0])));
}

extern "C" void kernel_launch(void* const* d_in, const int* in_sizes, int n_in,
                              void* d_out, int out_size, void* d_ws, size_t ws_size,
                              hipStream_t stream) {
  const float* x = (const float*)d_in[0];
  const int* eidx = (const int*)d_in[1];
  const int* batch = (const int*)d_in[2];
  const float* xmord = (const float*)d_in[3];
  const float* Wl1 = (const float*)d_in[4];
  const float* bl1 = (const float*)d_in[5];
  const float* Wr1 = (const float*)d_in[6];
  const float* Wl2 = (const float*)d_in[7];
  const float* bl2 = (const float*)d_in[8];
  const float* Wr2 = (const float*)d_in[9];
  const float* Wl3 = (const float*)d_in[10];
  const float* bl3 = (const float*)d_in[11];
  const float* Wr3 = (const float*)d_in[12];
  const float* Wf1 = (const float*)d_in[13];
  const float* bf1 = (const float*)d_in[14];
  const float* g1 = (const float*)d_in[15];
  const float* be1 = (const float*)d_in[16];
  const float* Wf2 = (const float*)d_in[17];
  const float* bf2 = (const float*)d_in[18];
  const float* g2 = (const float*)d_in[19];
  const float* be2 = (const float*)d_in[20];
  const float* Wf3 = (const float*)d_in[21];
  const float* bf3 = (const float*)d_in[22];
  const float* g3 = (const float*)d_in[23];
  const float* be3 = (const float*)d_in[24];
  const float* Wout = (const float*)d_in[25];
  const float* bout = (const float*)d_in[26];
  float* out = (float*)d_out;

  const int N = in_sizes[2];
  const int E = in_sizes[1] / 2;
  const int B = in_sizes[3] / MORD;
  const int nbins = (N + 1023) >> 10;
  const int* src = eidx;
  const int* dst = eidx + E;

  char* ws = (char*)d_ws;
  size_t off_ = 0;
  auto alloc = [&](size_t bytes) { size_t o = off_; off_ += (bytes + 255) & ~(size_t)255; return o; };
  size_t oX1 = alloc((size_t)N * 8 * 2);
  size_t oAGG1 = alloc((size_t)N * 8 * 2);
  size_t oX2 = alloc((size_t)N * 32 * 2);
  size_t oX3 = alloc((size_t)N * 32 * 2);
  size_t oAGG = alloc((size_t)N * 32 * 2);
  size_t oOff = alloc((size_t)(N + 1) * 4);
  size_t oCsr = alloc((size_t)E * 4);
  size_t oEbuf = alloc((size_t)E * 8);
  size_t oH3 = alloc((size_t)N * 32 * 2);
  size_t oGoff = alloc((size_t)(B + 1) * 4);
  size_t oStats = alloc(8192 * 4);
  size_t oWc1 = alloc(352 * 64 * 2);
  size_t oWc2 = alloc(352 * 64 * 2);
  size_t oWc3 = alloc(352 * 64 * 2);
  size_t oBbf1 = alloc(512 * 896 * 2);
  size_t oW2p = alloc(128 * 512 * 2 + 1024);
  size_t oPerm = alloc((size_t)N * 4);
  size_t oDegp = alloc((size_t)N * 4);
  size_t oAbf = alloc((size_t)B * 896 * 2);
  (void)ws_size;

  unsigned short* X1 = (unsigned short*)(ws + oX1);
  unsigned short* AGG1 = (unsigned short*)(ws + oAGG1);
  unsigned short* X2 = (unsigned short*)(ws + oX2);
  unsigned short* X3 = (unsigned short*)(ws + oX3);
  unsigned short* AGG = (unsigned short*)(ws + oAGG);
  int* offp = (int*)(ws + oOff);
  int* csr = (int*)(ws + oCsr);
  unsigned long long* ebuf = (unsigned long long*)(ws + oEbuf);
  unsigned short* H3 = (unsigned short*)(ws + oH3);
  int* goff = (int*)(ws + oGoff);
  float* st = (float*)(ws + oStats);
  int* bhist = (int*)(st + 4096);
  int* boff = (int*)(st + 4608);
  int* gcur = (int*)(st + 5184);
  int* dcnt = (int*)(st + 5696);
  int* dcur0 = (int*)(st + 5728);
  unsigned short* Wc1 = (unsigned short*)(ws + oWc1);
  unsigned short* Wc2 = (unsigned short*)(ws + oWc2);
  unsigned short* Wc3 = (unsigned short*)(ws + oWc3);
  unsigned short* Bbf1 = (unsigned short*)(ws + oBbf1);
  unsigned short* W2p = (unsigned short*)(ws + oW2p);
  float* b2p = (float*)(ws + oW2p + 131072);
  int* perm = (int*)(ws + oPerm);
  int* degp = (int*)(ws + oDegp);
  unsigned short* Abf = (unsigned short*)(ws + oAbf);
  float *s1 = st, *q1 = st + 512;
  float *s2 = st + 2048, *q2 = st + 2176;
  float *s3 = st + 2560, *q3 = st + 2624;

  // MLP overlays: m1/m2 in AGG; m3 in off/csr region (dead after gather2).
  unsigned short* m1 = (unsigned short*)(ws + oAGG);
  float* m2 = (float*)(ws + oAGG + 16777216);
  float* m3 = (float*)(ws + oOff);

  hipMemsetAsync(st, 0, 5760 * 4, stream);

  // CSR build + all prep (Wcat, goff, Wf1 cvt, xmord cvt) in one launch
  int cvtA_blocks = (B * 224 + 255) / 256;
  mega_prep<<<dim3(778 + cvtA_blocks, 2), 256, 0, stream>>>(dst, bhist, E, nbins,
                                                            Wl1, Wr1, Wc1, Wl2, Wr2, Wc2, Wl3, Wr3, Wc3,
                                                            batch, goff, N, B, Wf1, Bbf1, xmord, Abf);
  bin_scan<<<1, 512, 0, stream>>>(bhist, boff, gcur, nbins, E);
  bin_split<<<400, 256, 0, stream>>>(src, dst, gcur, ebuf, E, nbins);
  bin_csr<<<nbins, 256, 0, stream>>>(ebuf, boff, offp, csr, dcnt, N, E);
  node_prep<<<dim3((N + 255) / 256, 2), 256, 0, stream>>>(x, offp, csr, X1, AGG1, dcnt, dcur0, perm, degp, N);

  // GNN layers (degree-sorted MFMA)
  mfconv_mfma<1, 4, 0><<<512, 512, 0, stream>>>(X1, AGG1, Wc1, bl1, perm, degp, X2, N);
  gather_c<<<(int)(((long long)N * 4 + 255) / 256), 256, 0, stream>>>(X2, offp, csr, AGG, N);
  mfconv_mfma<2, 8, 0><<<512, 512, 0, stream>>>(X2, AGG, Wc2, bl2, perm, degp, X3, N);
  gather_c<<<(int)(((long long)N * 4 + 255) / 256), 256, 0, stream>>>(X3, offp, csr, AGG, N);
  mfconv_mfma<2, 8, 1><<<512, 512, 0, stream>>>(X3, AGG, Wc3, bl3, perm, degp, H3, N);

  // MLP head
  gemm_fc1b<<<dim3(4, B / 128), 256, 0, stream>>>(Abf, Bbf1, bf1, m1, s1, q1, B, 512, 896);
  prepW2_bn<<<32, 256, 0, stream>>>(Wf2, bf2, s1, q1, g1, be1, W2p, b2p, 128, 512, 1.f / B);
  gemm_fc2<<<dim3(1, B / 128), 256, 0, stream>>>(m1, W2p, b2p, m2, s2, q2, B, 128, 512);
  gemm_fc3<<<dim3(1, B / 64), 256, 0, stream>>>(m2, Wf3, bf3, s2, q2, g2, be2, m3, s3, q3, B, 1.f / B);
  pool_head<<<(B * 64 + 255) / 256, 256, 0, stream>>>(H3, goff, m3, s3, q3, g3, be3, Wout, bout, out, B, 1.f / B);
}

// Round 16
// 298.052 us; speedup vs baseline: 1.4182x; 1.0179x over previous
//
#include <hip/hip_runtime.h>
#include <hip/hip_bf16.h>
#include <math.h>

#define MORD 862

typedef short s16x8 __attribute__((ext_vector_type(8)));
typedef float f32x4 __attribute__((ext_vector_type(4)));
typedef float f32x4a __attribute__((ext_vector_type(4), aligned(4)));

static __device__ __forceinline__ unsigned short f2bf(float v) {
  __hip_bfloat16 h = __float2bfloat16(v);
  return *(unsigned short*)&h;
}
static __device__ __forceinline__ float bf2f(unsigned short u) {
  unsigned int x = ((unsigned int)u) << 16;
  return *(float*)&x;
}

// ---- Binned CSR build ----
__global__ __launch_bounds__(512) void bin_scan(const int* __restrict__ bhist, int* __restrict__ boff,
                                                int* __restrict__ gcur, int nbins, int E) {
  __shared__ int ts[512];
  int tid = threadIdx.x;
  int v = (tid < nbins) ? bhist[tid] : 0;
  ts[tid] = v;
  __syncthreads();
  for (int st = 1; st < 512; st <<= 1) {
    int t = (tid >= st) ? ts[tid - st] : 0;
    __syncthreads();
    ts[tid] += t;
    __syncthreads();
  }
  int ex = ts[tid] - v;
  if (tid < nbins) { boff[tid] = ex; gcur[tid] = ex; }
  if (tid == 0) boff[nbins] = E;
}

__global__ __launch_bounds__(256) void bin_split(const int* __restrict__ srcA, const int* __restrict__ dstA,
                                                 int* __restrict__ gcur, unsigned long long* __restrict__ ebuf,
                                                 int E, int nbins) {
  __shared__ unsigned long long sbuf[512 * 8];
  __shared__ int lcur[512];
  int tid = threadIdx.x;
  for (int base = blockIdx.x * 1024; base < E; base += (int)gridDim.x * 1024) {
    for (int i = tid; i < nbins; i += 256) lcur[i] = 0;
    __syncthreads();
    int e0 = base + tid * 4;
#pragma unroll
    for (int j = 0; j < 4; j++) {
      int e = e0 + j;
      if (e < E) {
        int d = dstA[e], s = srcA[e];
        int bin = d >> 10;
        unsigned long long p = ((unsigned long long)(unsigned int)d << 32) | (unsigned int)s;
        int slot = atomicAdd(&lcur[bin], 1);
        if (slot < 8) sbuf[bin * 8 + slot] = p;
        else { int g = atomicAdd(&gcur[bin], 1); ebuf[g] = p; }
      }
    }
    __syncthreads();
    for (int b = tid; b < nbins; b += 256) {
      int cnt = min(lcur[b], 8);
      if (cnt > 0) {
        int g = atomicAdd(&gcur[b], cnt);
        for (int k = 0; k < cnt; k++) ebuf[g + k] = sbuf[b * 8 + k];
      }
    }
    __syncthreads();
  }
}

// bin_csr + fused degree histogram (dcnt[11])
__global__ __launch_bounds__(256) void bin_csr(const unsigned long long* __restrict__ ebuf,
                                               const int* __restrict__ boff,
                                               int* __restrict__ off, int* __restrict__ csr,
                                               int* __restrict__ dcnt,
                                               int N, int E) {
  __shared__ int lcur[1024];
  __shared__ int part[256];
  __shared__ int ldc[11];
  int b = blockIdx.x;
  int n0 = b << 10;
  int nn = min(1024, N - n0);
  int e0 = boff[b], e1 = boff[b + 1];
  int tid = threadIdx.x;
  for (int i = tid; i < nn; i += 256) lcur[i] = 0;
  if (tid < 11) ldc[tid] = 0;
  __syncthreads();
  for (int e = e0 + tid; e < e1; e += 256) {
    int d = (int)(ebuf[e] >> 32);
    atomicAdd(&lcur[d - n0], 1);
  }
  __syncthreads();
  int base4 = tid * 4;
  int c0 = (base4 < nn) ? lcur[base4] : 0;
  int c1 = (base4 + 1 < nn) ? lcur[base4 + 1] : 0;
  int c2 = (base4 + 2 < nn) ? lcur[base4 + 2] : 0;
  int c3 = (base4 + 3 < nn) ? lcur[base4 + 3] : 0;
  int tot = c0 + c1 + c2 + c3;
  if (base4 < nn) atomicAdd(&ldc[min(c0, 10)], 1);
  if (base4 + 1 < nn) atomicAdd(&ldc[min(c1, 10)], 1);
  if (base4 + 2 < nn) atomicAdd(&ldc[min(c2, 10)], 1);
  if (base4 + 3 < nn) atomicAdd(&ldc[min(c3, 10)], 1);
  part[tid] = tot;
  __syncthreads();
  for (int st = 1; st < 256; st <<= 1) {
    int t = (tid >= st) ? part[tid - st] : 0;
    __syncthreads();
    part[tid] += t;
    __syncthreads();
  }
  int pre = part[tid] - tot;
  __syncthreads();
  if (base4 < nn)     { lcur[base4]     = pre;                off[n0 + base4]     = e0 + pre; }
  if (base4 + 1 < nn) { lcur[base4 + 1] = pre + c0;           off[n0 + base4 + 1] = e0 + pre + c0; }
  if (base4 + 2 < nn) { lcur[base4 + 2] = pre + c0 + c1;      off[n0 + base4 + 2] = e0 + pre + c0 + c1; }
  if (base4 + 3 < nn) { lcur[base4 + 3] = pre + c0 + c1 + c2; off[n0 + base4 + 3] = e0 + pre + c0 + c1 + c2; }
  if (b == 0 && tid == 0) off[N] = E;
  __syncthreads();
  if (tid < 11 && ldc[tid]) atomicAdd(&dcnt[tid], ldc[tid]);
  for (int e = e0 + tid; e < e1; e += 256) {
    unsigned long long p = ebuf[e];
    int d = (int)(p >> 32);
    int s = (int)(p & 0xffffffffu);
    int slot = atomicAdd(&lcur[d - n0], 1);
    csr[e0 + slot] = s;
  }
}

// y=0 (bx<64): bin histogram (64 blocks -> low flush contention).
// y=1: bx<264 Wcat; 264..329 goff; 330..841 Wf1 row cvt; 842.. xmord row cvt.
__global__ __launch_bounds__(256) void mega_prep(const int* __restrict__ dstA, int* __restrict__ bhist, int E, int nbins,
                                                 const float* __restrict__ Wl1, const float* __restrict__ Wr1,
                                                 unsigned short* __restrict__ Wc1,
                                                 const float* __restrict__ Wl2, const float* __restrict__ Wr2,
                                                 unsigned short* __restrict__ Wc2,
                                                 const float* __restrict__ Wl3, const float* __restrict__ Wr3,
                                                 unsigned short* __restrict__ Wc3,
                                                 const int* __restrict__ batch, int* __restrict__ goff, int N, int B,
                                                 const float* __restrict__ Wf1, unsigned short* __restrict__ Bbf1,
                                                 const float* __restrict__ xm, unsigned short* __restrict__ Abf) {
  if (blockIdx.y == 0) {
    if (blockIdx.x >= 64) return;
    __shared__ int lh[512];
    for (int i = threadIdx.x; i < nbins; i += 256) lh[i] = 0;
    __syncthreads();
    for (int e = blockIdx.x * 256 + threadIdx.x; e < E; e += 64 * 256)
      atomicAdd(&lh[dstA[e] >> 10], 1);
    __syncthreads();
    for (int i = threadIdx.x; i < nbins; i += 256)
      if (lh[i]) atomicAdd(&bhist[i], lh[i]);
    return;
  }
  int bx = blockIdx.x;
  if (bx >= 330) {
    // one row per block, fully coalesced vectorized cvt
    const float* srow;
    unsigned short* drow;
    if (bx >= 842) {
      int r = bx - 842;
      if (r >= B) return;
      srow = xm + (size_t)r * MORD;
      drow = Abf + (size_t)r * 896;
    } else {
      int r = bx - 330;
      srow = Wf1 + (size_t)r * MORD;
      drow = Bbf1 + (size_t)r * 896;
    }
    int t = threadIdx.x;
    if (t >= 224) return;
    int c4 = t * 4;
    float fv[4];
    if (c4 + 4 <= MORD) {
      f32x4a v = *(const f32x4a*)(srow + c4);
      fv[0] = v[0]; fv[1] = v[1]; fv[2] = v[2]; fv[3] = v[3];
    } else {
#pragma unroll
      for (int j = 0; j < 4; j++) fv[j] = (c4 + j < MORD) ? srow[c4 + j] : 0.f;
    }
    unsigned short w[4];
#pragma unroll
    for (int j = 0; j < 4; j++) w[j] = f2bf(fv[j]);
    *(unsigned long long*)(drow + c4) = *(unsigned long long*)w;
    return;
  }
  if (bx >= 264) {
    int b = (bx - 264) * 256 + threadIdx.x;
    if (b > B) return;
    int lo = 0, hi = N;
    while (lo < hi) {
      int mid = (lo + hi) >> 1;
      if (batch[mid] < b) lo = mid + 1; else hi = mid;
    }
    goff[b] = lo;
    return;
  }
  int set = bx / 88;
  const float* Wl = set == 0 ? Wl1 : (set == 1 ? Wl2 : Wl3);
  const float* Wr = set == 0 ? Wr1 : (set == 1 ? Wr2 : Wr3);
  unsigned short* Wc = set == 0 ? Wc1 : (set == 1 ? Wc2 : Wc3);
  int CIN = set == 0 ? 8 : 32;
  int idx = (bx - set * 88) * 256 + threadIdx.x;
  if (idx >= 352 * 64) return;
  int row = idx >> 6, k = idx & 63;
  int d = row >> 5, o = row & 31;
  float v = 0.f;
  if (k < CIN) v = Wl[((size_t)d * 32 + o) * CIN + k];
  else if (k < 2 * CIN) v = Wr[((size_t)d * 32 + o) * CIN + (k - CIN)];
  Wc[idx] = f2bf(v);
}

// y=0: layer-1 prep (4-wide pipelined gather). y=1: degree-sorted perm scatter.
__global__ __launch_bounds__(256) void node_prep(const float* __restrict__ x, const int* __restrict__ off,
                                                 const int* __restrict__ csr,
                                                 unsigned short* __restrict__ x1, unsigned short* __restrict__ agg1,
                                                 const int* __restrict__ dcnt, int* __restrict__ dcur0,
                                                 int* __restrict__ perm, int* __restrict__ degp, int N) {
  if (blockIdx.y == 1) {
    __shared__ int ldc[11];
    __shared__ int lbase[11];
    int tid = threadIdx.x;
    int n0 = blockIdx.x * 1024;
    if (n0 >= N) return;
    if (tid < 11) ldc[tid] = 0;
    __syncthreads();
    int d[4], slot[4];
#pragma unroll
    for (int j = 0; j < 4; j++) {
      int n = n0 + tid * 4 + j;
      d[j] = -1;
      if (n < N) {
        d[j] = min(off[n + 1] - off[n], 10);
        slot[j] = atomicAdd(&ldc[d[j]], 1);
      }
    }
    __syncthreads();
    if (tid < 11) {
      int pre = 0;
      for (int d2 = 0; d2 < tid; d2++) pre += dcnt[d2];
      lbase[tid] = pre + (ldc[tid] ? atomicAdd(&dcur0[tid], ldc[tid]) : 0);
    }
    __syncthreads();
#pragma unroll
    for (int j = 0; j < 4; j++) {
      int n = n0 + tid * 4 + j;
      if (n < N) {
        int p = lbase[d[j]] + slot[j];
        perm[p] = n;
        degp[p] = d[j];
      }
    }
    return;
  }
  int n = blockIdx.x * 256 + threadIdx.x;
  if (n >= N) return;
  int a = off[n], b = off[n + 1];
  float ag[8] = {};
  for (int base = a; base < b; base += 4) {
    int rem = b - base;
    int j1 = base + (rem > 1 ? 1 : 0);
    int j2 = base + (rem > 2 ? 2 : 0);
    int j3 = base + (rem > 3 ? 3 : 0);
    int cc0 = csr[base], cc1 = csr[j1], cc2 = csr[j2], cc3 = csr[j3];
    f32x4a v0a = *(const f32x4a*)(x + (size_t)cc0 * 8);
    f32x4a v0b = *(const f32x4a*)(x + (size_t)cc0 * 8 + 4);
    f32x4a v1a = *(const f32x4a*)(x + (size_t)cc1 * 8);
    f32x4a v1b = *(const f32x4a*)(x + (size_t)cc1 * 8 + 4);
    f32x4a v2a = *(const f32x4a*)(x + (size_t)cc2 * 8);
    f32x4a v2b = *(const f32x4a*)(x + (size_t)cc2 * 8 + 4);
    f32x4a v3a = *(const f32x4a*)(x + (size_t)cc3 * 8);
    f32x4a v3b = *(const f32x4a*)(x + (size_t)cc3 * 8 + 4);
    float m1 = rem > 1 ? 1.f : 0.f;
    float m2 = rem > 2 ? 1.f : 0.f;
    float m3 = rem > 3 ? 1.f : 0.f;
#pragma unroll
    for (int t = 0; t < 4; t++) {
      ag[t] += v0a[t];
      ag[t] = fmaf(m1, v1a[t], ag[t]);
      ag[t] = fmaf(m2, v2a[t], ag[t]);
      ag[t] = fmaf(m3, v3a[t], ag[t]);
      ag[t + 4] += v0b[t];
      ag[t + 4] = fmaf(m1, v1b[t], ag[t + 4]);
      ag[t + 4] = fmaf(m2, v2b[t], ag[t + 4]);
      ag[t + 4] = fmaf(m3, v3b[t], ag[t + 4]);
    }
  }
  const float* xo = x + (size_t)n * 8;
  s16x8 w0, w1;
#pragma unroll
  for (int t = 0; t < 8; t++) {
    w0[t] = (short)f2bf(ag[t]);
    w1[t] = (short)f2bf(xo[t]);
  }
  *(s16x8*)(agg1 + (size_t)n * 8) = w0;
  *(s16x8*)(x1 + (size_t)n * 8) = w1;
}

// neighbor-sum over compact X[N][32] -> AGG[N][32], 4-wide pipelined
__global__ __launch_bounds__(256) void gather_c(const unsigned short* __restrict__ X, const int* __restrict__ off,
                                                const int* __restrict__ csr, unsigned short* __restrict__ AGG, int N) {
  long long tid = (long long)blockIdx.x * 256 + threadIdx.x;
  if (tid >= (long long)N * 4) return;
  int n = (int)(tid >> 2), q = (int)(tid & 3);
  int a = off[n], b = off[n + 1];
  float s[8] = {};
  for (int base = a; base < b; base += 4) {
    int rem = b - base;
    int j1 = base + (rem > 1 ? 1 : 0);
    int j2 = base + (rem > 2 ? 2 : 0);
    int j3 = base + (rem > 3 ? 3 : 0);
    int cc0 = csr[base], cc1 = csr[j1], cc2 = csr[j2], cc3 = csr[j3];
    const s16x8 v0 = *(const s16x8*)(X + (size_t)cc0 * 32 + q * 8);
    const s16x8 v1 = *(const s16x8*)(X + (size_t)cc1 * 32 + q * 8);
    const s16x8 v2 = *(const s16x8*)(X + (size_t)cc2 * 32 + q * 8);
    const s16x8 v3 = *(const s16x8*)(X + (size_t)cc3 * 32 + q * 8);
    float m1 = rem > 1 ? 1.f : 0.f;
    float m2 = rem > 2 ? 1.f : 0.f;
    float m3 = rem > 3 ? 1.f : 0.f;
#pragma unroll
    for (int t = 0; t < 8; t++) {
      s[t] += bf2f((unsigned short)v0[t]);
      s[t] = fmaf(m1, bf2f((unsigned short)v1[t]), s[t]);
      s[t] = fmaf(m2, bf2f((unsigned short)v2[t]), s[t]);
      s[t] = fmaf(m3, bf2f((unsigned short)v3[t]), s[t]);
    }
  }
  s16x8 w;
#pragma unroll
  for (int t = 0; t < 8; t++) w[t] = (short)f2bf(s[t]);
  *(s16x8*)(AGG + (size_t)n * 32 + q * 8) = w;
}

// MFMA degree-sorted transform
template <int KS, int ACH, int OUTMODE>
__global__ __launch_bounds__(512, 4) void mfconv_mfma(const unsigned short* __restrict__ xin,
                                                      const unsigned short* __restrict__ agg,
                                                      const unsigned short* __restrict__ Wcat,
                                                      const float* __restrict__ bl,
                                                      const int* __restrict__ perm,
                                                      const int* __restrict__ degp,
                                                      unsigned short* __restrict__ outp, int N) {
  __shared__ __align__(16) unsigned short As[128 * ACH * 8];
  __shared__ __align__(16) unsigned short Bs[352 * 64];
  __shared__ float sbias[352];
  const int tid = threadIdx.x;
  const int wid = tid >> 6, lane = tid & 63;

  for (int s = wid; s < 44; s += 8) {
    int c = s * 64 + lane;
    int cs = c ^ ((c >> 3) & 7);
    __builtin_amdgcn_global_load_lds((const __attribute__((address_space(1))) void*)((const char*)Wcat + (size_t)cs * 16),
                                     (__attribute__((address_space(3))) void*)((char*)Bs + s * 1024), 16, 0, 0);
  }
  for (int i = tid; i < 352; i += 512) sbias[i] = bl[i];

  const int ra = wid * 16 + (lane & 15);
  const int g4 = lane >> 4;
  const int lc = lane & 15;
  const int rl0 = wid * 16 + g4 * 4;

  const int ntiles = N >> 7;
  for (int t = blockIdx.x; t < ntiles; t += (int)gridDim.x) {
    const int row0 = t << 7;
    __syncthreads();
    for (int s = wid; s < 2 * ACH; s += 8) {
      int c = s * 64 + lane;
      int row = c / ACH, ch = c & (ACH - 1);
      int cs = ch ^ (row & (ACH - 1));
      size_t g = (size_t)perm[row0 + row];
      const char* srcp;
      if (ACH == 4) {
        srcp = (cs == 1) ? (const char*)xin + g * 16 : (const char*)agg + g * 16;
      } else {
        srcp = (cs < 4) ? (const char*)agg + g * 64 + (size_t)cs * 16
                        : (const char*)xin + g * 64 + (size_t)(cs - 4) * 16;
      }
      __builtin_amdgcn_global_load_lds((const __attribute__((address_space(1))) void*)srcp,
                                       (__attribute__((address_space(3))) void*)((char*)As + s * 1024), 16, 0, 0);
    }
    int dj[4], pj[4];
#pragma unroll
    for (int j = 0; j < 4; j++) {
      int rr = row0 + rl0 + j;
      dj[j] = degp[rr];
      pj[j] = perm[rr];
    }
    int dmin = degp[row0], dmax = degp[row0 + 127];
    __syncthreads();

    s16x8 af[KS];
#pragma unroll
    for (int kk = 0; kk < KS; kk++) {
      int cha = (kk * 4 + g4) ^ (ra & (ACH - 1));
      af[kk] = *(const s16x8*)((const char*)As + (size_t)(ra * ACH + cha) * 16);
    }

    for (int nn2 = dmin * 2; nn2 <= dmax * 2 + 1; nn2++) {
      f32x4 acc = {};
      int rb = nn2 * 16 + lc;
#pragma unroll
      for (int kk = 0; kk < KS; kk++) {
        int cb = rb * 8 + kk * 4 + g4;
        s16x8 bf = *(const s16x8*)((const char*)Bs + (size_t)(cb ^ (rb & 7)) * 16);
        acc = __builtin_amdgcn_mfma_f32_16x16x32_bf16(af[kk], bf, acc, 0, 0, 0);
      }
      int dsel = nn2 >> 1;
      int o = (nn2 & 1) * 16 + lc;
      float bv = sbias[dsel * 32 + o];
#pragma unroll
      for (int j = 0; j < 4; j++) {
        if (dj[j] == dsel) {
          float v = acc[j] + bv;
          if (OUTMODE == 0) v = fmaxf(v, 0.f);
          outp[(size_t)pj[j] * 32 + o] = f2bf(v);
        }
      }
    }
  }
}

// fc1: bf16 MFMA GEMM 128x128 BK=64 global_load_lds; relu+bias -> bf16; fused colstats; XCD swizzle.
__global__ __launch_bounds__(256) void gemm_fc1b(const unsigned short* __restrict__ A,
                                                 const unsigned short* __restrict__ Bw,
                                                 const float* __restrict__ bias,
                                                 unsigned short* __restrict__ Cout,
                                                 float* __restrict__ csum, float* __restrict__ csq,
                                                 int M, int Nn, int Kp) {
  __shared__ __align__(16) unsigned short As[128 * 64];
  __shared__ __align__(16) unsigned short Bs[128 * 64];
  __shared__ float scs[128], sqs[128];
  int tid = threadIdx.x;
  int wid = tid >> 6, lane = tid & 63;
  int lin = blockIdx.x + blockIdx.y * 4;
  int swz = (lin & 7) * 64 + (lin >> 3);
  int m0 = (swz >> 2) * 128, n0 = (swz & 3) * 128;
  int wr = wid >> 1, wc = wid & 1;
  f32x4 acc[4][4] = {};

  int srow_l = lane >> 3;
  int scol = (lane & 7) * 8;
  int aReadBase = ((wr * 64 + (lane & 15)) * 128) + ((lane >> 4) * 16);
  int bReadBase = ((wc * 64 + (lane & 15)) * 128) + ((lane >> 4) * 16);

  const unsigned short* Ablk = A + (size_t)m0 * Kp;
  const unsigned short* Bblk = Bw + (size_t)n0 * Kp;

  for (int k0 = 0; k0 < Kp; k0 += 64) {
#pragma unroll
    for (int i = 0; i < 4; i++) {
      int s = wid * 4 + i;
      int row = s * 8 + srow_l;
      const unsigned short* ga = Ablk + (size_t)row * Kp + k0 + scol;
      const unsigned short* gb = Bblk + (size_t)row * Kp + k0 + scol;
      __builtin_amdgcn_global_load_lds((const __attribute__((address_space(1))) void*)ga,
                                       (__attribute__((address_space(3))) void*)(As + s * 512), 16, 0, 0);
      __builtin_amdgcn_global_load_lds((const __attribute__((address_space(1))) void*)gb,
                                       (__attribute__((address_space(3))) void*)(Bs + s * 512), 16, 0, 0);
    }
    __syncthreads();
#pragma unroll
    for (int kk = 0; kk < 2; kk++) {
      s16x8 af[4], bfr[4];
#pragma unroll
      for (int m = 0; m < 4; m++)
        af[m] = *(const s16x8*)((const char*)As + aReadBase + m * (16 * 128) + kk * 64);
#pragma unroll
      for (int n = 0; n < 4; n++)
        bfr[n] = *(const s16x8*)((const char*)Bs + bReadBase + n * (16 * 128) + kk * 64);
#pragma unroll
      for (int m = 0; m < 4; m++)
#pragma unroll
        for (int n = 0; n < 4; n++)
          acc[m][n] = __builtin_amdgcn_mfma_f32_16x16x32_bf16(af[m], bfr[n], acc[m][n], 0, 0, 0);
    }
    __syncthreads();
  }

  if (tid < 128) { scs[tid] = 0.f; sqs[tid] = 0.f; }
  __syncthreads();
  int rbase = m0 + wr * 64 + (lane >> 4) * 4;
  int lc = lane & 15;
#pragma unroll
  for (int n = 0; n < 4; n++) {
    int colb = wc * 64 + n * 16 + lc;
    float bv = bias[n0 + colb];
    float s = 0.f, q = 0.f;
#pragma unroll
    for (int m = 0; m < 4; m++) {
#pragma unroll
      for (int j = 0; j < 4; j++) {
        int row = rbase + m * 16 + j;
        float v = fmaxf(acc[m][n][j] + bv, 0.f);
        Cout[(size_t)row * Nn + n0 + colb] = f2bf(v);
        s += v;
        q = fmaf(v, v, q);
      }
    }
    s += __shfl_xor(s, 16); q += __shfl_xor(q, 16);
    s += __shfl_xor(s, 32); q += __shfl_xor(q, 32);
    if ((lane >> 4) == 0) { atomicAdd(&scs[colb], s); atomicAdd(&sqs[colb], q); }
  }
  __syncthreads();
  if (tid < 128) { atomicAdd(&csum[n0 + tid], scs[tid]); atomicAdd(&csq[n0 + tid], sqs[tid]); }
}

// prepW2 with BN1 folded
__global__ __launch_bounds__(256) void prepW2_bn(const float* __restrict__ W2, const float* __restrict__ b2,
                                                 const float* __restrict__ s1, const float* __restrict__ q1,
                                                 const float* __restrict__ g1, const float* __restrict__ be1,
                                                 unsigned short* __restrict__ W2p, float* __restrict__ b2p,
                                                 int Nn, int K, float invM) {
  __shared__ float a1l[512], h1l[512];
  for (int c = threadIdx.x; c < K; c += 256) {
    float mu = s1[c] * invM;
    float var = q1[c] * invM - mu * mu;
    float sc = g1[c] * rsqrtf(var + 1e-5f);
    a1l[c] = sc;
    h1l[c] = be1[c] - mu * sc;
  }
  __syncthreads();
  int wid = threadIdx.x >> 6, lane = threadIdx.x & 63;
  int n = blockIdx.x * 4 + wid;
  if (n >= Nn) return;
  float part = 0.f;
  for (int k = lane; k < K; k += 64) {
    float w = W2[(size_t)n * K + k];
    W2p[(size_t)n * K + k] = f2bf(w * a1l[k]);
    part = fmaf(w, h1l[k], part);
  }
#pragma unroll
  for (int off = 32; off > 0; off >>= 1) part += __shfl_down(part, off, 64);
  if (lane == 0) b2p[n] = b2[n] + part;
}

// fc2: bf16 MFMA GEMM 128x128, f32 out, relu, fused colstats
__global__ __launch_bounds__(256) void gemm_fc2(const unsigned short* __restrict__ A,
                                                const unsigned short* __restrict__ Bw,
                                                const float* __restrict__ bias,
                                                float* __restrict__ Cout,
                                                float* __restrict__ csum, float* __restrict__ csq,
                                                int M, int Nn, int Kp) {
  __shared__ __align__(16) unsigned short As[128 * 64];
  __shared__ __align__(16) unsigned short Bs[128 * 64];
  __shared__ float scs[128], sqs[128];
  int tid = threadIdx.x;
  int wid = tid >> 6, lane = tid & 63;
  int m0 = blockIdx.y * 128;
  int wr = wid >> 1, wc = wid & 1;
  f32x4 acc[4][4] = {};

  int srow_l = lane >> 3;
  int scol = (lane & 7) * 8;
  int aReadBase = ((wr * 64 + (lane & 15)) * 128) + ((lane >> 4) * 16);
  int bReadBase = ((wc * 64 + (lane & 15)) * 128) + ((lane >> 4) * 16);

  const unsigned short* Ablk = A + (size_t)m0 * Kp;

  for (int k0 = 0; k0 < Kp; k0 += 64) {
#pragma unroll
    for (int i = 0; i < 4; i++) {
      int s = wid * 4 + i;
      int row = s * 8 + srow_l;
      const unsigned short* ga = Ablk + (size_t)row * Kp + k0 + scol;
      const unsigned short* gb = Bw + (size_t)row * Kp + k0 + scol;
      __builtin_amdgcn_global_load_lds((const __attribute__((address_space(1))) void*)ga,
                                       (__attribute__((address_space(3))) void*)(As + s * 512), 16, 0, 0);
      __builtin_amdgcn_global_load_lds((const __attribute__((address_space(1))) void*)gb,
                                       (__attribute__((address_space(3))) void*)(Bs + s * 512), 16, 0, 0);
    }
    __syncthreads();
#pragma unroll
    for (int kk = 0; kk < 2; kk++) {
      s16x8 af[4], bfr[4];
#pragma unroll
      for (int m = 0; m < 4; m++)
        af[m] = *(const s16x8*)((const char*)As + aReadBase + m * (16 * 128) + kk * 64);
#pragma unroll
      for (int n = 0; n < 4; n++)
        bfr[n] = *(const s16x8*)((const char*)Bs + bReadBase + n * (16 * 128) + kk * 64);
#pragma unroll
      for (int m = 0; m < 4; m++)
#pragma unroll
        for (int n = 0; n < 4; n++)
          acc[m][n] = __builtin_amdgcn_mfma_f32_16x16x32_bf16(af[m], bfr[n], acc[m][n], 0, 0, 0);
    }
    __syncthreads();
  }

  if (tid < 128) { scs[tid] = 0.f; sqs[tid] = 0.f; }
  __syncthreads();
  int rbase = m0 + wr * 64 + (lane >> 4) * 4;
  int lc = lane & 15;
#pragma unroll
  for (int n = 0; n < 4; n++) {
    int colb = wc * 64 + n * 16 + lc;
    float bv = bias[colb];
    float s = 0.f, q = 0.f;
#pragma unroll
    for (int m = 0; m < 4; m++) {
#pragma unroll
      for (int j = 0; j < 4; j++) {
        int row = rbase + m * 16 + j;
        float v = fmaxf(acc[m][n][j] + bv, 0.f);
        Cout[(size_t)row * Nn + colb] = v;
        s += v;
        q = fmaf(v, v, q);
      }
    }
    s += __shfl_xor(s, 16); q += __shfl_xor(q, 16);
    s += __shfl_xor(s, 32); q += __shfl_xor(q, 32);
    if ((lane >> 4) == 0) { atomicAdd(&scs[colb], s); atomicAdd(&sqs[colb], q); }
  }
  __syncthreads();
  if (tid < 128) { atomicAdd(&csum[tid], scs[tid]); atomicAdd(&csq[tid], sqs[tid]); }
}

// fc3: fp32 GEMM with BN2 applied to input + relu + fused colstats
__global__ __launch_bounds__(256) void gemm_fc3(const float* __restrict__ A, const float* __restrict__ Bw,
                                                const float* __restrict__ bias,
                                                const float* __restrict__ s2v, const float* __restrict__ q2v,
                                                const float* __restrict__ g2, const float* __restrict__ be2,
                                                float* __restrict__ C, float* __restrict__ s3, float* __restrict__ q3,
                                                int M, float invM) {
  const int BM = 64, BN = 64, BK = 16, K = 128;
  __shared__ float As[BK][BM + 1];
  __shared__ float Bs[BK][BN + 1];
  __shared__ float a2l[128], h2l[128];
  __shared__ float scs[64], sqs[64];
  int tid = threadIdx.x;
  for (int c = tid; c < 128; c += 256) {
    float mu = s2v[c] * invM;
    float var = q2v[c] * invM - mu * mu;
    float sc = g2[c] * rsqrtf(var + 1e-5f);
    a2l[c] = sc;
    h2l[c] = be2[c] - mu * sc;
  }
  if (tid < 64) { scs[tid] = 0.f; sqs[tid] = 0.f; }
  __syncthreads();
  int bm = blockIdx.y * BM;
  int tr = tid / 16, tc = tid % 16;
  float acc[4][4] = {};
  for (int k0 = 0; k0 < K; k0 += BK) {
    for (int i = tid; i < BM * BK; i += 256) {
      int m = i / BK, k = i % BK;
      float v = A[(size_t)(bm + m) * K + k0 + k];
      As[k][m] = fmaf(v, a2l[k0 + k], h2l[k0 + k]);
    }
    for (int i = tid; i < BN * BK; i += 256) {
      int n = i / BK, k = i % BK;
      Bs[k][n] = Bw[(size_t)n * K + k0 + k];
    }
    __syncthreads();
#pragma unroll
    for (int k = 0; k < BK; k++) {
      float a4[4], b4[4];
#pragma unroll
      for (int xx = 0; xx < 4; xx++) a4[xx] = As[k][tr * 4 + xx];
#pragma unroll
      for (int yy = 0; yy < 4; yy++) b4[yy] = Bs[k][tc * 4 + yy];
#pragma unroll
      for (int xx = 0; xx < 4; xx++)
#pragma unroll
        for (int yy = 0; yy < 4; yy++) acc[xx][yy] = fmaf(a4[xx], b4[yy], acc[xx][yy]);
    }
    __syncthreads();
  }
#pragma unroll
  for (int yy = 0; yy < 4; yy++) {
    int n = tc * 4 + yy;
    float bv = bias[n];
    float s = 0.f, q = 0.f;
#pragma unroll
    for (int xx = 0; xx < 4; xx++) {
      int m = bm + tr * 4 + xx;
      float v = fmaxf(acc[xx][yy] + bv, 0.f);
      C[(size_t)m * 64 + n] = v;
      s += v;
      q = fmaf(v, v, q);
    }
    atomicAdd(&scs[n], s);
    atomicAdd(&sqs[n], q);
  }
  __syncthreads();
  if (tid < 64) { atomicAdd(&s3[tid], scs[tid]); atomicAdd(&q3[tid], sqs[tid]); }
}

// fused mean-pool (bf16 H3) + BN3 + output head. one wave per graph.
__global__ __launch_bounds__(256) void pool_head(const unsigned short* __restrict__ H3, const int* __restrict__ goff,
                                                 const float* __restrict__ m3,
                                                 const float* __restrict__ s3, const float* __restrict__ q3,
                                                 const float* __restrict__ g3, const float* __restrict__ be3,
                                                 const float* __restrict__ Wout, const float* __restrict__ bout,
                                                 float* __restrict__ out, int B, float invM) {
  __shared__ float a3l[64], h3l[64];
  if (threadIdx.x < 64) {
    int c = threadIdx.x;
    float mu = s3[c] * invM;
    float var = q3[c] * invM - mu * mu;
    float sc = g3[c] * rsqrtf(var + 1e-5f);
    a3l[c] = sc;
    h3l[c] = be3[c] - mu * sc;
  }
  __syncthreads();
  int w = (int)((blockIdx.x * 256 + threadIdx.x) >> 6);
  if (w >= B) return;
  int lane = threadIdx.x & 63;
  int c = lane & 31, r2 = lane >> 5;
  int a = goff[w], b = goff[w + 1];
  float s = 0.f;
  for (int r = a + r2; r < b; r += 2) s += bf2f(H3[(size_t)r * 32 + c]);
  s += __shfl_down(s, 32);
  float val = 0.f;
  if (r2 == 0) val = (s / fmaxf((float)(b - a), 1.f)) * Wout[c];
  float mv = m3[(size_t)w * 64 + lane];
  val += fmaf(mv, a3l[lane], h3l[lane]) * Wout[32 + lane];
#pragma unroll
  for (int off = 32; off > 0; off >>= 1) val += __shfl_down(val, off);
  if (lane == 0) out[w] = 1.f / (1.f + expf(-(val + bout[0])));
}

extern "C" void kernel_launch(void* const* d_in, const int* in_sizes, int n_in,
                              void* d_out, int out_size, void* d_ws, size_t ws_size,
                              hipStream_t stream) {
  const float* x = (const float*)d_in[0];
  const int* eidx = (const int*)d_in[1];
  const int* batch = (const int*)d_in[2];
  const float* xmord = (const float*)d_in[3];
  const float* Wl1 = (const float*)d_in[4];
  const float* bl1 = (const float*)d_in[5];
  const float* Wr1 = (const float*)d_in[6];
  const float* Wl2 = (const float*)d_in[7];
  const float* bl2 = (const float*)d_in[8];
  const float* Wr2 = (const float*)d_in[9];
  const float* Wl3 = (const float*)d_in[10];
  const float* bl3 = (const float*)d_in[11];
  const float* Wr3 = (const float*)d_in[12];
  const float* Wf1 = (const float*)d_in[13];
  const float* bf1 = (const float*)d_in[14];
  const float* g1 = (const float*)d_in[15];
  const float* be1 = (const float*)d_in[16];
  const float* Wf2 = (const float*)d_in[17];
  const float* bf2 = (const float*)d_in[18];
  const float* g2 = (const float*)d_in[19];
  const float* be2 = (const float*)d_in[20];
  const float* Wf3 = (const float*)d_in[21];
  const float* bf3 = (const float*)d_in[22];
  const float* g3 = (const float*)d_in[23];
  const float* be3 = (const float*)d_in[24];
  const float* Wout = (const float*)d_in[25];
  const float* bout = (const float*)d_in[26];
  float* out = (float*)d_out;

  const int N = in_sizes[2];
  const int E = in_sizes[1] / 2;
  const int B = in_sizes[3] / MORD;
  const int nbins = (N + 1023) >> 10;
  const int* src = eidx;
  const int* dst = eidx + E;

  char* ws = (char*)d_ws;
  size_t off_ = 0;
  auto alloc = [&](size_t bytes) { size_t o = off_; off_ += (bytes + 255) & ~(size_t)255; return o; };
  size_t oX1 = alloc((size_t)N * 8 * 2);
  size_t oAGG1 = alloc((size_t)N * 8 * 2);
  size_t oX2 = alloc((size_t)N * 32 * 2);
  size_t oX3 = alloc((size_t)N * 32 * 2);
  size_t oAGG = alloc((size_t)N * 32 * 2);
  size_t oOff = alloc((size_t)(N + 1) * 4);
  size_t oCsr = alloc((size_t)E * 4);
  size_t oEbuf = alloc((size_t)E * 8);
  size_t oH3 = alloc((size_t)N * 32 * 2);
  size_t oGoff = alloc((size_t)(B + 1) * 4);
  size_t oStats = alloc(8192 * 4);
  size_t oWc1 = alloc(352 * 64 * 2);
  size_t oWc2 = alloc(352 * 64 * 2);
  size_t oWc3 = alloc(352 * 64 * 2);
  size_t oBbf1 = alloc(512 * 896 * 2);
  size_t oW2p = alloc(128 * 512 * 2 + 1024);
  size_t oPerm = alloc((size_t)N * 4);
  size_t oDegp = alloc((size_t)N * 4);
  size_t oAbf = alloc((size_t)B * 896 * 2);
  (void)ws_size;

  unsigned short* X1 = (unsigned short*)(ws + oX1);
  unsigned short* AGG1 = (unsigned short*)(ws + oAGG1);
  unsigned short* X2 = (unsigned short*)(ws + oX2);
  unsigned short* X3 = (unsigned short*)(ws + oX3);
  unsigned short* AGG = (unsigned short*)(ws + oAGG);
  int* offp = (int*)(ws + oOff);
  int* csr = (int*)(ws + oCsr);
  unsigned long long* ebuf = (unsigned long long*)(ws + oEbuf);
  unsigned short* H3 = (unsigned short*)(ws + oH3);
  int* goff = (int*)(ws + oGoff);
  float* st = (float*)(ws + oStats);
  int* bhist = (int*)(st + 4096);
  int* boff = (int*)(st + 4608);
  int* gcur = (int*)(st + 5184);
  int* dcnt = (int*)(st + 5696);
  int* dcur0 = (int*)(st + 5728);
  unsigned short* Wc1 = (unsigned short*)(ws + oWc1);
  unsigned short* Wc2 = (unsigned short*)(ws + oWc2);
  unsigned short* Wc3 = (unsigned short*)(ws + oWc3);
  unsigned short* Bbf1 = (unsigned short*)(ws + oBbf1);
  unsigned short* W2p = (unsigned short*)(ws + oW2p);
  float* b2p = (float*)(ws + oW2p + 131072);
  int* perm = (int*)(ws + oPerm);
  int* degp = (int*)(ws + oDegp);
  unsigned short* Abf = (unsigned short*)(ws + oAbf);
  float *s1 = st, *q1 = st + 512;
  float *s2 = st + 2048, *q2 = st + 2176;
  float *s3 = st + 2560, *q3 = st + 2624;

  // MLP overlays: m1/m2 in AGG; m3 in off/csr region (dead after gather2).
  unsigned short* m1 = (unsigned short*)(ws + oAGG);
  float* m2 = (float*)(ws + oAGG + 16777216);
  float* m3 = (float*)(ws + oOff);

  hipMemsetAsync(st, 0, 5760 * 4, stream);

  // CSR build + all prep (Wcat, goff, Wf1 cvt, xmord cvt) in one launch
  mega_prep<<<dim3(842 + B, 2), 256, 0, stream>>>(dst, bhist, E, nbins,
                                                  Wl1, Wr1, Wc1, Wl2, Wr2, Wc2, Wl3, Wr3, Wc3,
                                                  batch, goff, N, B, Wf1, Bbf1, xmord, Abf);
  bin_scan<<<1, 512, 0, stream>>>(bhist, boff, gcur, nbins, E);
  bin_split<<<400, 256, 0, stream>>>(src, dst, gcur, ebuf, E, nbins);
  bin_csr<<<nbins, 256, 0, stream>>>(ebuf, boff, offp, csr, dcnt, N, E);
  node_prep<<<dim3((N + 255) / 256, 2), 256, 0, stream>>>(x, offp, csr, X1, AGG1, dcnt, dcur0, perm, degp, N);

  // GNN layers (degree-sorted MFMA)
  mfconv_mfma<1, 4, 0><<<512, 512, 0, stream>>>(X1, AGG1, Wc1, bl1, perm, degp, X2, N);
  gather_c<<<(int)(((long long)N * 4 + 255) / 256), 256, 0, stream>>>(X2, offp, csr, AGG, N);
  mfconv_mfma<2, 8, 0><<<512, 512, 0, stream>>>(X2, AGG, Wc2, bl2, perm, degp, X3, N);
  gather_c<<<(int)(((long long)N * 4 + 255) / 256), 256, 0, stream>>>(X3, offp, csr, AGG, N);
  mfconv_mfma<2, 8, 1><<<512, 512, 0, stream>>>(X3, AGG, Wc3, bl3, perm, degp, H3, N);

  // MLP head
  gemm_fc1b<<<dim3(4, B / 128), 256, 0, stream>>>(Abf, Bbf1, bf1, m1, s1, q1, B, 512, 896);
  prepW2_bn<<<32, 256, 0, stream>>>(Wf2, bf2, s1, q1, g1, be1, W2p, b2p, 128, 512, 1.f / B);
  gemm_fc2<<<dim3(1, B / 128), 256, 0, stream>>>(m1, W2p, b2p, m2, s2, q2, B, 128, 512);
  gemm_fc3<<<dim3(1, B / 64), 256, 0, stream>>>(m2, Wf3, bf3, s2, q2, g2, be2, m3, s3, q3, B, 1.f / B);
  pool_head<<<(B * 64 + 255) / 256, 256, 0, stream>>>(H3, goff, m3, s3, q3, g3, be3, Wout, bout, out, B, 1.f / B);
}

// Round 17
// 294.724 us; speedup vs baseline: 1.4342x; 1.0113x over previous
//
#include <hip/hip_runtime.h>
#include <hip/hip_bf16.h>
#include <math.h>

#define MORD 862

typedef short s16x8 __attribute__((ext_vector_type(8)));
typedef float f32x4 __attribute__((ext_vector_type(4)));
typedef float f32x4a __attribute__((ext_vector_type(4), aligned(4)));

static __device__ __forceinline__ unsigned short f2bf(float v) {
  __hip_bfloat16 h = __float2bfloat16(v);
  return *(unsigned short*)&h;
}
static __device__ __forceinline__ float bf2f(unsigned short u) {
  unsigned int x = ((unsigned int)u) << 16;
  return *(float*)&x;
}

// bin_split: edges -> per-bin segments of packed u32 (dloc<<19 | src). Local prefix scan of bhist.
__global__ __launch_bounds__(256) void bin_split(const int* __restrict__ srcA, const int* __restrict__ dstA,
                                                 const int* __restrict__ bhist, int* __restrict__ gcur0,
                                                 unsigned int* __restrict__ ebuf, int E, int nbins) {
  __shared__ unsigned int sbuf[512 * 8];
  __shared__ int lcur[512];
  __shared__ int sscan[512];
  int tid = threadIdx.x;
  // exclusive prefix of bhist (512-entry Hillis-Steele, 2 elems/thread)
  int v0 = (tid < nbins) ? bhist[tid] : 0;
  int v1 = (tid + 256 < nbins) ? bhist[tid + 256] : 0;
  sscan[tid] = v0;
  sscan[tid + 256] = v1;
  __syncthreads();
  for (int st = 1; st < 512; st <<= 1) {
    int a0 = (tid >= st) ? sscan[tid - st] : 0;
    int a1 = (tid + 256 >= st) ? sscan[tid + 256 - st] : 0;
    __syncthreads();
    sscan[tid] += a0;
    sscan[tid + 256] += a1;
    __syncthreads();
  }
  sscan[tid] -= v0;        // exclusive
  sscan[tid + 256] -= v1;
  __syncthreads();

  for (int base = blockIdx.x * 1024; base < E; base += (int)gridDim.x * 1024) {
    for (int i = tid; i < nbins; i += 256) lcur[i] = 0;
    __syncthreads();
    int e0 = base + tid * 4;
#pragma unroll
    for (int j = 0; j < 4; j++) {
      int e = e0 + j;
      if (e < E) {
        int d = dstA[e], s = srcA[e];
        int bin = d >> 10;
        unsigned int p = ((unsigned int)(d & 1023) << 19) | (unsigned int)s;
        int slot = atomicAdd(&lcur[bin], 1);
        if (slot < 8) sbuf[bin * 8 + slot] = p;
        else { int g = sscan[bin] + atomicAdd(&gcur0[bin], 1); ebuf[g] = p; }
      }
    }
    __syncthreads();
    for (int b = tid; b < nbins; b += 256) {
      int cnt = min(lcur[b], 8);
      if (cnt > 0) {
        int g = sscan[b] + atomicAdd(&gcur0[b], cnt);
        for (int k = 0; k < cnt; k++) ebuf[g + k] = sbuf[b * 8 + k];
      }
    }
    __syncthreads();
  }
}

// bin_csr: one block per bin; local scan of bhist for segment bounds; packed u32 decode;
// fused degree histogram (dcnt[11]).
__global__ __launch_bounds__(256) void bin_csr(const unsigned int* __restrict__ ebuf,
                                               const int* __restrict__ bhist,
                                               int* __restrict__ off, int* __restrict__ csr,
                                               int* __restrict__ dcnt,
                                               int N, int E, int nbins) {
  __shared__ int lcur[1024];
  __shared__ int part[256];
  __shared__ int ldc[11];
  __shared__ int sscan[512];
  int b = blockIdx.x;
  int n0 = b << 10;
  int nn = min(1024, N - n0);
  int tid = threadIdx.x;
  // exclusive prefix of bhist
  int v0 = (tid < nbins) ? bhist[tid] : 0;
  int v1 = (tid + 256 < nbins) ? bhist[tid + 256] : 0;
  sscan[tid] = v0;
  sscan[tid + 256] = v1;
  __syncthreads();
  for (int st = 1; st < 512; st <<= 1) {
    int a0 = (tid >= st) ? sscan[tid - st] : 0;
    int a1 = (tid + 256 >= st) ? sscan[tid + 256 - st] : 0;
    __syncthreads();
    sscan[tid] += a0;
    sscan[tid + 256] += a1;
    __syncthreads();
  }
  sscan[tid] -= v0;
  sscan[tid + 256] -= v1;
  __syncthreads();
  int e0 = sscan[b];
  int e1 = e0 + bhist[b];

  for (int i = tid; i < nn; i += 256) lcur[i] = 0;
  if (tid < 11) ldc[tid] = 0;
  __syncthreads();
  for (int e = e0 + tid; e < e1; e += 256) {
    int dloc = (int)(ebuf[e] >> 19);
    atomicAdd(&lcur[dloc], 1);
  }
  __syncthreads();
  int base4 = tid * 4;
  int c0 = (base4 < nn) ? lcur[base4] : 0;
  int c1 = (base4 + 1 < nn) ? lcur[base4 + 1] : 0;
  int c2 = (base4 + 2 < nn) ? lcur[base4 + 2] : 0;
  int c3 = (base4 + 3 < nn) ? lcur[base4 + 3] : 0;
  int tot = c0 + c1 + c2 + c3;
  if (base4 < nn) atomicAdd(&ldc[min(c0, 10)], 1);
  if (base4 + 1 < nn) atomicAdd(&ldc[min(c1, 10)], 1);
  if (base4 + 2 < nn) atomicAdd(&ldc[min(c2, 10)], 1);
  if (base4 + 3 < nn) atomicAdd(&ldc[min(c3, 10)], 1);
  part[tid] = tot;
  __syncthreads();
  for (int st = 1; st < 256; st <<= 1) {
    int t = (tid >= st) ? part[tid - st] : 0;
    __syncthreads();
    part[tid] += t;
    __syncthreads();
  }
  int pre = part[tid] - tot;
  __syncthreads();
  if (base4 < nn)     { lcur[base4]     = pre;                off[n0 + base4]     = e0 + pre; }
  if (base4 + 1 < nn) { lcur[base4 + 1] = pre + c0;           off[n0 + base4 + 1] = e0 + pre + c0; }
  if (base4 + 2 < nn) { lcur[base4 + 2] = pre + c0 + c1;      off[n0 + base4 + 2] = e0 + pre + c0 + c1; }
  if (base4 + 3 < nn) { lcur[base4 + 3] = pre + c0 + c1 + c2; off[n0 + base4 + 3] = e0 + pre + c0 + c1 + c2; }
  if (b == 0 && tid == 0) off[N] = E;
  __syncthreads();
  if (tid < 11 && ldc[tid]) atomicAdd(&dcnt[tid], ldc[tid]);
  for (int e = e0 + tid; e < e1; e += 256) {
    unsigned int p = ebuf[e];
    int dloc = (int)(p >> 19);
    int s = (int)(p & 0x7FFFFu);
    int slot = atomicAdd(&lcur[dloc], 1);
    csr[e0 + slot] = s;
  }
}

// y=0 (bx<64): bin histogram. y=1: bx<264 Wcat; 264..329 goff; 330..841 Wf1 row cvt; 842.. xmord row cvt.
__global__ __launch_bounds__(256) void mega_prep(const int* __restrict__ dstA, int* __restrict__ bhist, int E, int nbins,
                                                 const float* __restrict__ Wl1, const float* __restrict__ Wr1,
                                                 unsigned short* __restrict__ Wc1,
                                                 const float* __restrict__ Wl2, const float* __restrict__ Wr2,
                                                 unsigned short* __restrict__ Wc2,
                                                 const float* __restrict__ Wl3, const float* __restrict__ Wr3,
                                                 unsigned short* __restrict__ Wc3,
                                                 const int* __restrict__ batch, int* __restrict__ goff, int N, int B,
                                                 const float* __restrict__ Wf1, unsigned short* __restrict__ Bbf1,
                                                 const float* __restrict__ xm, unsigned short* __restrict__ Abf) {
  if (blockIdx.y == 0) {
    if (blockIdx.x >= 64) return;
    __shared__ int lh[512];
    for (int i = threadIdx.x; i < nbins; i += 256) lh[i] = 0;
    __syncthreads();
    for (int e = blockIdx.x * 256 + threadIdx.x; e < E; e += 64 * 256)
      atomicAdd(&lh[dstA[e] >> 10], 1);
    __syncthreads();
    for (int i = threadIdx.x; i < nbins; i += 256)
      if (lh[i]) atomicAdd(&bhist[i], lh[i]);
    return;
  }
  int bx = blockIdx.x;
  if (bx >= 330) {
    const float* srow;
    unsigned short* drow;
    if (bx >= 842) {
      int r = bx - 842;
      if (r >= B) return;
      srow = xm + (size_t)r * MORD;
      drow = Abf + (size_t)r * 896;
    } else {
      int r = bx - 330;
      srow = Wf1 + (size_t)r * MORD;
      drow = Bbf1 + (size_t)r * 896;
    }
    int t = threadIdx.x;
    if (t >= 224) return;
    int c4 = t * 4;
    float fv[4];
    if (c4 + 4 <= MORD) {
      f32x4a v = *(const f32x4a*)(srow + c4);
      fv[0] = v[0]; fv[1] = v[1]; fv[2] = v[2]; fv[3] = v[3];
    } else {
#pragma unroll
      for (int j = 0; j < 4; j++) fv[j] = (c4 + j < MORD) ? srow[c4 + j] : 0.f;
    }
    unsigned short w[4];
#pragma unroll
    for (int j = 0; j < 4; j++) w[j] = f2bf(fv[j]);
    *(unsigned long long*)(drow + c4) = *(unsigned long long*)w;
    return;
  }
  if (bx >= 264) {
    int b = (bx - 264) * 256 + threadIdx.x;
    if (b > B) return;
    int lo = 0, hi = N;
    while (lo < hi) {
      int mid = (lo + hi) >> 1;
      if (batch[mid] < b) lo = mid + 1; else hi = mid;
    }
    goff[b] = lo;
    return;
  }
  int set = bx / 88;
  const float* Wl = set == 0 ? Wl1 : (set == 1 ? Wl2 : Wl3);
  const float* Wr = set == 0 ? Wr1 : (set == 1 ? Wr2 : Wr3);
  unsigned short* Wc = set == 0 ? Wc1 : (set == 1 ? Wc2 : Wc3);
  int CIN = set == 0 ? 8 : 32;
  int idx = (bx - set * 88) * 256 + threadIdx.x;
  if (idx >= 352 * 64) return;
  int row = idx >> 6, k = idx & 63;
  int d = row >> 5, o = row & 31;
  float v = 0.f;
  if (k < CIN) v = Wl[((size_t)d * 32 + o) * CIN + k];
  else if (k < 2 * CIN) v = Wr[((size_t)d * 32 + o) * CIN + (k - CIN)];
  Wc[idx] = f2bf(v);
}

// y=0: layer-1 prep (4-wide pipelined gather). y=1: degree-sorted perm scatter.
__global__ __launch_bounds__(256) void node_prep(const float* __restrict__ x, const int* __restrict__ off,
                                                 const int* __restrict__ csr,
                                                 unsigned short* __restrict__ x1, unsigned short* __restrict__ agg1,
                                                 const int* __restrict__ dcnt, int* __restrict__ dcur0,
                                                 int* __restrict__ perm, int* __restrict__ degp, int N) {
  if (blockIdx.y == 1) {
    __shared__ int ldc[11];
    __shared__ int lbase[11];
    int tid = threadIdx.x;
    int n0 = blockIdx.x * 1024;
    if (n0 >= N) return;
    if (tid < 11) ldc[tid] = 0;
    __syncthreads();
    int d[4], slot[4];
#pragma unroll
    for (int j = 0; j < 4; j++) {
      int n = n0 + tid * 4 + j;
      d[j] = -1;
      if (n < N) {
        d[j] = min(off[n + 1] - off[n], 10);
        slot[j] = atomicAdd(&ldc[d[j]], 1);
      }
    }
    __syncthreads();
    if (tid < 11) {
      int pre = 0;
      for (int d2 = 0; d2 < tid; d2++) pre += dcnt[d2];
      lbase[tid] = pre + (ldc[tid] ? atomicAdd(&dcur0[tid], ldc[tid]) : 0);
    }
    __syncthreads();
#pragma unroll
    for (int j = 0; j < 4; j++) {
      int n = n0 + tid * 4 + j;
      if (n < N) {
        int p = lbase[d[j]] + slot[j];
        perm[p] = n;
        degp[p] = d[j];
      }
    }
    return;
  }
  int n = blockIdx.x * 256 + threadIdx.x;
  if (n >= N) return;
  int a = off[n], b = off[n + 1];
  float ag[8] = {};
  for (int base = a; base < b; base += 4) {
    int rem = b - base;
    int j1 = base + (rem > 1 ? 1 : 0);
    int j2 = base + (rem > 2 ? 2 : 0);
    int j3 = base + (rem > 3 ? 3 : 0);
    int cc0 = csr[base], cc1 = csr[j1], cc2 = csr[j2], cc3 = csr[j3];
    f32x4a v0a = *(const f32x4a*)(x + (size_t)cc0 * 8);
    f32x4a v0b = *(const f32x4a*)(x + (size_t)cc0 * 8 + 4);
    f32x4a v1a = *(const f32x4a*)(x + (size_t)cc1 * 8);
    f32x4a v1b = *(const f32x4a*)(x + (size_t)cc1 * 8 + 4);
    f32x4a v2a = *(const f32x4a*)(x + (size_t)cc2 * 8);
    f32x4a v2b = *(const f32x4a*)(x + (size_t)cc2 * 8 + 4);
    f32x4a v3a = *(const f32x4a*)(x + (size_t)cc3 * 8);
    f32x4a v3b = *(const f32x4a*)(x + (size_t)cc3 * 8 + 4);
    float m1 = rem > 1 ? 1.f : 0.f;
    float m2 = rem > 2 ? 1.f : 0.f;
    float m3 = rem > 3 ? 1.f : 0.f;
#pragma unroll
    for (int t = 0; t < 4; t++) {
      ag[t] += v0a[t];
      ag[t] = fmaf(m1, v1a[t], ag[t]);
      ag[t] = fmaf(m2, v2a[t], ag[t]);
      ag[t] = fmaf(m3, v3a[t], ag[t]);
      ag[t + 4] += v0b[t];
      ag[t + 4] = fmaf(m1, v1b[t], ag[t + 4]);
      ag[t + 4] = fmaf(m2, v2b[t], ag[t + 4]);
      ag[t + 4] = fmaf(m3, v3b[t], ag[t + 4]);
    }
  }
  const float* xo = x + (size_t)n * 8;
  s16x8 w0, w1;
#pragma unroll
  for (int t = 0; t < 8; t++) {
    w0[t] = (short)f2bf(ag[t]);
    w1[t] = (short)f2bf(xo[t]);
  }
  *(s16x8*)(agg1 + (size_t)n * 8) = w0;
  *(s16x8*)(x1 + (size_t)n * 8) = w1;
}

// neighbor-sum over compact X[N][32] -> AGG[N][32], 4-wide pipelined
__global__ __launch_bounds__(256) void gather_c(const unsigned short* __restrict__ X, const int* __restrict__ off,
                                                const int* __restrict__ csr, unsigned short* __restrict__ AGG, int N) {
  long long tid = (long long)blockIdx.x * 256 + threadIdx.x;
  if (tid >= (long long)N * 4) return;
  int n = (int)(tid >> 2), q = (int)(tid & 3);
  int a = off[n], b = off[n + 1];
  float s[8] = {};
  for (int base = a; base < b; base += 4) {
    int rem = b - base;
    int j1 = base + (rem > 1 ? 1 : 0);
    int j2 = base + (rem > 2 ? 2 : 0);
    int j3 = base + (rem > 3 ? 3 : 0);
    int cc0 = csr[base], cc1 = csr[j1], cc2 = csr[j2], cc3 = csr[j3];
    const s16x8 v0 = *(const s16x8*)(X + (size_t)cc0 * 32 + q * 8);
    const s16x8 v1 = *(const s16x8*)(X + (size_t)cc1 * 32 + q * 8);
    const s16x8 v2 = *(const s16x8*)(X + (size_t)cc2 * 32 + q * 8);
    const s16x8 v3 = *(const s16x8*)(X + (size_t)cc3 * 32 + q * 8);
    float m1 = rem > 1 ? 1.f : 0.f;
    float m2 = rem > 2 ? 1.f : 0.f;
    float m3 = rem > 3 ? 1.f : 0.f;
#pragma unroll
    for (int t = 0; t < 8; t++) {
      s[t] += bf2f((unsigned short)v0[t]);
      s[t] = fmaf(m1, bf2f((unsigned short)v1[t]), s[t]);
      s[t] = fmaf(m2, bf2f((unsigned short)v2[t]), s[t]);
      s[t] = fmaf(m3, bf2f((unsigned short)v3[t]), s[t]);
    }
  }
  s16x8 w;
#pragma unroll
  for (int t = 0; t < 8; t++) w[t] = (short)f2bf(s[t]);
  *(s16x8*)(AGG + (size_t)n * 32 + q * 8) = w;
}

// MFMA degree-sorted transform
template <int KS, int ACH, int OUTMODE>
__global__ __launch_bounds__(512, 4) void mfconv_mfma(const unsigned short* __restrict__ xin,
                                                      const unsigned short* __restrict__ agg,
                                                      const unsigned short* __restrict__ Wcat,
                                                      const float* __restrict__ bl,
                                                      const int* __restrict__ perm,
                                                      const int* __restrict__ degp,
                                                      unsigned short* __restrict__ outp, int N) {
  __shared__ __align__(16) unsigned short As[128 * ACH * 8];
  __shared__ __align__(16) unsigned short Bs[352 * 64];
  __shared__ float sbias[352];
  const int tid = threadIdx.x;
  const int wid = tid >> 6, lane = tid & 63;

  for (int s = wid; s < 44; s += 8) {
    int c = s * 64 + lane;
    int cs = c ^ ((c >> 3) & 7);
    __builtin_amdgcn_global_load_lds((const __attribute__((address_space(1))) void*)((const char*)Wcat + (size_t)cs * 16),
                                     (__attribute__((address_space(3))) void*)((char*)Bs + s * 1024), 16, 0, 0);
  }
  for (int i = tid; i < 352; i += 512) sbias[i] = bl[i];

  const int ra = wid * 16 + (lane & 15);
  const int g4 = lane >> 4;
  const int lc = lane & 15;
  const int rl0 = wid * 16 + g4 * 4;

  const int ntiles = N >> 7;
  for (int t = blockIdx.x; t < ntiles; t += (int)gridDim.x) {
    const int row0 = t << 7;
    __syncthreads();
    for (int s = wid; s < 2 * ACH; s += 8) {
      int c = s * 64 + lane;
      int row = c / ACH, ch = c & (ACH - 1);
      int cs = ch ^ (row & (ACH - 1));
      size_t g = (size_t)perm[row0 + row];
      const char* srcp;
      if (ACH == 4) {
        srcp = (cs == 1) ? (const char*)xin + g * 16 : (const char*)agg + g * 16;
      } else {
        srcp = (cs < 4) ? (const char*)agg + g * 64 + (size_t)cs * 16
                        : (const char*)xin + g * 64 + (size_t)(cs - 4) * 16;
      }
      __builtin_amdgcn_global_load_lds((const __attribute__((address_space(1))) void*)srcp,
                                       (__attribute__((address_space(3))) void*)((char*)As + s * 1024), 16, 0, 0);
    }
    int dj[4], pj[4];
#pragma unroll
    for (int j = 0; j < 4; j++) {
      int rr = row0 + rl0 + j;
      dj[j] = degp[rr];
      pj[j] = perm[rr];
    }
    int dmin = degp[row0], dmax = degp[row0 + 127];
    __syncthreads();

    s16x8 af[KS];
#pragma unroll
    for (int kk = 0; kk < KS; kk++) {
      int cha = (kk * 4 + g4) ^ (ra & (ACH - 1));
      af[kk] = *(const s16x8*)((const char*)As + (size_t)(ra * ACH + cha) * 16);
    }

    for (int nn2 = dmin * 2; nn2 <= dmax * 2 + 1; nn2++) {
      f32x4 acc = {};
      int rb = nn2 * 16 + lc;
#pragma unroll
      for (int kk = 0; kk < KS; kk++) {
        int cb = rb * 8 + kk * 4 + g4;
        s16x8 bf = *(const s16x8*)((const char*)Bs + (size_t)(cb ^ (rb & 7)) * 16);
        acc = __builtin_amdgcn_mfma_f32_16x16x32_bf16(af[kk], bf, acc, 0, 0, 0);
      }
      int dsel = nn2 >> 1;
      int o = (nn2 & 1) * 16 + lc;
      float bv = sbias[dsel * 32 + o];
#pragma unroll
      for (int j = 0; j < 4; j++) {
        if (dj[j] == dsel) {
          float v = acc[j] + bv;
          if (OUTMODE == 0) v = fmaxf(v, 0.f);
          outp[(size_t)pj[j] * 32 + o] = f2bf(v);
        }
      }
    }
  }
}

// fc1: bf16 MFMA GEMM 128x128 BK=64 global_load_lds; relu+bias -> bf16; fused colstats; XCD swizzle.
__global__ __launch_bounds__(256) void gemm_fc1b(const unsigned short* __restrict__ A,
                                                 const unsigned short* __restrict__ Bw,
                                                 const float* __restrict__ bias,
                                                 unsigned short* __restrict__ Cout,
                                                 float* __restrict__ csum, float* __restrict__ csq,
                                                 int M, int Nn, int Kp) {
  __shared__ __align__(16) unsigned short As[128 * 64];
  __shared__ __align__(16) unsigned short Bs[128 * 64];
  __shared__ float scs[128], sqs[128];
  int tid = threadIdx.x;
  int wid = tid >> 6, lane = tid & 63;
  int lin = blockIdx.x + blockIdx.y * 4;
  int swz = (lin & 7) * 64 + (lin >> 3);
  int m0 = (swz >> 2) * 128, n0 = (swz & 3) * 128;
  int wr = wid >> 1, wc = wid & 1;
  f32x4 acc[4][4] = {};

  int srow_l = lane >> 3;
  int scol = (lane & 7) * 8;
  int aReadBase = ((wr * 64 + (lane & 15)) * 128) + ((lane >> 4) * 16);
  int bReadBase = ((wc * 64 + (lane & 15)) * 128) + ((lane >> 4) * 16);

  const unsigned short* Ablk = A + (size_t)m0 * Kp;
  const unsigned short* Bblk = Bw + (size_t)n0 * Kp;

  for (int k0 = 0; k0 < Kp; k0 += 64) {
#pragma unroll
    for (int i = 0; i < 4; i++) {
      int s = wid * 4 + i;
      int row = s * 8 + srow_l;
      const unsigned short* ga = Ablk + (size_t)row * Kp + k0 + scol;
      const unsigned short* gb = Bblk + (size_t)row * Kp + k0 + scol;
      __builtin_amdgcn_global_load_lds((const __attribute__((address_space(1))) void*)ga,
                                       (__attribute__((address_space(3))) void*)(As + s * 512), 16, 0, 0);
      __builtin_amdgcn_global_load_lds((const __attribute__((address_space(1))) void*)gb,
                                       (__attribute__((address_space(3))) void*)(Bs + s * 512), 16, 0, 0);
    }
    __syncthreads();
#pragma unroll
    for (int kk = 0; kk < 2; kk++) {
      s16x8 af[4], bfr[4];
#pragma unroll
      for (int m = 0; m < 4; m++)
        af[m] = *(const s16x8*)((const char*)As + aReadBase + m * (16 * 128) + kk * 64);
#pragma unroll
      for (int n = 0; n < 4; n++)
        bfr[n] = *(const s16x8*)((const char*)Bs + bReadBase + n * (16 * 128) + kk * 64);
#pragma unroll
      for (int m = 0; m < 4; m++)
#pragma unroll
        for (int n = 0; n < 4; n++)
          acc[m][n] = __builtin_amdgcn_mfma_f32_16x16x32_bf16(af[m], bfr[n], acc[m][n], 0, 0, 0);
    }
    __syncthreads();
  }

  if (tid < 128) { scs[tid] = 0.f; sqs[tid] = 0.f; }
  __syncthreads();
  int rbase = m0 + wr * 64 + (lane >> 4) * 4;
  int lc = lane & 15;
#pragma unroll
  for (int n = 0; n < 4; n++) {
    int colb = wc * 64 + n * 16 + lc;
    float bv = bias[n0 + colb];
    float s = 0.f, q = 0.f;
#pragma unroll
    for (int m = 0; m < 4; m++) {
#pragma unroll
      for (int j = 0; j < 4; j++) {
        int row = rbase + m * 16 + j;
        float v = fmaxf(acc[m][n][j] + bv, 0.f);
        Cout[(size_t)row * Nn + n0 + colb] = f2bf(v);
        s += v;
        q = fmaf(v, v, q);
      }
    }
    s += __shfl_xor(s, 16); q += __shfl_xor(q, 16);
    s += __shfl_xor(s, 32); q += __shfl_xor(q, 32);
    if ((lane >> 4) == 0) { atomicAdd(&scs[colb], s); atomicAdd(&sqs[colb], q); }
  }
  __syncthreads();
  if (tid < 128) { atomicAdd(&csum[n0 + tid], scs[tid]); atomicAdd(&csq[n0 + tid], sqs[tid]); }
}

// prepW2 with BN1 folded
__global__ __launch_bounds__(256) void prepW2_bn(const float* __restrict__ W2, const float* __restrict__ b2,
                                                 const float* __restrict__ s1, const float* __restrict__ q1,
                                                 const float* __restrict__ g1, const float* __restrict__ be1,
                                                 unsigned short* __restrict__ W2p, float* __restrict__ b2p,
                                                 int Nn, int K, float invM) {
  __shared__ float a1l[512], h1l[512];
  for (int c = threadIdx.x; c < K; c += 256) {
    float mu = s1[c] * invM;
    float var = q1[c] * invM - mu * mu;
    float sc = g1[c] * rsqrtf(var + 1e-5f);
    a1l[c] = sc;
    h1l[c] = be1[c] - mu * sc;
  }
  __syncthreads();
  int wid = threadIdx.x >> 6, lane = threadIdx.x & 63;
  int n = blockIdx.x * 4 + wid;
  if (n >= Nn) return;
  float part = 0.f;
  for (int k = lane; k < K; k += 64) {
    float w = W2[(size_t)n * K + k];
    W2p[(size_t)n * K + k] = f2bf(w * a1l[k]);
    part = fmaf(w, h1l[k], part);
  }
#pragma unroll
  for (int off = 32; off > 0; off >>= 1) part += __shfl_down(part, off, 64);
  if (lane == 0) b2p[n] = b2[n] + part;
}

// fc2: bf16 MFMA GEMM 128x128, f32 out, relu, fused colstats
__global__ __launch_bounds__(256) void gemm_fc2(const unsigned short* __restrict__ A,
                                                const unsigned short* __restrict__ Bw,
                                                const float* __restrict__ bias,
                                                float* __restrict__ Cout,
                                                float* __restrict__ csum, float* __restrict__ csq,
                                                int M, int Nn, int Kp) {
  __shared__ __align__(16) unsigned short As[128 * 64];
  __shared__ __align__(16) unsigned short Bs[128 * 64];
  __shared__ float scs[128], sqs[128];
  int tid = threadIdx.x;
  int wid = tid >> 6, lane = tid & 63;
  int m0 = blockIdx.y * 128;
  int wr = wid >> 1, wc = wid & 1;
  f32x4 acc[4][4] = {};

  int srow_l = lane >> 3;
  int scol = (lane & 7) * 8;
  int aReadBase = ((wr * 64 + (lane & 15)) * 128) + ((lane >> 4) * 16);
  int bReadBase = ((wc * 64 + (lane & 15)) * 128) + ((lane >> 4) * 16);

  const unsigned short* Ablk = A + (size_t)m0 * Kp;

  for (int k0 = 0; k0 < Kp; k0 += 64) {
#pragma unroll
    for (int i = 0; i < 4; i++) {
      int s = wid * 4 + i;
      int row = s * 8 + srow_l;
      const unsigned short* ga = Ablk + (size_t)row * Kp + k0 + scol;
      const unsigned short* gb = Bw + (size_t)row * Kp + k0 + scol;
      __builtin_amdgcn_global_load_lds((const __attribute__((address_space(1))) void*)ga,
                                       (__attribute__((address_space(3))) void*)(As + s * 512), 16, 0, 0);
      __builtin_amdgcn_global_load_lds((const __attribute__((address_space(1))) void*)gb,
                                       (__attribute__((address_space(3))) void*)(Bs + s * 512), 16, 0, 0);
    }
    __syncthreads();
#pragma unroll
    for (int kk = 0; kk < 2; kk++) {
      s16x8 af[4], bfr[4];
#pragma unroll
      for (int m = 0; m < 4; m++)
        af[m] = *(const s16x8*)((const char*)As + aReadBase + m * (16 * 128) + kk * 64);
#pragma unroll
      for (int n = 0; n < 4; n++)
        bfr[n] = *(const s16x8*)((const char*)Bs + bReadBase + n * (16 * 128) + kk * 64);
#pragma unroll
      for (int m = 0; m < 4; m++)
#pragma unroll
        for (int n = 0; n < 4; n++)
          acc[m][n] = __builtin_amdgcn_mfma_f32_16x16x32_bf16(af[m], bfr[n], acc[m][n], 0, 0, 0);
    }
    __syncthreads();
  }

  if (tid < 128) { scs[tid] = 0.f; sqs[tid] = 0.f; }
  __syncthreads();
  int rbase = m0 + wr * 64 + (lane >> 4) * 4;
  int lc = lane & 15;
#pragma unroll
  for (int n = 0; n < 4; n++) {
    int colb = wc * 64 + n * 16 + lc;
    float bv = bias[colb];
    float s = 0.f, q = 0.f;
#pragma unroll
    for (int m = 0; m < 4; m++) {
#pragma unroll
      for (int j = 0; j < 4; j++) {
        int row = rbase + m * 16 + j;
        float v = fmaxf(acc[m][n][j] + bv, 0.f);
        Cout[(size_t)row * Nn + colb] = v;
        s += v;
        q = fmaf(v, v, q);
      }
    }
    s += __shfl_xor(s, 16); q += __shfl_xor(q, 16);
    s += __shfl_xor(s, 32); q += __shfl_xor(q, 32);
    if ((lane >> 4) == 0) { atomicAdd(&scs[colb], s); atomicAdd(&sqs[colb], q); }
  }
  __syncthreads();
  if (tid < 128) { atomicAdd(&csum[tid], scs[tid]); atomicAdd(&csq[tid], sqs[tid]); }
}

// fc3: fp32 GEMM with BN2 applied to input + relu + fused colstats
__global__ __launch_bounds__(256) void gemm_fc3(const float* __restrict__ A, const float* __restrict__ Bw,
                                                const float* __restrict__ bias,
                                                const float* __restrict__ s2v, const float* __restrict__ q2v,
                                                const float* __restrict__ g2, const float* __restrict__ be2,
                                                float* __restrict__ C, float* __restrict__ s3, float* __restrict__ q3,
                                                int M, float invM) {
  const int BM = 64, BN = 64, BK = 16, K = 128;
  __shared__ float As[BK][BM + 1];
  __shared__ float Bs[BK][BN + 1];
  __shared__ float a2l[128], h2l[128];
  __shared__ float scs[64], sqs[64];
  int tid = threadIdx.x;
  for (int c = tid; c < 128; c += 256) {
    float mu = s2v[c] * invM;
    float var = q2v[c] * invM - mu * mu;
    float sc = g2[c] * rsqrtf(var + 1e-5f);
    a2l[c] = sc;
    h2l[c] = be2[c] - mu * sc;
  }
  if (tid < 64) { scs[tid] = 0.f; sqs[tid] = 0.f; }
  __syncthreads();
  int bm = blockIdx.y * BM;
  int tr = tid / 16, tc = tid % 16;
  float acc[4][4] = {};
  for (int k0 = 0; k0 < K; k0 += BK) {
    for (int i = tid; i < BM * BK; i += 256) {
      int m = i / BK, k = i % BK;
      float v = A[(size_t)(bm + m) * K + k0 + k];
      As[k][m] = fmaf(v, a2l[k0 + k], h2l[k0 + k]);
    }
    for (int i = tid; i < BN * BK; i += 256) {
      int n = i / BK, k = i % BK;
      Bs[k][n] = Bw[(size_t)n * K + k0 + k];
    }
    __syncthreads();
#pragma unroll
    for (int k = 0; k < BK; k++) {
      float a4[4], b4[4];
#pragma unroll
      for (int xx = 0; xx < 4; xx++) a4[xx] = As[k][tr * 4 + xx];
#pragma unroll
      for (int yy = 0; yy < 4; yy++) b4[yy] = Bs[k][tc * 4 + yy];
#pragma unroll
      for (int xx = 0; xx < 4; xx++)
#pragma unroll
        for (int yy = 0; yy < 4; yy++) acc[xx][yy] = fmaf(a4[xx], b4[yy], acc[xx][yy]);
    }
    __syncthreads();
  }
#pragma unroll
  for (int yy = 0; yy < 4; yy++) {
    int n = tc * 4 + yy;
    float bv = bias[n];
    float s = 0.f, q = 0.f;
#pragma unroll
    for (int xx = 0; xx < 4; xx++) {
      int m = bm + tr * 4 + xx;
      float v = fmaxf(acc[xx][yy] + bv, 0.f);
      C[(size_t)m * 64 + n] = v;
      s += v;
      q = fmaf(v, v, q);
    }
    atomicAdd(&scs[n], s);
    atomicAdd(&sqs[n], q);
  }
  __syncthreads();
  if (tid < 64) { atomicAdd(&s3[tid], scs[tid]); atomicAdd(&q3[tid], sqs[tid]); }
}

// fused mean-pool (bf16 H3) + BN3 + output head. one wave per graph.
__global__ __launch_bounds__(256) void pool_head(const unsigned short* __restrict__ H3, const int* __restrict__ goff,
                                                 const float* __restrict__ m3,
                                                 const float* __restrict__ s3, const float* __restrict__ q3,
                                                 const float* __restrict__ g3, const float* __restrict__ be3,
                                                 const float* __restrict__ Wout, const float* __restrict__ bout,
                                                 float* __restrict__ out, int B, float invM) {
  __shared__ float a3l[64], h3l[64];
  if (threadIdx.x < 64) {
    int c = threadIdx.x;
    float mu = s3[c] * invM;
    float var = q3[c] * invM - mu * mu;
    float sc = g3[c] * rsqrtf(var + 1e-5f);
    a3l[c] = sc;
    h3l[c] = be3[c] - mu * sc;
  }
  __syncthreads();
  int w = (int)((blockIdx.x * 256 + threadIdx.x) >> 6);
  if (w >= B) return;
  int lane = threadIdx.x & 63;
  int c = lane & 31, r2 = lane >> 5;
  int a = goff[w], b = goff[w + 1];
  float s = 0.f;
  for (int r = a + r2; r < b; r += 2) s += bf2f(H3[(size_t)r * 32 + c]);
  s += __shfl_down(s, 32);
  float val = 0.f;
  if (r2 == 0) val = (s / fmaxf((float)(b - a), 1.f)) * Wout[c];
  float mv = m3[(size_t)w * 64 + lane];
  val += fmaf(mv, a3l[lane], h3l[lane]) * Wout[32 + lane];
#pragma unroll
  for (int off = 32; off > 0; off >>= 1) val += __shfl_down(val, off);
  if (lane == 0) out[w] = 1.f / (1.f + expf(-(val + bout[0])));
}

extern "C" void kernel_launch(void* const* d_in, const int* in_sizes, int n_in,
                              void* d_out, int out_size, void* d_ws, size_t ws_size,
                              hipStream_t stream) {
  const float* x = (const float*)d_in[0];
  const int* eidx = (const int*)d_in[1];
  const int* batch = (const int*)d_in[2];
  const float* xmord = (const float*)d_in[3];
  const float* Wl1 = (const float*)d_in[4];
  const float* bl1 = (const float*)d_in[5];
  const float* Wr1 = (const float*)d_in[6];
  const float* Wl2 = (const float*)d_in[7];
  const float* bl2 = (const float*)d_in[8];
  const float* Wr2 = (const float*)d_in[9];
  const float* Wl3 = (const float*)d_in[10];
  const float* bl3 = (const float*)d_in[11];
  const float* Wr3 = (const float*)d_in[12];
  const float* Wf1 = (const float*)d_in[13];
  const float* bf1 = (const float*)d_in[14];
  const float* g1 = (const float*)d_in[15];
  const float* be1 = (const float*)d_in[16];
  const float* Wf2 = (const float*)d_in[17];
  const float* bf2 = (const float*)d_in[18];
  const float* g2 = (const float*)d_in[19];
  const float* be2 = (const float*)d_in[20];
  const float* Wf3 = (const float*)d_in[21];
  const float* bf3 = (const float*)d_in[22];
  const float* g3 = (const float*)d_in[23];
  const float* be3 = (const float*)d_in[24];
  const float* Wout = (const float*)d_in[25];
  const float* bout = (const float*)d_in[26];
  float* out = (float*)d_out;

  const int N = in_sizes[2];
  const int E = in_sizes[1] / 2;
  const int B = in_sizes[3] / MORD;
  const int nbins = (N + 1023) >> 10;
  const int* src = eidx;
  const int* dst = eidx + E;

  char* ws = (char*)d_ws;
  size_t off_ = 0;
  auto alloc = [&](size_t bytes) { size_t o = off_; off_ += (bytes + 255) & ~(size_t)255; return o; };
  size_t oX1 = alloc((size_t)N * 8 * 2);
  size_t oAGG1 = alloc((size_t)N * 8 * 2);
  size_t oX2 = alloc((size_t)N * 32 * 2);
  size_t oX3 = alloc((size_t)N * 32 * 2);
  size_t oAGG = alloc((size_t)N * 32 * 2);
  size_t oOff = alloc((size_t)(N + 1) * 4);
  size_t oCsr = alloc((size_t)E * 4);
  size_t oEbuf = alloc((size_t)E * 4);
  size_t oH3 = alloc((size_t)N * 32 * 2);
  size_t oGoff = alloc((size_t)(B + 1) * 4);
  size_t oStats = alloc(8192 * 4);
  size_t oWc1 = alloc(352 * 64 * 2);
  size_t oWc2 = alloc(352 * 64 * 2);
  size_t oWc3 = alloc(352 * 64 * 2);
  size_t oBbf1 = alloc(512 * 896 * 2);
  size_t oW2p = alloc(128 * 512 * 2 + 1024);
  size_t oPerm = alloc((size_t)N * 4);
  size_t oDegp = alloc((size_t)N * 4);
  size_t oAbf = alloc((size_t)B * 896 * 2);
  (void)ws_size;

  unsigned short* X1 = (unsigned short*)(ws + oX1);
  unsigned short* AGG1 = (unsigned short*)(ws + oAGG1);
  unsigned short* X2 = (unsigned short*)(ws + oX2);
  unsigned short* X3 = (unsigned short*)(ws + oX3);
  unsigned short* AGG = (unsigned short*)(ws + oAGG);
  int* offp = (int*)(ws + oOff);
  int* csr = (int*)(ws + oCsr);
  unsigned int* ebuf = (unsigned int*)(ws + oEbuf);
  unsigned short* H3 = (unsigned short*)(ws + oH3);
  int* goff = (int*)(ws + oGoff);
  float* st = (float*)(ws + oStats);
  int* bhist = (int*)(st + 4096);
  int* gcur0 = (int*)(st + 5184);
  int* dcnt = (int*)(st + 5696);
  int* dcur0 = (int*)(st + 5728);
  unsigned short* Wc1 = (unsigned short*)(ws + oWc1);
  unsigned short* Wc2 = (unsigned short*)(ws + oWc2);
  unsigned short* Wc3 = (unsigned short*)(ws + oWc3);
  unsigned short* Bbf1 = (unsigned short*)(ws + oBbf1);
  unsigned short* W2p = (unsigned short*)(ws + oW2p);
  float* b2p = (float*)(ws + oW2p + 131072);
  int* perm = (int*)(ws + oPerm);
  int* degp = (int*)(ws + oDegp);
  unsigned short* Abf = (unsigned short*)(ws + oAbf);
  float *s1 = st, *q1 = st + 512;
  float *s2 = st + 2048, *q2 = st + 2176;
  float *s3 = st + 2560, *q3 = st + 2624;

  // MLP overlays: m1/m2 in AGG; m3 in off/csr region (dead after gather2).
  unsigned short* m1 = (unsigned short*)(ws + oAGG);
  float* m2 = (float*)(ws + oAGG + 16777216);
  float* m3 = (float*)(ws + oOff);

  hipMemsetAsync(st, 0, 5760 * 4, stream);

  // CSR build + all prep (Wcat, goff, Wf1 cvt, xmord cvt) in one launch
  mega_prep<<<dim3(842 + B, 2), 256, 0, stream>>>(dst, bhist, E, nbins,
                                                  Wl1, Wr1, Wc1, Wl2, Wr2, Wc2, Wl3, Wr3, Wc3,
                                                  batch, goff, N, B, Wf1, Bbf1, xmord, Abf);
  bin_split<<<400, 256, 0, stream>>>(src, dst, bhist, gcur0, ebuf, E, nbins);
  bin_csr<<<nbins, 256, 0, stream>>>(ebuf, bhist, offp, csr, dcnt, N, E, nbins);
  node_prep<<<dim3((N + 255) / 256, 2), 256, 0, stream>>>(x, offp, csr, X1, AGG1, dcnt, dcur0, perm, degp, N);

  // GNN layers (degree-sorted MFMA)
  mfconv_mfma<1, 4, 0><<<512, 512, 0, stream>>>(X1, AGG1, Wc1, bl1, perm, degp, X2, N);
  gather_c<<<(int)(((long long)N * 4 + 255) / 256), 256, 0, stream>>>(X2, offp, csr, AGG, N);
  mfconv_mfma<2, 8, 0><<<512, 512, 0, stream>>>(X2, AGG, Wc2, bl2, perm, degp, X3, N);
  gather_c<<<(int)(((long long)N * 4 + 255) / 256), 256, 0, stream>>>(X3, offp, csr, AGG, N);
  mfconv_mfma<2, 8, 1><<<512, 512, 0, stream>>>(X3, AGG, Wc3, bl3, perm, degp, H3, N);

  // MLP head
  gemm_fc1b<<<dim3(4, B / 128), 256, 0, stream>>>(Abf, Bbf1, bf1, m1, s1, q1, B, 512, 896);
  prepW2_bn<<<32, 256, 0, stream>>>(Wf2, bf2, s1, q1, g1, be1, W2p, b2p, 128, 512, 1.f / B);
  gemm_fc2<<<dim3(1, B / 128), 256, 0, stream>>>(m1, W2p, b2p, m2, s2, q2, B, 128, 512);
  gemm_fc3<<<dim3(1, B / 64), 256, 0, stream>>>(m2, Wf3, bf3, s2, q2, g2, be2, m3, s3, q3, B, 1.f / B);
  pool_head<<<(B * 64 + 255) / 256, 256, 0, stream>>>(H3, goff, m3, s3, q3, g3, be3, Wout, bout, out, B, 1.f / B);
}